// Round 1
// baseline (640.703 us; speedup 1.0000x reference)
//
#include <hip/hip_runtime.h>

typedef unsigned long long u64;

// bit-block order: z 0..3 = diag blocks (0,0)..(3,3); 4=B(0,3) 5=B(1,3) 6=B(2,3)
//                  7=B(3,0) 8=B(3,1) 9=B(3,2)   (transposes computed directly via R symmetry)
__device__ __constant__ int c_pi[10]   = {0,1,2,3,0,1,2,3,3,3};
__device__ __constant__ int c_pj[10]   = {0,1,2,3,3,3,3,0,1,2};
__device__ __constant__ int c_dri[10]  = {1,5,8,10,4,7,9,4,7,9};   // dr index per block (stale-blk trace)
__device__ __constant__ int c_diag[10] = {1,1,1,1,0,0,0,0,0,0};
// C block sources per (row-block i, col-block j); -1 = identity (diag)
__device__ __constant__ int c_src[16]  = {-1,7,8,9,  4,-1,8,9,  5,5,-1,9,  6,6,6,-1};

// ---------- 1. center + L2-normalize each feature row: R_uv = y_u . y_v ----------
__global__ __launch_bounds__(128) void k_rownorm(const float* __restrict__ f, float* __restrict__ y) {
  int r = blockIdx.x, t = threadIdx.x;
  __shared__ float red[128];
  float v = f[r*128 + t];
  red[t] = v; __syncthreads();
  for (int s = 64; s > 0; s >>= 1) { if (t < s) red[t] += red[t+s]; __syncthreads(); }
  float mean = red[0] * (1.0f/128.0f);
  __syncthreads();
  float xc = v - mean;
  red[t] = xc*xc; __syncthreads();
  for (int s = 64; s > 0; s >>= 1) { if (t < s) red[t] += red[t+s]; __syncthreads(); }
  float inv = 1.0f / sqrtf(red[0]);
  y[r*128 + t] = xc * inv;
}

// ---------- 2. correlation bit blocks: bits = (|y_a . y_b| > sigmoid(sparse[dri])) ----------
__global__ __launch_bounds__(256) void k_corrbits(const float* __restrict__ y,
                                                  const float* __restrict__ sparse,
                                                  u64* __restrict__ bits) {
  __shared__ float la[32*68];
  __shared__ float lb[32*68];
  __shared__ unsigned char lby[64*68];
  int z = blockIdx.z;
  int a0 = c_pi[z]*1024 + blockIdx.x*64;
  int b0 = c_pj[z]*1024 + blockIdx.y*64;
  int tid = threadIdx.x;
  int tx = tid & 15, ty = tid >> 4;
  float acc[4][4] = {};
  for (int kc = 0; kc < 128; kc += 32) {
    for (int e = tid; e < 2048; e += 256) {
      int rr = e >> 5, kk = e & 31;
      la[kk*68 + rr] = y[(a0+rr)*128 + kc + kk];
      lb[kk*68 + rr] = y[(b0+rr)*128 + kc + kk];
    }
    __syncthreads();
#pragma unroll
    for (int k = 0; k < 32; ++k) {
      const float4 av = *(const float4*)&la[k*68 + ty*4];
      const float4 bv = *(const float4*)&lb[k*68 + tx*4];
      acc[0][0] += av.x*bv.x; acc[0][1] += av.x*bv.y; acc[0][2] += av.x*bv.z; acc[0][3] += av.x*bv.w;
      acc[1][0] += av.y*bv.x; acc[1][1] += av.y*bv.y; acc[1][2] += av.y*bv.z; acc[1][3] += av.y*bv.w;
      acc[2][0] += av.z*bv.x; acc[2][1] += av.z*bv.y; acc[2][2] += av.z*bv.z; acc[2][3] += av.z*bv.w;
      acc[3][0] += av.w*bv.x; acc[3][1] += av.w*bv.y; acc[3][2] += av.w*bv.z; acc[3][3] += av.w*bv.w;
    }
    __syncthreads();
  }
  float sv = sparse[c_dri[z]];
  float dr = 1.0f / (1.0f + expf(-sv));   // sigmoid
  int dg = c_diag[z];
#pragma unroll
  for (int ri = 0; ri < 4; ++ri) {
    int ga = blockIdx.x*64 + ty*4 + ri;
#pragma unroll
    for (int ci = 0; ci < 4; ++ci) {
      int gb = blockIdx.y*64 + tx*4 + ci;
      int on = (fabsf(acc[ri][ci]) > dr) && !(dg && (ga == gb));
      lby[(ty*4+ri)*68 + tx*4+ci] = (unsigned char)on;
    }
  }
  __syncthreads();
  if (tid < 64) {
    u64 w = 0;
    for (int c2 = 0; c2 < 64; ++c2) w |= ((u64)lby[tid*68 + c2]) << c2;
    bits[z*16384 + (blockIdx.x*64 + tid)*16 + blockIdx.y] = w;
  }
}

// ---------- 3. mask rows: mask(u,:) = union of C-rows selected by A-row bits ----------
__global__ __launch_bounds__(64) void k_maskrows(const u64* __restrict__ bits, u64* __restrict__ mask) {
  int u = blockIdx.x;
  int i = u >> 10, a = u & 1023;
  int t = threadIdx.x;
  __shared__ u64 drow[16];
  if (t < 16) drow[t] = bits[i*16384 + a*16 + t];   // A-block row (diag bit already excluded)
  __syncthreads();
  int j = t >> 4, wl = t & 15;
  u64 out;
  if (j == i) {
    out = drow[wl];                                  // A @ I = A on the diagonal block
  } else {
    const u64* S = bits + c_src[i*4 + j]*16384;
    out = 0;
    for (int w2 = 0; w2 < 16; ++w2) {
      u64 m = drow[w2];
      while (m) {
        int b = __builtin_ctzll(m); m &= m - 1;
        out |= S[(w2*64 + b)*16 + wl];
      }
    }
  }
  mask[u*64 + t] = out;
}

// ---------- 4. 64x64 bit-tile transpose ----------
__global__ __launch_bounds__(64) void k_bittrans(const u64* __restrict__ mask, u64* __restrict__ maskT) {
  __shared__ u64 w[64];
  int t = threadIdx.x;
  int tI = blockIdx.x, tJ = blockIdx.y;
  w[t] = mask[(tI*64 + t)*64 + tJ];
  __syncthreads();
  u64 out = 0;
  for (int k = 0; k < 64; ++k) out |= ((w[k] >> t) & 1ULL) << k;
  maskT[(tJ*64 + t)*64 + tI] = out;
}

// ---------- 5. degrees (row popcounts) -> norm = d^-0.5, sfac = d^-1.5 ----------
__global__ __launch_bounds__(64) void k_degrees(const u64* __restrict__ rows,
                                                float* __restrict__ nrm, float* __restrict__ sfac) {
  int v = blockIdx.x, t = threadIdx.x;
  int cnt = __popcll(rows[v*64 + t]);
  for (int off = 32; off > 0; off >>= 1) cnt += __shfl_down(cnt, off);
  if (t == 0) {
    if (cnt > 0) {
      float d = (float)cnt;
      float n = 1.0f / sqrtf(d);
      nrm[v] = n;
      sfac[v] = n * (1.0f / d);
    } else { nrm[v] = 0.0f; sfac[v] = 0.0f; }
  }
}

// ---------- 6. bit-gather aggregation: out[v] = feat[v] + sfac[v] * sum_{u in row(v)} nrm[u]*feat[u] ----------
template<int F>
__global__ __launch_bounds__(128) void k_gather(const u64* __restrict__ rows, const float* __restrict__ feat,
                                                const float* __restrict__ nrm, const float* __restrict__ sfac,
                                                float* __restrict__ out) {
  int v = blockIdx.x, t = threadIdx.x;
  if (F == 128) {
    float acc = 0.0f;
    for (int w = 0; w < 64; ++w) {
      u64 m = rows[v*64 + w];
      while (m) {
        int b = __builtin_ctzll(m); m &= m - 1;
        int u = w*64 + b;
        acc += nrm[u] * feat[u*128 + t];
      }
    }
    out[v*128 + t] = feat[v*128 + t] + sfac[v] * acc;
  } else {  // F == 512, float4 per lane
    const float4* f4 = (const float4*)feat;
    float4 acc = make_float4(0.f,0.f,0.f,0.f);
    for (int w = 0; w < 64; ++w) {
      u64 m = rows[v*64 + w];
      while (m) {
        int b = __builtin_ctzll(m); m &= m - 1;
        int u = w*64 + b;
        float nv = nrm[u];
        float4 x = f4[u*128 + t];
        acc.x += nv*x.x; acc.y += nv*x.y; acc.z += nv*x.z; acc.w += nv*x.w;
      }
    }
    float s = sfac[v];
    float4 xv = f4[v*128 + t];
    float4 r;
    r.x = xv.x + s*acc.x; r.y = xv.y + s*acc.y; r.z = xv.z + s*acc.z; r.w = xv.w + s*acc.w;
    ((float4*)out)[v*128 + t] = r;
  }
}

// ---------- 7. fp32 GEMM (M=4096, N=256) + bias + relu, writes into 512-wide concat buffer ----------
__global__ __launch_bounds__(256) void k_gemm_bias_relu(const float* __restrict__ A, const float* __restrict__ B,
                                                        const float* __restrict__ bias, float* __restrict__ out,
                                                        int K, int colOff) {
  __shared__ float la[32*68];
  __shared__ float lb[32*68];
  int tid = threadIdx.x;
  int tx = tid & 15, ty = tid >> 4;
  int m0 = blockIdx.x*64, n0 = blockIdx.y*64;
  float acc[4][4] = {};
  for (int kc = 0; kc < K; kc += 32) {
    for (int e = tid; e < 2048; e += 256) {
      int rr = e >> 5, kk = e & 31;
      la[kk*68 + rr] = A[(m0+rr)*K + kc + kk];
    }
    for (int e = tid; e < 2048; e += 256) {
      int kk = e >> 6, cc = e & 63;
      lb[kk*68 + cc] = B[(kc+kk)*256 + n0 + cc];
    }
    __syncthreads();
#pragma unroll
    for (int k = 0; k < 32; ++k) {
      const float4 av = *(const float4*)&la[k*68 + ty*4];
      const float4 bv = *(const float4*)&lb[k*68 + tx*4];
      acc[0][0] += av.x*bv.x; acc[0][1] += av.x*bv.y; acc[0][2] += av.x*bv.z; acc[0][3] += av.x*bv.w;
      acc[1][0] += av.y*bv.x; acc[1][1] += av.y*bv.y; acc[1][2] += av.y*bv.z; acc[1][3] += av.y*bv.w;
      acc[2][0] += av.z*bv.x; acc[2][1] += av.z*bv.y; acc[2][2] += av.z*bv.z; acc[2][3] += av.z*bv.w;
      acc[3][0] += av.w*bv.x; acc[3][1] += av.w*bv.y; acc[3][2] += av.w*bv.z; acc[3][3] += av.w*bv.w;
    }
    __syncthreads();
  }
#pragma unroll
  for (int ri = 0; ri < 4; ++ri) {
    int row = m0 + ty*4 + ri;
#pragma unroll
    for (int ci = 0; ci < 4; ++ci) {
      int col = n0 + tx*4 + ci;
      float vv = acc[ri][ci] + bias[col];
      out[row*512 + colOff + col] = vv > 0.0f ? vv : 0.0f;
    }
  }
}

// ---------- 8. BatchNorm (training): per-column mean/var (fp64 accum) -> scale/shift ----------
__global__ __launch_bounds__(256) void k_bnstats(const float* __restrict__ h, const float* __restrict__ gamma,
                                                 const float* __restrict__ beta, float* __restrict__ scale,
                                                 float* __restrict__ shift) {
  int col = blockIdx.x, t = threadIdx.x;
  double s = 0.0, s2 = 0.0;
  for (int r = t; r < 4096; r += 256) {
    double v = (double)h[r*512 + col];
    s += v; s2 += v*v;
  }
  __shared__ double ls[256], ls2[256];
  ls[t] = s; ls2[t] = s2; __syncthreads();
  for (int st = 128; st > 0; st >>= 1) {
    if (t < st) { ls[t] += ls[t+st]; ls2[t] += ls2[t+st]; }
    __syncthreads();
  }
  if (t == 0) {
    double mean = ls[0] / 4096.0;
    double var = ls2[0] / 4096.0 - mean*mean;
    float inv = (float)(1.0 / sqrt(var + 1e-5));
    float sc = gamma[col] * inv;
    scale[col] = sc;
    shift[col] = beta[col] - (float)mean * sc;
  }
}

__global__ __launch_bounds__(256) void k_bnapply(const float* __restrict__ h, const float* __restrict__ scale,
                                                 const float* __restrict__ shift, float* __restrict__ hn) {
  int i = blockIdx.x*256 + threadIdx.x;     // 524288 float4s, grid covers exactly
  const float4 v = ((const float4*)h)[i];
  int cb = (i & 127) * 4;
  float4 r;
  r.x = v.x*scale[cb+0] + shift[cb+0];
  r.y = v.y*scale[cb+1] + shift[cb+1];
  r.z = v.z*scale[cb+2] + shift[cb+2];
  r.w = v.w*scale[cb+3] + shift[cb+3];
  ((float4*)hn)[i] = r;
}

// ---------- 9. readout + softmax(c) modality mixing ----------
__global__ __launch_bounds__(256) void k_final(const float* __restrict__ hn, const float* __restrict__ w_ro,
                                               const float* __restrict__ cl, float* __restrict__ out) {
  int gid = blockIdx.x*256 + threadIdx.x;  // 0..4095 = node*4 + cls
  int node = gid >> 2, cls = gid & 3;
  float c0 = cl[0], c1 = cl[1], c2 = cl[2], c3 = cl[3];
  float mx = fmaxf(fmaxf(c0,c1), fmaxf(c2,c3));
  float e0 = expf(c0-mx), e1 = expf(c1-mx), e2 = expf(c2-mx), e3 = expf(c3-mx);
  float esum = e0+e1+e2+e3;
  float wm0 = e0/esum, wm1 = e1/esum, wm2 = e2/esum, wm3 = e3/esum;
  float wms[4] = {wm0, wm1, wm2, wm3};
  float res = 0.0f;
  for (int m = 0; m < 4; ++m) {
    const float* row = hn + (m*1024 + node)*512;
    float a = 0.0f;
    for (int k = 0; k < 512; ++k) a += row[k] * w_ro[k*4 + cls];
    res += wms[m] * a;
  }
  out[gid] = res;
}

extern "C" void kernel_launch(void* const* d_in, const int* in_sizes, int n_in,
                              void* d_out, int out_size, void* d_ws, size_t ws_size,
                              hipStream_t stream) {
  const float* features = (const float*)d_in[0];
  const float* sparse   = (const float*)d_in[1];
  const float* cmix     = (const float*)d_in[2];
  const float* wAC1 = (const float*)d_in[3];
  const float* bAC1 = (const float*)d_in[4];
  const float* wCA1 = (const float*)d_in[5];
  const float* bCA1 = (const float*)d_in[6];
  const float* wAC2 = (const float*)d_in[7];
  const float* bAC2 = (const float*)d_in[8];
  const float* wCA2 = (const float*)d_in[9];
  const float* bCA2 = (const float*)d_in[10];
  const float* gamma1 = (const float*)d_in[11];
  const float* beta1  = (const float*)d_in[12];
  const float* gamma2 = (const float*)d_in[13];
  const float* beta2  = (const float*)d_in[14];
  const float* w_ro   = (const float*)d_in[15];
  float* out = (float*)d_out;

  char* ws = (char*)d_ws;
  const size_t MB = 1024ull*1024ull;
  float* y     = (float*)(ws + 0);             // 2 MB
  u64*   bits  = (u64*)(ws + 2*MB);            // 1.25 MB (10 blocks x 1024 x 16 words)
  u64*   mask  = (u64*)(ws + 4*MB);            // 2 MB
  u64*   maskT = (u64*)(ws + 6*MB);            // 2 MB
  float* nrm1  = (float*)(ws + 8*MB);
  float* sfac1 = (float*)(ws + 8*MB + 65536);
  float* nrm2  = (float*)(ws + 8*MB + 2*65536);
  float* sfac2 = (float*)(ws + 8*MB + 3*65536);
  float* scale1= (float*)(ws + 8*MB + 4*65536);
  float* shift1= (float*)(ws + 8*MB + 4*65536 + 4096);
  float* scale2= (float*)(ws + 8*MB + 4*65536 + 8192);
  float* shift2= (float*)(ws + 8*MB + 4*65536 + 12288);
  float* preA  = (float*)(ws + 9*MB);          // 8 MB
  float* preB  = (float*)(ws + 17*MB);         // 8 MB
  float* h     = (float*)(ws + 25*MB);         // 8 MB
  float* hn    = (float*)(ws + 33*MB);         // 8 MB   (total ~41 MB)

  k_rownorm<<<dim3(4096), dim3(128), 0, stream>>>(features, y);
  k_corrbits<<<dim3(16,16,10), dim3(256), 0, stream>>>(y, sparse, bits);
  k_maskrows<<<dim3(4096), dim3(64), 0, stream>>>(bits, mask);
  k_bittrans<<<dim3(64,64), dim3(64), 0, stream>>>(mask, maskT);
  k_degrees<<<dim3(4096), dim3(64), 0, stream>>>(mask,  nrm2, sfac2);   // indeg2 = row sums
  k_degrees<<<dim3(4096), dim3(64), 0, stream>>>(maskT, nrm1, sfac1);   // indeg1 = col sums

  // layer 1
  k_gather<128><<<dim3(4096), dim3(128), 0, stream>>>(maskT, features, nrm1, sfac1, preA); // gin1 agg
  k_gather<128><<<dim3(4096), dim3(128), 0, stream>>>(mask,  features, nrm2, sfac2, preB); // gin2 agg
  k_gemm_bias_relu<<<dim3(64,4), dim3(256), 0, stream>>>(preA, wAC1, bAC1, h, 128, 0);
  k_gemm_bias_relu<<<dim3(64,4), dim3(256), 0, stream>>>(preB, wCA1, bCA1, h, 128, 256);
  k_bnstats<<<dim3(512), dim3(256), 0, stream>>>(h, gamma1, beta1, scale1, shift1);
  k_bnapply<<<dim3(2048), dim3(256), 0, stream>>>(h, scale1, shift1, hn);

  // layer 2
  k_gather<512><<<dim3(4096), dim3(128), 0, stream>>>(maskT, hn, nrm1, sfac1, preA);
  k_gather<512><<<dim3(4096), dim3(128), 0, stream>>>(mask,  hn, nrm2, sfac2, preB);
  k_gemm_bias_relu<<<dim3(64,4), dim3(256), 0, stream>>>(preA, wAC2, bAC2, h, 512, 0);
  k_gemm_bias_relu<<<dim3(64,4), dim3(256), 0, stream>>>(preB, wCA2, bCA2, h, 512, 256);
  k_bnstats<<<dim3(512), dim3(256), 0, stream>>>(h, gamma2, beta2, scale2, shift2);
  k_bnapply<<<dim3(2048), dim3(256), 0, stream>>>(h, scale2, shift2, hn);

  k_final<<<dim3(16), dim3(256), 0, stream>>>(hn, w_ro, cmix, out);
}

// Round 2
// 543.307 us; speedup vs baseline: 1.1793x; 1.1793x over previous
//
#include <hip/hip_runtime.h>

typedef unsigned long long u64;
typedef __attribute__((ext_vector_type(8))) short s8v;   // 8 bf16 = 4 VGPRs (MFMA A/B frag)
typedef __attribute__((ext_vector_type(4))) float f4v;   // MFMA C/D frag

__device__ __constant__ int c_pi[10]   = {0,1,2,3,0,1,2,3,3,3};
__device__ __constant__ int c_pj[10]   = {0,1,2,3,3,3,3,0,1,2};
__device__ __constant__ int c_dri[10]  = {1,5,8,10,4,7,9,4,7,9};
__device__ __constant__ int c_diag[10] = {1,1,1,1,0,0,0,0,0,0};
__device__ __constant__ int c_src[16]  = {-1,7,8,9,  4,-1,8,9,  5,5,-1,9,  6,6,6,-1};

// truncation split: v ~= hi + lo, rel err <= ~2^-16
__device__ inline void split2(float v, short& h, short& l) {
  unsigned int u = __float_as_uint(v);
  h = (short)(u >> 16);
  float fh = __uint_as_float(u & 0xffff0000u);
  l = (short)(__float_as_uint(v - fh) >> 16);
}

// ---------- 1. center + L2-normalize feature rows, write split bf16 ----------
__global__ __launch_bounds__(128) void k_rownorm(const float* __restrict__ f,
                                                 short* __restrict__ yhi, short* __restrict__ ylo) {
  int r = blockIdx.x, t = threadIdx.x;
  __shared__ float red[128];
  float v = f[r*128 + t];
  red[t] = v; __syncthreads();
  for (int s = 64; s > 0; s >>= 1) { if (t < s) red[t] += red[t+s]; __syncthreads(); }
  float mean = red[0] * (1.0f/128.0f);
  __syncthreads();
  float xc = v - mean;
  red[t] = xc*xc; __syncthreads();
  for (int s = 64; s > 0; s >>= 1) { if (t < s) red[t] += red[t+s]; __syncthreads(); }
  float inv = 1.0f / sqrtf(red[0]);
  short h, l; split2(xc*inv, h, l);
  yhi[r*128 + t] = h; ylo[r*128 + t] = l;
}

// ---------- 2. generic fp32 -> split bf16 (vectorized) ----------
__global__ __launch_bounds__(256) void k_split(const float* __restrict__ in,
                                               short* __restrict__ hi, short* __restrict__ lo) {
  int i = blockIdx.x*256 + threadIdx.x;
  float4 v = ((const float4*)in)[i];
  short4 h, l;
  split2(v.x, h.x, l.x); split2(v.y, h.y, l.y);
  split2(v.z, h.z, l.z); split2(v.w, h.w, l.w);
  ((short4*)hi)[i] = h; ((short4*)lo)[i] = l;
}

// ---------- 3. correlation bit blocks via MFMA (3-chain split) ----------
__global__ __launch_bounds__(256) void k_corr(const short* __restrict__ yhi, const short* __restrict__ ylo,
                                              const float* __restrict__ sparse, u64* __restrict__ bits) {
  int z = blockIdx.z;
  int a0 = c_pi[z]*1024 + blockIdx.x*64;
  int b0 = c_pj[z]*1024 + blockIdx.y*64;
  int tid = threadIdx.x, lane = tid & 63, wid = tid >> 6;
  int quad = lane >> 4, l15 = lane & 15;
  int arow = a0 + wid*16 + l15;
  f4v acc[4];
  #pragma unroll
  for (int i = 0; i < 4; ++i) { acc[i][0]=0.f; acc[i][1]=0.f; acc[i][2]=0.f; acc[i][3]=0.f; }
  #pragma unroll
  for (int ks = 0; ks < 4; ++ks) {
    s8v a_h = *(const s8v*)(yhi + (size_t)arow*128 + ks*32 + quad*8);
    s8v a_l = *(const s8v*)(ylo + (size_t)arow*128 + ks*32 + quad*8);
    #pragma unroll
    for (int nt = 0; nt < 4; ++nt) {
      int brow = b0 + nt*16 + l15;
      s8v b_h = *(const s8v*)(yhi + (size_t)brow*128 + ks*32 + quad*8);
      s8v b_l = *(const s8v*)(ylo + (size_t)brow*128 + ks*32 + quad*8);
      acc[nt] = __builtin_amdgcn_mfma_f32_16x16x32_bf16(a_h, b_h, acc[nt], 0, 0, 0);
      acc[nt] = __builtin_amdgcn_mfma_f32_16x16x32_bf16(a_h, b_l, acc[nt], 0, 0, 0);
      acc[nt] = __builtin_amdgcn_mfma_f32_16x16x32_bf16(a_l, b_h, acc[nt], 0, 0, 0);
    }
  }
  __shared__ unsigned char lby[64*68];
  float sv = sparse[c_dri[z]];
  float dr = 1.0f / (1.0f + expf(-sv));
  int dg = c_diag[z];
  #pragma unroll
  for (int nt = 0; nt < 4; ++nt) {
    #pragma unroll
    for (int reg = 0; reg < 4; ++reg) {
      int lr = wid*16 + quad*4 + reg;
      int lc = nt*16 + l15;
      int ga = blockIdx.x*64 + lr, gb = blockIdx.y*64 + lc;
      int on = (fabsf(acc[nt][reg]) > dr) && !(dg && (ga == gb));
      lby[lr*68 + lc] = (unsigned char)on;
    }
  }
  __syncthreads();
  if (tid < 64) {
    u64 w = 0;
    for (int c2 = 0; c2 < 64; ++c2) w |= ((u64)lby[tid*68 + c2]) << c2;
    bits[z*16384 + (blockIdx.x*64 + tid)*16 + blockIdx.y] = w;
  }
}

// ---------- 4. mask rows (boolean A@C) ----------
__global__ __launch_bounds__(64) void k_maskrows(const u64* __restrict__ bits, u64* __restrict__ mask) {
  int u = blockIdx.x;
  int i = u >> 10, a = u & 1023;
  int t = threadIdx.x;
  __shared__ u64 drow[16];
  if (t < 16) drow[t] = bits[i*16384 + a*16 + t];
  __syncthreads();
  int j = t >> 4, wl = t & 15;
  u64 out;
  if (j == i) {
    out = drow[wl];
  } else {
    const u64* S = bits + c_src[i*4 + j]*16384;
    out = 0;
    for (int w2 = 0; w2 < 16; ++w2) {
      u64 m = drow[w2];
      while (m) {
        int b = __builtin_ctzll(m); m &= m - 1;
        out |= S[(w2*64 + b)*16 + wl];
      }
    }
  }
  mask[u*64 + t] = out;
}

// ---------- 5. 64x64 bit transpose ----------
__global__ __launch_bounds__(64) void k_bittrans(const u64* __restrict__ mask, u64* __restrict__ maskT) {
  __shared__ u64 w[64];
  int t = threadIdx.x;
  int tI = blockIdx.x, tJ = blockIdx.y;
  w[t] = mask[(tI*64 + t)*64 + tJ];
  __syncthreads();
  u64 out = 0;
  for (int k = 0; k < 64; ++k) out |= ((w[k] >> t) & 1ULL) << k;
  maskT[(tJ*64 + t)*64 + tI] = out;
}

// ---------- 6. degrees -> nrm = d^-0.5, sfac = d^-1.5 ----------
__global__ __launch_bounds__(64) void k_degrees(const u64* __restrict__ rows,
                                                float* __restrict__ nrm, float* __restrict__ sfac) {
  int v = blockIdx.x, t = threadIdx.x;
  int cnt = __popcll(rows[v*64 + t]);
  for (int off = 32; off > 0; off >>= 1) cnt += __shfl_down(cnt, off);
  if (t == 0) {
    if (cnt > 0) {
      float d = (float)cnt;
      float n = 1.0f / sqrtf(d);
      nrm[v] = n; sfac[v] = n / d;
    } else { nrm[v] = 0.0f; sfac[v] = 0.0f; }
  }
}

// ---------- 7. weight prep: [Wa|Wb] (Kx256 each) -> WT hi/lo [512 x K] ----------
__global__ __launch_bounds__(256) void k_prepWT(const float* __restrict__ Wa, const float* __restrict__ Wb,
                                                short* __restrict__ wthi, short* __restrict__ wtlo, int K) {
  __shared__ float lds[64*65];
  int tid = threadIdx.x;
  int k0 = blockIdx.x*64, n0 = blockIdx.y*64;
  const float* W = (n0 < 256) ? Wa : Wb;
  int nc0 = n0 & 255;
  for (int e = tid; e < 4096; e += 256) {
    int r = e >> 6, c = e & 63;
    lds[r*65 + c] = W[(size_t)(k0+r)*256 + nc0 + c];
  }
  __syncthreads();
  for (int e = tid; e < 4096; e += 256) {
    int nl = e >> 6, kc = e & 63;
    short h, l; split2(lds[kc*65 + nl], h, l);
    size_t o = (size_t)(n0+nl)*K + k0 + kc;
    wthi[o] = h; wtlo[o] = l;
  }
}

// ---------- 8. dense GEMM: Z[4096x512] = A(split) @ WT(split), 3-chain ----------
__global__ __launch_bounds__(256) void k_dense(const short* __restrict__ ahi, const short* __restrict__ alo,
                                               const short* __restrict__ wthi, const short* __restrict__ wtlo,
                                               float* __restrict__ Z, int K) {
  int tid = threadIdx.x, lane = tid & 63, wid = tid >> 6;
  int quad = lane >> 4, l15 = lane & 15;
  int m0 = blockIdx.x*64, n0 = blockIdx.y*64;
  int arow = m0 + wid*16 + l15;
  const s8v* ah = (const s8v*)(ahi + (size_t)arow*K);
  const s8v* al = (const s8v*)(alo + (size_t)arow*K);
  f4v acc[4];
  #pragma unroll
  for (int i = 0; i < 4; ++i) { acc[i][0]=0.f; acc[i][1]=0.f; acc[i][2]=0.f; acc[i][3]=0.f; }
  int ksteps = K >> 5;
  for (int ks = 0; ks < ksteps; ++ks) {
    s8v a_h = ah[ks*4 + quad];
    s8v a_l = al[ks*4 + quad];
    #pragma unroll
    for (int nt = 0; nt < 4; ++nt) {
      int nr = n0 + nt*16 + l15;
      s8v b_h = *(const s8v*)(wthi + (size_t)nr*K + ks*32 + quad*8);
      s8v b_l = *(const s8v*)(wtlo + (size_t)nr*K + ks*32 + quad*8);
      acc[nt] = __builtin_amdgcn_mfma_f32_16x16x32_bf16(a_h, b_h, acc[nt], 0, 0, 0);
      acc[nt] = __builtin_amdgcn_mfma_f32_16x16x32_bf16(a_h, b_l, acc[nt], 0, 0, 0);
      acc[nt] = __builtin_amdgcn_mfma_f32_16x16x32_bf16(a_l, b_h, acc[nt], 0, 0, 0);
    }
  }
  #pragma unroll
  for (int nt = 0; nt < 4; ++nt) {
    #pragma unroll
    for (int reg = 0; reg < 4; ++reg) {
      int row = m0 + wid*16 + quad*4 + reg;
      int col = n0 + nt*16 + l15;
      Z[(size_t)row*512 + col] = acc[nt][reg];
    }
  }
}

// ---------- 9. B prep: BT[512 x 4096]: rows 0..255 = nrm1*Z[:,0:256]^T, 256..511 = nrm2*Z[:,256:512]^T ----------
__global__ __launch_bounds__(256) void k_prepB(const float* __restrict__ Z, const float* __restrict__ nrm1,
                                               const float* __restrict__ nrm2,
                                               short* __restrict__ bthi, short* __restrict__ btlo) {
  __shared__ float lds[64*65];
  int tid = threadIdx.x;
  int u0 = blockIdx.x*64, c0 = blockIdx.y*64;
  const float* nrm = (c0 < 256) ? nrm1 : nrm2;
  for (int e = tid; e < 4096; e += 256) {
    int r = e >> 6, c = e & 63;
    lds[r*65 + c] = Z[(size_t)(u0+r)*512 + c0 + c] * nrm[u0 + r];
  }
  __syncthreads();
  for (int e = tid; e < 4096; e += 256) {
    int cl = e >> 6, ul = e & 63;
    short h, l; split2(lds[ul*65 + cl], h, l);
    size_t o = (size_t)(c0+cl)*4096 + u0 + ul;
    bthi[o] = h; btlo[o] = l;
  }
}

// ---------- 10. mask GEMM: h[:,zoff..zoff+256) = relu(Z + sfac * (bits @ BT^T) + bias) ----------
__global__ __launch_bounds__(256) void k_maskgemm(const u64* __restrict__ bits,
                                                  const short* __restrict__ bthi, const short* __restrict__ btlo,
                                                  const float* __restrict__ Z, const float* __restrict__ sfac,
                                                  const float* __restrict__ bias,
                                                  float* __restrict__ h, int zoff) {
  __shared__ s8v lut[256];   // byte -> 8 bf16 {0,1}
  int tid = threadIdx.x;
  {
    s8v e;
    #pragma unroll
    for (int j = 0; j < 8; ++j) e[j] = ((tid >> j) & 1) ? (short)0x3F80 : (short)0;
    lut[tid] = e;
  }
  __syncthreads();
  int lane = tid & 63, wid = tid >> 6;
  int quad = lane >> 4, l15 = lane & 15;
  int m0 = blockIdx.x*64;
  int n0 = blockIdx.y*64;                 // 0..255
  int nrow = n0 + wid*16 + l15;
  const s8v* bhp = (const s8v*)(bthi + (size_t)nrow*4096);
  const s8v* blp = (const s8v*)(btlo + (size_t)nrow*4096);
  f4v acc[4];
  #pragma unroll
  for (int i = 0; i < 4; ++i) { acc[i][0]=0.f; acc[i][1]=0.f; acc[i][2]=0.f; acc[i][3]=0.f; }
  for (int kw = 0; kw < 64; ++kw) {
    u64 w0 = bits[(size_t)(m0 +  0 + l15)*64 + kw];
    u64 w1 = bits[(size_t)(m0 + 16 + l15)*64 + kw];
    u64 w2 = bits[(size_t)(m0 + 32 + l15)*64 + kw];
    u64 w3 = bits[(size_t)(m0 + 48 + l15)*64 + kw];
    int a0 = __any(w0 != 0), a1 = __any(w1 != 0), a2 = __any(w2 != 0), a3 = __any(w3 != 0);
    if (!(a0 | a1 | a2 | a3)) continue;
    #pragma unroll
    for (int half = 0; half < 2; ++half) {
      int ks = kw*2 + half;
      s8v b_h = bhp[ks*4 + quad];
      s8v b_l = blp[ks*4 + quad];
      int sh = half*32 + quad*8;
      if (a0) {
        s8v af = lut[(unsigned int)(w0 >> sh) & 0xffu];
        acc[0] = __builtin_amdgcn_mfma_f32_16x16x32_bf16(af, b_h, acc[0], 0, 0, 0);
        acc[0] = __builtin_amdgcn_mfma_f32_16x16x32_bf16(af, b_l, acc[0], 0, 0, 0);
      }
      if (a1) {
        s8v af = lut[(unsigned int)(w1 >> sh) & 0xffu];
        acc[1] = __builtin_amdgcn_mfma_f32_16x16x32_bf16(af, b_h, acc[1], 0, 0, 0);
        acc[1] = __builtin_amdgcn_mfma_f32_16x16x32_bf16(af, b_l, acc[1], 0, 0, 0);
      }
      if (a2) {
        s8v af = lut[(unsigned int)(w2 >> sh) & 0xffu];
        acc[2] = __builtin_amdgcn_mfma_f32_16x16x32_bf16(af, b_h, acc[2], 0, 0, 0);
        acc[2] = __builtin_amdgcn_mfma_f32_16x16x32_bf16(af, b_l, acc[2], 0, 0, 0);
      }
      if (a3) {
        s8v af = lut[(unsigned int)(w3 >> sh) & 0xffu];
        acc[3] = __builtin_amdgcn_mfma_f32_16x16x32_bf16(af, b_h, acc[3], 0, 0, 0);
        acc[3] = __builtin_amdgcn_mfma_f32_16x16x32_bf16(af, b_l, acc[3], 0, 0, 0);
      }
    }
  }
  int n = n0 + wid*16 + l15;
  float bn = bias[n];
  #pragma unroll
  for (int ms = 0; ms < 4; ++ms) {
    #pragma unroll
    for (int reg = 0; reg < 4; ++reg) {
      int v = m0 + ms*16 + quad*4 + reg;
      float val = Z[(size_t)v*512 + zoff + n] + sfac[v]*acc[ms][reg] + bn;
      h[(size_t)v*512 + zoff + n] = fmaxf(val, 0.0f);
    }
  }
}

// ---------- 11. BatchNorm stats (fp64) ----------
__global__ __launch_bounds__(256) void k_bnstats(const float* __restrict__ h, const float* __restrict__ gamma,
                                                 const float* __restrict__ beta, float* __restrict__ scale,
                                                 float* __restrict__ shift) {
  int col = blockIdx.x, t = threadIdx.x;
  double s = 0.0, s2 = 0.0;
  for (int r = t; r < 4096; r += 256) {
    double v = (double)h[(size_t)r*512 + col];
    s += v; s2 += v*v;
  }
  __shared__ double ls[256], ls2[256];
  ls[t] = s; ls2[t] = s2; __syncthreads();
  for (int st = 128; st > 0; st >>= 1) {
    if (t < st) { ls[t] += ls[t+st]; ls2[t] += ls2[t+st]; }
    __syncthreads();
  }
  if (t == 0) {
    double mean = ls[0] / 4096.0;
    double var = ls2[0] / 4096.0 - mean*mean;
    float inv = (float)(1.0 / sqrt(var + 1e-5));
    float sc = gamma[col] * inv;
    scale[col] = sc;
    shift[col] = beta[col] - (float)mean * sc;
  }
}

// ---------- 12. BN apply + split to bf16 hi/lo ----------
__global__ __launch_bounds__(256) void k_bnapply_split(const float* __restrict__ h, const float* __restrict__ scale,
                                                       const float* __restrict__ shift,
                                                       short* __restrict__ hnhi, short* __restrict__ hnlo) {
  int i = blockIdx.x*256 + threadIdx.x;       // 524288 float4s
  float4 v = ((const float4*)h)[i];
  float4 sc = ((const float4*)scale)[i & 127];
  float4 sh = ((const float4*)shift)[i & 127];
  short4 hh, ll;
  split2(v.x*sc.x + sh.x, hh.x, ll.x);
  split2(v.y*sc.y + sh.y, hh.y, ll.y);
  split2(v.z*sc.z + sh.z, hh.z, ll.z);
  split2(v.w*sc.w + sh.w, hh.w, ll.w);
  ((short4*)hnhi)[i] = hh; ((short4*)hnlo)[i] = ll;
}

// ---------- 13. fold BN2 into readout: w2[k][c] = scale2[k]*w_ro[k][c]; Csh[c] = sum shift2[k]*w_ro[k][c] ----------
__global__ __launch_bounds__(512) void k_mkro(const float* __restrict__ scale2, const float* __restrict__ shift2,
                                              const float* __restrict__ w_ro,
                                              float* __restrict__ w2, float* __restrict__ Csh) {
  __shared__ f4v red[512];
  int t = threadIdx.x;
  float sc = scale2[t], sh = shift2[t];
  f4v p;
  #pragma unroll
  for (int c = 0; c < 4; ++c) {
    float w = w_ro[t*4 + c];
    w2[t*4 + c] = sc * w;
    p[c] = sh * w;
  }
  red[t] = p; __syncthreads();
  for (int st = 256; st > 0; st >>= 1) {
    if (t < st) red[t] += red[t+st];
    __syncthreads();
  }
  if (t < 4) Csh[t] = red[0][t];
}

// ---------- 14. final readout + modality softmax mix ----------
__global__ __launch_bounds__(256) void k_final2(const float* __restrict__ h, const float* __restrict__ w2,
                                                const float* __restrict__ Csh, const float* __restrict__ cl,
                                                float* __restrict__ out) {
  int node = blockIdx.x;
  int t = threadIdx.x, m = t >> 6, lane = t & 63;
  const float* row = h + (size_t)(m*1024 + node)*512;
  float a0 = 0.f, a1 = 0.f, a2 = 0.f, a3 = 0.f;
  for (int it = 0; it < 8; ++it) {
    int k = lane + it*64;
    float hv = row[k];
    float4 w = ((const float4*)w2)[k];
    a0 += hv*w.x; a1 += hv*w.y; a2 += hv*w.z; a3 += hv*w.w;
  }
  for (int off = 32; off > 0; off >>= 1) {
    a0 += __shfl_down(a0, off); a1 += __shfl_down(a1, off);
    a2 += __shfl_down(a2, off); a3 += __shfl_down(a3, off);
  }
  __shared__ float part[4][4];
  if (lane == 0) { part[m][0]=a0; part[m][1]=a1; part[m][2]=a2; part[m][3]=a3; }
  __syncthreads();
  if (t < 4) {
    float c0 = cl[0], c1 = cl[1], c2 = cl[2], c3 = cl[3];
    float mx = fmaxf(fmaxf(c0,c1), fmaxf(c2,c3));
    float e0 = expf(c0-mx), e1 = expf(c1-mx), e2 = expf(c2-mx), e3 = expf(c3-mx);
    float inv = 1.0f/(e0+e1+e2+e3);
    float r = (e0*part[0][t] + e1*part[1][t] + e2*part[2][t] + e3*part[3][t]) * inv + Csh[t];
    out[node*4 + t] = r;
  }
}

extern "C" void kernel_launch(void* const* d_in, const int* in_sizes, int n_in,
                              void* d_out, int out_size, void* d_ws, size_t ws_size,
                              hipStream_t stream) {
  const float* features = (const float*)d_in[0];
  const float* sparse   = (const float*)d_in[1];
  const float* cmix     = (const float*)d_in[2];
  const float* wAC1 = (const float*)d_in[3];
  const float* bAC1 = (const float*)d_in[4];
  const float* wCA1 = (const float*)d_in[5];
  const float* bCA1 = (const float*)d_in[6];
  const float* wAC2 = (const float*)d_in[7];
  const float* bAC2 = (const float*)d_in[8];
  const float* wCA2 = (const float*)d_in[9];
  const float* bCA2 = (const float*)d_in[10];
  const float* gamma1 = (const float*)d_in[11];
  const float* beta1  = (const float*)d_in[12];
  const float* gamma2 = (const float*)d_in[13];
  const float* beta2  = (const float*)d_in[14];
  const float* w_ro   = (const float*)d_in[15];
  float* out = (float*)d_out;

  char* ws = (char*)d_ws;
  const size_t MB = 1024ull*1024ull, KB = 1024ull;
  u64*   bits  = (u64*)(ws + 0);                 // 1.25 MB
  u64*   mask  = (u64*)(ws + 2*MB);              // 2 MB
  u64*   maskT = (u64*)(ws + 4*MB);              // 2 MB
  float* nrm1  = (float*)(ws + 6*MB);
  float* sfac1 = (float*)(ws + 6*MB + 64*KB);
  float* nrm2  = (float*)(ws + 6*MB + 128*KB);
  float* sfac2 = (float*)(ws + 6*MB + 192*KB);
  float* scale1= (float*)(ws + 6*MB + 256*KB);
  float* shift1= (float*)(ws + 6*MB + 260*KB);
  float* scale2= (float*)(ws + 6*MB + 264*KB);
  float* shift2= (float*)(ws + 6*MB + 268*KB);
  float* Csh   = (float*)(ws + 6*MB + 272*KB);
  float* w2ro  = (float*)(ws + 6*MB + 276*KB);
  short* WT1hi = (short*)(ws + 6*MB + 512*KB);   // 128 KB
  short* WT1lo = (short*)(ws + 6*MB + 640*KB);   // 128 KB
  short* WT2hi = (short*)(ws + 6*MB + 768*KB);   // 512 KB
  short* WT2lo = (short*)(ws + 6*MB + 1280*KB);  // 512 KB
  // multi-use region [8MB, 16MB+2MB):
  short* yhi   = (short*)(ws + 8*MB);            // 1 MB  (dead after k_corr)
  short* ylo   = (short*)(ws + 9*MB);            // 1 MB
  short* fhi   = (short*)(ws + 16*MB);           // 1 MB  (dead after Z1 GEMM)
  short* flo   = (short*)(ws + 17*MB);           // 1 MB
  short* BThi  = (short*)(ws + 8*MB);            // 4 MB  (written by prepB after prior users dead)
  short* BTlo  = (short*)(ws + 12*MB);           // 4 MB
  short* hnhi  = (short*)(ws + 8*MB);            // 4 MB  (after L1 maskgemms; overwritten by L2 prepB after Z2)
  short* hnlo  = (short*)(ws + 12*MB);           // 4 MB
  float* Z     = (float*)(ws + 18*MB);           // 8 MB
  float* h     = (float*)(ws + 26*MB);           // 8 MB  (total 34 MB)

  // graph prep
  k_rownorm<<<dim3(4096), dim3(128), 0, stream>>>(features, yhi, ylo);
  k_split<<<dim3(512), dim3(256), 0, stream>>>(features, fhi, flo);   // 4096*128/4 = 131072 f4
  k_corr<<<dim3(16,16,10), dim3(256), 0, stream>>>(yhi, ylo, sparse, bits);
  k_maskrows<<<dim3(4096), dim3(64), 0, stream>>>(bits, mask);
  k_bittrans<<<dim3(64,64), dim3(64), 0, stream>>>(mask, maskT);
  k_degrees<<<dim3(4096), dim3(64), 0, stream>>>(mask,  nrm2, sfac2);
  k_degrees<<<dim3(4096), dim3(64), 0, stream>>>(maskT, nrm1, sfac1);
  k_prepWT<<<dim3(2,8), dim3(256), 0, stream>>>(wAC1, wCA1, WT1hi, WT1lo, 128);
  k_prepWT<<<dim3(8,8), dim3(256), 0, stream>>>(wAC2, wCA2, WT2hi, WT2lo, 512);

  // layer 1 (reassociated: h = relu(Z + sfac*(bits@(nrm*Z)) + b))
  k_dense<<<dim3(64,8), dim3(256), 0, stream>>>(fhi, flo, WT1hi, WT1lo, Z, 128);
  k_prepB<<<dim3(64,8), dim3(256), 0, stream>>>(Z, nrm1, nrm2, BThi, BTlo);
  k_maskgemm<<<dim3(64,4), dim3(256), 0, stream>>>(maskT, BThi, BTlo, Z, sfac1, bAC1, h, 0);
  k_maskgemm<<<dim3(64,4), dim3(256), 0, stream>>>(mask,  BThi + 256*4096, BTlo + 256*4096, Z, sfac2, bCA1, h, 256);
  k_bnstats<<<dim3(512), dim3(256), 0, stream>>>(h, gamma1, beta1, scale1, shift1);
  k_bnapply_split<<<dim3(2048), dim3(256), 0, stream>>>(h, scale1, shift1, hnhi, hnlo);

  // layer 2
  k_dense<<<dim3(64,8), dim3(256), 0, stream>>>(hnhi, hnlo, WT2hi, WT2lo, Z, 512);
  k_prepB<<<dim3(64,8), dim3(256), 0, stream>>>(Z, nrm1, nrm2, BThi, BTlo);
  k_maskgemm<<<dim3(64,4), dim3(256), 0, stream>>>(maskT, BThi, BTlo, Z, sfac1, bAC2, h, 0);
  k_maskgemm<<<dim3(64,4), dim3(256), 0, stream>>>(mask,  BThi + 256*4096, BTlo + 256*4096, Z, sfac2, bCA2, h, 256);
  k_bnstats<<<dim3(512), dim3(256), 0, stream>>>(h, gamma2, beta2, scale2, shift2);

  // readout (BN2 folded into weights)
  k_mkro<<<dim3(1), dim3(512), 0, stream>>>(scale2, shift2, w_ro, w2ro, Csh);
  k_final2<<<dim3(1024), dim3(256), 0, stream>>>(h, w2ro, Csh, cmix, out);
}

// Round 3
// 495.214 us; speedup vs baseline: 1.2938x; 1.0971x over previous
//
#include <hip/hip_runtime.h>

typedef unsigned long long u64;
typedef __attribute__((ext_vector_type(8))) short s8v;   // 8 bf16 = 4 VGPRs (MFMA A/B frag)
typedef __attribute__((ext_vector_type(4))) float f4v;   // MFMA C/D frag

__device__ __constant__ int c_pi[10]   = {0,1,2,3,0,1,2,3,3,3};
__device__ __constant__ int c_pj[10]   = {0,1,2,3,3,3,3,0,1,2};
__device__ __constant__ int c_dri[10]  = {1,5,8,10,4,7,9,4,7,9};
__device__ __constant__ int c_diag[10] = {1,1,1,1,0,0,0,0,0,0};
__device__ __constant__ int c_src[16]  = {-1,7,8,9,  4,-1,8,9,  5,5,-1,9,  6,6,6,-1};

// round-to-nearest bf16
__device__ inline unsigned short bf16rn(float v) {
  unsigned int u = __float_as_uint(v);
  unsigned int r = u + 0x7fffu + ((u >> 16) & 1u);
  return (unsigned short)(r >> 16);
}
// 2-way RN split: v ~= h + l, residual ~2^-18 |v|
__device__ inline void split2(float v, short& h, short& l) {
  unsigned short hs = bf16rn(v);
  float fh = __uint_as_float(((unsigned int)hs) << 16);
  h = (short)hs;
  l = (short)bf16rn(v - fh);
}
// 3-way RN split: v ~= h + m + l, residual ~2^-27 |v|
__device__ inline void split3(float v, short& h, short& m, short& l) {
  unsigned short hs = bf16rn(v);
  float fh = __uint_as_float(((unsigned int)hs) << 16);
  float r1 = v - fh;                       // exact
  unsigned short ms = bf16rn(r1);
  float fm = __uint_as_float(((unsigned int)ms) << 16);
  h = (short)hs; m = (short)ms;
  l = (short)bf16rn(r1 - fm);              // r1-fm exact
}

// ---------- 1. center+normalize rows -> y 3-split; also feature 2-split ----------
__global__ __launch_bounds__(128) void k_rownorm(const float* __restrict__ f,
                                                 short* __restrict__ yh, short* __restrict__ ym,
                                                 short* __restrict__ yl,
                                                 short* __restrict__ fhi, short* __restrict__ flo) {
  int r = blockIdx.x, t = threadIdx.x;
  __shared__ float red[128];
  float v = f[r*128 + t];
  red[t] = v; __syncthreads();
  for (int s = 64; s > 0; s >>= 1) { if (t < s) red[t] += red[t+s]; __syncthreads(); }
  float mean = red[0] * (1.0f/128.0f);
  __syncthreads();
  float xc = v - mean;
  red[t] = xc*xc; __syncthreads();
  for (int s = 64; s > 0; s >>= 1) { if (t < s) red[t] += red[t+s]; __syncthreads(); }
  float inv = 1.0f / sqrtf(red[0]);
  short a, b, c;
  split3(xc*inv, a, b, c);
  yh[r*128 + t] = a; ym[r*128 + t] = b; yl[r*128 + t] = c;
  short fh, fl; split2(v, fh, fl);
  fhi[r*128 + t] = fh; flo[r*128 + t] = fl;
}

// ---------- 2. correlation bit blocks via MFMA, 6-chain (fp32-accurate) ----------
__global__ __launch_bounds__(256) void k_corr(const short* __restrict__ yh, const short* __restrict__ ym,
                                              const short* __restrict__ yl,
                                              const float* __restrict__ sparse, u64* __restrict__ bits) {
  int z = blockIdx.z;
  int a0 = c_pi[z]*1024 + blockIdx.x*64;
  int b0 = c_pj[z]*1024 + blockIdx.y*64;
  int tid = threadIdx.x, lane = tid & 63, wid = tid >> 6;
  int quad = lane >> 4, l15 = lane & 15;
  int arow = a0 + wid*16 + l15;
  f4v acc[4];
  #pragma unroll
  for (int i = 0; i < 4; ++i) { acc[i][0]=0.f; acc[i][1]=0.f; acc[i][2]=0.f; acc[i][3]=0.f; }
  #pragma unroll
  for (int ks = 0; ks < 4; ++ks) {
    size_t ao = (size_t)arow*128 + ks*32 + quad*8;
    s8v a_h = *(const s8v*)(yh + ao);
    s8v a_m = *(const s8v*)(ym + ao);
    s8v a_l = *(const s8v*)(yl + ao);
    #pragma unroll
    for (int nt = 0; nt < 4; ++nt) {
      size_t bo = (size_t)(b0 + nt*16 + l15)*128 + ks*32 + quad*8;
      s8v b_h = *(const s8v*)(yh + bo);
      s8v b_m = *(const s8v*)(ym + bo);
      s8v b_l = *(const s8v*)(yl + bo);
      acc[nt] = __builtin_amdgcn_mfma_f32_16x16x32_bf16(a_h, b_h, acc[nt], 0, 0, 0);
      acc[nt] = __builtin_amdgcn_mfma_f32_16x16x32_bf16(a_h, b_m, acc[nt], 0, 0, 0);
      acc[nt] = __builtin_amdgcn_mfma_f32_16x16x32_bf16(a_m, b_h, acc[nt], 0, 0, 0);
      acc[nt] = __builtin_amdgcn_mfma_f32_16x16x32_bf16(a_m, b_m, acc[nt], 0, 0, 0);
      acc[nt] = __builtin_amdgcn_mfma_f32_16x16x32_bf16(a_h, b_l, acc[nt], 0, 0, 0);
      acc[nt] = __builtin_amdgcn_mfma_f32_16x16x32_bf16(a_l, b_h, acc[nt], 0, 0, 0);
    }
  }
  __shared__ unsigned char lby[64*68];
  float sv = sparse[c_dri[z]];
  float dr = 1.0f / (1.0f + expf(-sv));
  int dg = c_diag[z];
  #pragma unroll
  for (int nt = 0; nt < 4; ++nt) {
    #pragma unroll
    for (int reg = 0; reg < 4; ++reg) {
      int lr = wid*16 + quad*4 + reg;
      int lc = nt*16 + l15;
      int ga = blockIdx.x*64 + lr, gb = blockIdx.y*64 + lc;
      int on = (fabsf(acc[nt][reg]) > dr) && !(dg && (ga == gb));
      lby[lr*68 + lc] = (unsigned char)on;
    }
  }
  __syncthreads();
  if (tid < 64) {
    u64 w = 0;
    for (int c2 = 0; c2 < 64; ++c2) w |= ((u64)lby[tid*68 + c2]) << c2;
    bits[z*16384 + (blockIdx.x*64 + tid)*16 + blockIdx.y] = w;
  }
}

// ---------- 3. mask rows (boolean A@C) + fused graph-2 degrees ----------
__global__ __launch_bounds__(64) void k_maskrows(const u64* __restrict__ bits, u64* __restrict__ mask,
                                                 float* __restrict__ nrm2, float* __restrict__ sfac2) {
  int u = blockIdx.x;
  int i = u >> 10, a = u & 1023;
  int t = threadIdx.x;
  __shared__ u64 drow[16];
  if (t < 16) drow[t] = bits[i*16384 + a*16 + t];
  __syncthreads();
  int j = t >> 4, wl = t & 15;
  u64 out;
  if (j == i) {
    out = drow[wl];
  } else {
    const u64* S = bits + c_src[i*4 + j]*16384;
    out = 0;
    for (int w2 = 0; w2 < 16; ++w2) {
      u64 m = drow[w2];
      while (m) {
        int b = __builtin_ctzll(m); m &= m - 1;
        out |= S[(w2*64 + b)*16 + wl];
      }
    }
  }
  mask[u*64 + t] = out;
  int cnt = __popcll(out);
  for (int off = 32; off > 0; off >>= 1) cnt += __shfl_down(cnt, off);
  if (t == 0) {
    if (cnt > 0) {
      float d = (float)cnt;
      float n = 1.0f / sqrtf(d);
      nrm2[u] = n; sfac2[u] = n / d;
    } else { nrm2[u] = 0.0f; sfac2[u] = 0.0f; }
  }
}

// ---------- 4. 64x64 bit transpose ----------
__global__ __launch_bounds__(64) void k_bittrans(const u64* __restrict__ mask, u64* __restrict__ maskT) {
  __shared__ u64 w[64];
  int t = threadIdx.x;
  int tI = blockIdx.x, tJ = blockIdx.y;
  w[t] = mask[(tI*64 + t)*64 + tJ];
  __syncthreads();
  u64 out = 0;
  for (int k = 0; k < 64; ++k) out |= ((w[k] >> t) & 1ULL) << k;
  maskT[(tJ*64 + t)*64 + tI] = out;
}

// ---------- 5. degrees for maskT ----------
__global__ __launch_bounds__(64) void k_degrees(const u64* __restrict__ rows,
                                                float* __restrict__ nrm, float* __restrict__ sfac) {
  int v = blockIdx.x, t = threadIdx.x;
  int cnt = __popcll(rows[v*64 + t]);
  for (int off = 32; off > 0; off >>= 1) cnt += __shfl_down(cnt, off);
  if (t == 0) {
    if (cnt > 0) {
      float d = (float)cnt;
      float n = 1.0f / sqrtf(d);
      nrm[v] = n; sfac[v] = n / d;
    } else { nrm[v] = 0.0f; sfac[v] = 0.0f; }
  }
}

// ---------- 6. weight prep: [Wa|Wb] (Kx256 each) -> WT hi/lo [512 x K] ----------
__global__ __launch_bounds__(256) void k_prepWT(const float* __restrict__ Wa, const float* __restrict__ Wb,
                                                short* __restrict__ wthi, short* __restrict__ wtlo, int K) {
  __shared__ float lds[64*65];
  int tid = threadIdx.x;
  int k0 = blockIdx.x*64, n0 = blockIdx.y*64;
  const float* W = (n0 < 256) ? Wa : Wb;
  int nc0 = n0 & 255;
  for (int e = tid; e < 4096; e += 256) {
    int r = e >> 6, c = e & 63;
    lds[r*65 + c] = W[(size_t)(k0+r)*256 + nc0 + c];
  }
  __syncthreads();
  for (int e = tid; e < 4096; e += 256) {
    int nl = e >> 6, kc = e & 63;
    short h, l; split2(lds[kc*65 + nl], h, l);
    size_t o = (size_t)(n0+nl)*K + k0 + kc;
    wthi[o] = h; wtlo[o] = l;
  }
}

// ---------- 7. dense GEMM: Z[4096x512] = A(split) @ WT(split), 3-chain ----------
__global__ __launch_bounds__(256) void k_dense(const short* __restrict__ ahi, const short* __restrict__ alo,
                                               const short* __restrict__ wthi, const short* __restrict__ wtlo,
                                               float* __restrict__ Z, int K) {
  int tid = threadIdx.x, lane = tid & 63, wid = tid >> 6;
  int quad = lane >> 4, l15 = lane & 15;
  int m0 = blockIdx.x*64, n0 = blockIdx.y*64;
  int arow = m0 + wid*16 + l15;
  const s8v* ah = (const s8v*)(ahi + (size_t)arow*K);
  const s8v* al = (const s8v*)(alo + (size_t)arow*K);
  f4v acc[4];
  #pragma unroll
  for (int i = 0; i < 4; ++i) { acc[i][0]=0.f; acc[i][1]=0.f; acc[i][2]=0.f; acc[i][3]=0.f; }
  int ksteps = K >> 5;
  for (int ks = 0; ks < ksteps; ++ks) {
    s8v a_h = ah[ks*4 + quad];
    s8v a_l = al[ks*4 + quad];
    #pragma unroll
    for (int nt = 0; nt < 4; ++nt) {
      int nr = n0 + nt*16 + l15;
      s8v b_h = *(const s8v*)(wthi + (size_t)nr*K + ks*32 + quad*8);
      s8v b_l = *(const s8v*)(wtlo + (size_t)nr*K + ks*32 + quad*8);
      acc[nt] = __builtin_amdgcn_mfma_f32_16x16x32_bf16(a_h, b_h, acc[nt], 0, 0, 0);
      acc[nt] = __builtin_amdgcn_mfma_f32_16x16x32_bf16(a_h, b_l, acc[nt], 0, 0, 0);
      acc[nt] = __builtin_amdgcn_mfma_f32_16x16x32_bf16(a_l, b_h, acc[nt], 0, 0, 0);
    }
  }
  #pragma unroll
  for (int nt = 0; nt < 4; ++nt) {
    #pragma unroll
    for (int reg = 0; reg < 4; ++reg) {
      int row = m0 + wid*16 + quad*4 + reg;
      int col = n0 + nt*16 + l15;
      Z[(size_t)row*512 + col] = acc[nt][reg];
    }
  }
}

// ---------- 8. B prep: BT[512 x 4096] rows 0..255 = (nrm1*Z[:,0:256])^T, 256.. = (nrm2*Z[:,256:512])^T ----------
__global__ __launch_bounds__(256) void k_prepB(const float* __restrict__ Z, const float* __restrict__ nrm1,
                                               const float* __restrict__ nrm2,
                                               short* __restrict__ bthi, short* __restrict__ btlo) {
  __shared__ float lds[64*65];
  int tid = threadIdx.x;
  int u0 = blockIdx.x*64, c0 = blockIdx.y*64;
  const float* nrm = (c0 < 256) ? nrm1 : nrm2;
  for (int e = tid; e < 4096; e += 256) {
    int r = e >> 6, c = e & 63;
    lds[r*65 + c] = Z[(size_t)(u0+r)*512 + c0 + c] * nrm[u0 + r];
  }
  __syncthreads();
  for (int e = tid; e < 4096; e += 256) {
    int cl = e >> 6, ul = e & 63;
    short h, l; split2(lds[ul*65 + cl], h, l);
    size_t o = (size_t)(c0+cl)*4096 + u0 + ul;
    bthi[o] = h; btlo[o] = l;
  }
}

// ---------- 9. fused mask GEMM, both graphs, in-block K-split (8 waves) ----------
// h[:, g*256 + n] = relu(Z[:, g*256+n] + sfac_g[v]*(bits_g @ BT_g)[v][n] + bias_g[n])
__global__ __launch_bounds__(512) void k_mg(const u64* __restrict__ bitsT, const u64* __restrict__ bitsR,
                                            const short* __restrict__ bthi, const short* __restrict__ btlo,
                                            const float* __restrict__ Z,
                                            const float* __restrict__ sfac1, const float* __restrict__ sfac2,
                                            const float* __restrict__ biasA, const float* __restrict__ biasB,
                                            float* __restrict__ h) {
  __shared__ s8v lut[256];                 // byte -> 8 bf16 {0,1}
  __shared__ float tile[64*65];
  int tid = threadIdx.x;
  if (tid < 256) {
    s8v e;
    #pragma unroll
    for (int j = 0; j < 8; ++j) e[j] = ((tid >> j) & 1) ? (short)0x3F80 : (short)0;
    lut[tid] = e;
  }
  __syncthreads();
  int g = blockIdx.z;
  const u64* rows = g ? bitsR : bitsT;
  const float* sfac = g ? sfac2 : sfac1;
  const float* bias = g ? biasB : biasA;
  int lane = tid & 63, wid = tid >> 6;
  int quad = lane >> 4, l15 = lane & 15;
  int ks = wid >> 2, nw = wid & 3;        // ks: K-half, nw: n-subtile
  int m0 = blockIdx.x*64;
  int n0 = blockIdx.y*64;                 // 0..255 within the graph's half
  int nrowg = g*256 + n0 + nw*16 + l15;
  const short* bh = bthi + (size_t)nrowg*4096;
  const short* bl = btlo + (size_t)nrowg*4096;
  f4v acc[4];
  #pragma unroll
  for (int i = 0; i < 4; ++i) { acc[i][0]=0.f; acc[i][1]=0.f; acc[i][2]=0.f; acc[i][3]=0.f; }
  int kw0 = ks*32;
  for (int kw = kw0; kw < kw0 + 32; ++kw) {
    u64 w0 = rows[(size_t)(m0 +  0 + l15)*64 + kw];
    u64 w1 = rows[(size_t)(m0 + 16 + l15)*64 + kw];
    u64 w2 = rows[(size_t)(m0 + 32 + l15)*64 + kw];
    u64 w3 = rows[(size_t)(m0 + 48 + l15)*64 + kw];
    int a0 = __any(w0 != 0), a1 = __any(w1 != 0), a2 = __any(w2 != 0), a3 = __any(w3 != 0);
    if (!(a0 | a1 | a2 | a3)) continue;
    #pragma unroll
    for (int half = 0; half < 2; ++half) {
      s8v b_h = *(const s8v*)(bh + kw*64 + half*32 + quad*8);
      s8v b_l = *(const s8v*)(bl + kw*64 + half*32 + quad*8);
      int sh = half*32 + quad*8;
      if (a0) {
        s8v af = lut[(unsigned int)(w0 >> sh) & 0xffu];
        acc[0] = __builtin_amdgcn_mfma_f32_16x16x32_bf16(af, b_h, acc[0], 0, 0, 0);
        acc[0] = __builtin_amdgcn_mfma_f32_16x16x32_bf16(af, b_l, acc[0], 0, 0, 0);
      }
      if (a1) {
        s8v af = lut[(unsigned int)(w1 >> sh) & 0xffu];
        acc[1] = __builtin_amdgcn_mfma_f32_16x16x32_bf16(af, b_h, acc[1], 0, 0, 0);
        acc[1] = __builtin_amdgcn_mfma_f32_16x16x32_bf16(af, b_l, acc[1], 0, 0, 0);
      }
      if (a2) {
        s8v af = lut[(unsigned int)(w2 >> sh) & 0xffu];
        acc[2] = __builtin_amdgcn_mfma_f32_16x16x32_bf16(af, b_h, acc[2], 0, 0, 0);
        acc[2] = __builtin_amdgcn_mfma_f32_16x16x32_bf16(af, b_l, acc[2], 0, 0, 0);
      }
      if (a3) {
        s8v af = lut[(unsigned int)(w3 >> sh) & 0xffu];
        acc[3] = __builtin_amdgcn_mfma_f32_16x16x32_bf16(af, b_h, acc[3], 0, 0, 0);
        acc[3] = __builtin_amdgcn_mfma_f32_16x16x32_bf16(af, b_l, acc[3], 0, 0, 0);
      }
    }
  }
  // combine the two K-halves through LDS, epilogue by ks==0 waves
  int nl = nw*16 + l15;
  if (ks == 1) {
    #pragma unroll
    for (int ms = 0; ms < 4; ++ms) {
      #pragma unroll
      for (int reg = 0; reg < 4; ++reg)
        tile[(ms*16 + quad*4 + reg)*65 + nl] = acc[ms][reg];
    }
  }
  __syncthreads();
  if (ks == 0) {
    int n = n0 + nl;
    float bn = bias[n];
    int zoff = g*256;
    #pragma unroll
    for (int ms = 0; ms < 4; ++ms) {
      #pragma unroll
      for (int reg = 0; reg < 4; ++reg) {
        int v = m0 + ms*16 + quad*4 + reg;
        float s = acc[ms][reg] + tile[(ms*16 + quad*4 + reg)*65 + nl];
        float val = Z[(size_t)v*512 + zoff + n] + sfac[v]*s + bn;
        h[(size_t)v*512 + zoff + n] = fmaxf(val, 0.0f);
      }
    }
  }
}

// ---------- 10. BatchNorm stats (fp64) ----------
__global__ __launch_bounds__(256) void k_bnstats(const float* __restrict__ h, const float* __restrict__ gamma,
                                                 const float* __restrict__ beta, float* __restrict__ scale,
                                                 float* __restrict__ shift) {
  int col = blockIdx.x, t = threadIdx.x;
  double s = 0.0, s2 = 0.0;
  for (int r = t; r < 4096; r += 256) {
    double v = (double)h[(size_t)r*512 + col];
    s += v; s2 += v*v;
  }
  __shared__ double ls[256], ls2[256];
  ls[t] = s; ls2[t] = s2; __syncthreads();
  for (int st = 128; st > 0; st >>= 1) {
    if (t < st) { ls[t] += ls[t+st]; ls2[t] += ls2[t+st]; }
    __syncthreads();
  }
  if (t == 0) {
    double mean = ls[0] / 4096.0;
    double var = ls2[0] / 4096.0 - mean*mean;
    float inv = (float)(1.0 / sqrt(var + 1e-5));
    float sc = gamma[col] * inv;
    scale[col] = sc;
    shift[col] = beta[col] - (float)mean * sc;
  }
}

// ---------- 11. BN apply + split to bf16 hi/lo ----------
__global__ __launch_bounds__(256) void k_bnapply_split(const float* __restrict__ h, const float* __restrict__ scale,
                                                       const float* __restrict__ shift,
                                                       short* __restrict__ hnhi, short* __restrict__ hnlo) {
  int i = blockIdx.x*256 + threadIdx.x;       // 524288 float4s
  float4 v = ((const float4*)h)[i];
  float4 sc = ((const float4*)scale)[i & 127];
  float4 sh = ((const float4*)shift)[i & 127];
  short4 hh, ll;
  split2(v.x*sc.x + sh.x, hh.x, ll.x);
  split2(v.y*sc.y + sh.y, hh.y, ll.y);
  split2(v.z*sc.z + sh.z, hh.z, ll.z);
  split2(v.w*sc.w + sh.w, hh.w, ll.w);
  ((short4*)hnhi)[i] = hh; ((short4*)hnlo)[i] = ll;
}

// ---------- 12. fold BN2 into readout weights ----------
__global__ __launch_bounds__(512) void k_mkro(const float* __restrict__ scale2, const float* __restrict__ shift2,
                                              const float* __restrict__ w_ro,
                                              float* __restrict__ w2, float* __restrict__ Csh) {
  __shared__ f4v red[512];
  int t = threadIdx.x;
  float sc = scale2[t], sh = shift2[t];
  f4v p;
  #pragma unroll
  for (int c = 0; c < 4; ++c) {
    float w = w_ro[t*4 + c];
    w2[t*4 + c] = sc * w;
    p[c] = sh * w;
  }
  red[t] = p; __syncthreads();
  for (int st = 256; st > 0; st >>= 1) {
    if (t < st) red[t] += red[t+st];
    __syncthreads();
  }
  if (t < 4) Csh[t] = red[0][t];
}

// ---------- 13. final readout + modality softmax mix ----------
__global__ __launch_bounds__(256) void k_final2(const float* __restrict__ h, const float* __restrict__ w2,
                                                const float* __restrict__ Csh, const float* __restrict__ cl,
                                                float* __restrict__ out) {
  int node = blockIdx.x;
  int t = threadIdx.x, m = t >> 6, lane = t & 63;
  const float* row = h + (size_t)(m*1024 + node)*512;
  float a0 = 0.f, a1 = 0.f, a2 = 0.f, a3 = 0.f;
  for (int it = 0; it < 8; ++it) {
    int k = lane + it*64;
    float hv = row[k];
    float4 w = ((const float4*)w2)[k];
    a0 += hv*w.x; a1 += hv*w.y; a2 += hv*w.z; a3 += hv*w.w;
  }
  for (int off = 32; off > 0; off >>= 1) {
    a0 += __shfl_down(a0, off); a1 += __shfl_down(a1, off);
    a2 += __shfl_down(a2, off); a3 += __shfl_down(a3, off);
  }
  __shared__ float part[4][4];
  if (lane == 0) { part[m][0]=a0; part[m][1]=a1; part[m][2]=a2; part[m][3]=a3; }
  __syncthreads();
  if (t < 4) {
    float c0 = cl[0], c1 = cl[1], c2 = cl[2], c3 = cl[3];
    float mx = fmaxf(fmaxf(c0,c1), fmaxf(c2,c3));
    float e0 = expf(c0-mx), e1 = expf(c1-mx), e2 = expf(c2-mx), e3 = expf(c3-mx);
    float inv = 1.0f/(e0+e1+e2+e3);
    float r = (e0*part[0][t] + e1*part[1][t] + e2*part[2][t] + e3*part[3][t]) * inv + Csh[t];
    out[node*4 + t] = r;
  }
}

extern "C" void kernel_launch(void* const* d_in, const int* in_sizes, int n_in,
                              void* d_out, int out_size, void* d_ws, size_t ws_size,
                              hipStream_t stream) {
  const float* features = (const float*)d_in[0];
  const float* sparse   = (const float*)d_in[1];
  const float* cmix     = (const float*)d_in[2];
  const float* wAC1 = (const float*)d_in[3];
  const float* bAC1 = (const float*)d_in[4];
  const float* wCA1 = (const float*)d_in[5];
  const float* bCA1 = (const float*)d_in[6];
  const float* wAC2 = (const float*)d_in[7];
  const float* bAC2 = (const float*)d_in[8];
  const float* wCA2 = (const float*)d_in[9];
  const float* bCA2 = (const float*)d_in[10];
  const float* gamma1 = (const float*)d_in[11];
  const float* beta1  = (const float*)d_in[12];
  const float* gamma2 = (const float*)d_in[13];
  const float* beta2  = (const float*)d_in[14];
  const float* w_ro   = (const float*)d_in[15];
  float* out = (float*)d_out;

  char* ws = (char*)d_ws;
  const size_t MB = 1024ull*1024ull, KB = 1024ull;
  u64*   bits  = (u64*)(ws + 0);                 // 1.25 MB
  u64*   mask  = (u64*)(ws + 2*MB);              // 2 MB
  u64*   maskT = (u64*)(ws + 4*MB);              // 2 MB
  float* nrm1  = (float*)(ws + 6*MB);
  float* sfac1 = (float*)(ws + 6*MB + 64*KB);
  float* nrm2  = (float*)(ws + 6*MB + 128*KB);
  float* sfac2 = (float*)(ws + 6*MB + 192*KB);
  float* scale1= (float*)(ws + 6*MB + 256*KB);
  float* shift1= (float*)(ws + 6*MB + 260*KB);
  float* scale2= (float*)(ws + 6*MB + 264*KB);
  float* shift2= (float*)(ws + 6*MB + 268*KB);
  float* Csh   = (float*)(ws + 6*MB + 272*KB);
  float* w2ro  = (float*)(ws + 6*MB + 276*KB);
  short* WT1hi = (short*)(ws + 6*MB + 512*KB);   // 128 KB
  short* WT1lo = (short*)(ws + 6*MB + 640*KB);   // 128 KB
  short* WT2hi = (short*)(ws + 6*MB + 768*KB);   // 512 KB
  short* WT2lo = (short*)(ws + 6*MB + 1280*KB);  // 512 KB
  // region [8MB,16MB): yh/ym/yl (dead after corr) -> BThi/BTlo -> hnhi/hnlo -> BThi/BTlo (L2)
  short* yh    = (short*)(ws + 8*MB);            // 1 MB
  short* ym    = (short*)(ws + 9*MB);            // 1 MB
  short* yl    = (short*)(ws + 10*MB);           // 1 MB
  short* BThi  = (short*)(ws + 8*MB);            // 4 MB
  short* BTlo  = (short*)(ws + 12*MB);           // 4 MB
  short* hnhi  = (short*)(ws + 8*MB);            // 4 MB
  short* hnlo  = (short*)(ws + 12*MB);           // 4 MB
  short* fhi   = (short*)(ws + 16*MB);           // 1 MB (dead after L1 dense)
  short* flo   = (short*)(ws + 17*MB);           // 1 MB
  float* Z     = (float*)(ws + 18*MB);           // 8 MB
  float* h     = (float*)(ws + 26*MB);           // 8 MB (total 34 MB)

  // graph prep
  k_rownorm<<<dim3(4096), dim3(128), 0, stream>>>(features, yh, ym, yl, fhi, flo);
  k_corr<<<dim3(16,16,10), dim3(256), 0, stream>>>(yh, ym, yl, sparse, bits);
  k_maskrows<<<dim3(4096), dim3(64), 0, stream>>>(bits, mask, nrm2, sfac2);
  k_bittrans<<<dim3(64,64), dim3(64), 0, stream>>>(mask, maskT);
  k_degrees<<<dim3(4096), dim3(64), 0, stream>>>(maskT, nrm1, sfac1);
  k_prepWT<<<dim3(2,8), dim3(256), 0, stream>>>(wAC1, wCA1, WT1hi, WT1lo, 128);
  k_prepWT<<<dim3(8,8), dim3(256), 0, stream>>>(wAC2, wCA2, WT2hi, WT2lo, 512);

  // layer 1:  h = relu(Z + sfac*(bits @ (nrm*Z)) + b)
  k_dense<<<dim3(64,8), dim3(256), 0, stream>>>(fhi, flo, WT1hi, WT1lo, Z, 128);
  k_prepB<<<dim3(64,8), dim3(256), 0, stream>>>(Z, nrm1, nrm2, BThi, BTlo);
  k_mg<<<dim3(64,4,2), dim3(512), 0, stream>>>(maskT, mask, BThi, BTlo, Z, sfac1, sfac2, bAC1, bCA1, h);
  k_bnstats<<<dim3(512), dim3(256), 0, stream>>>(h, gamma1, beta1, scale1, shift1);
  k_bnapply_split<<<dim3(2048), dim3(256), 0, stream>>>(h, scale1, shift1, hnhi, hnlo);

  // layer 2
  k_dense<<<dim3(64,8), dim3(256), 0, stream>>>(hnhi, hnlo, WT2hi, WT2lo, Z, 512);
  k_prepB<<<dim3(64,8), dim3(256), 0, stream>>>(Z, nrm1, nrm2, BThi, BTlo);
  k_mg<<<dim3(64,4,2), dim3(512), 0, stream>>>(maskT, mask, BThi, BTlo, Z, sfac1, sfac2, bAC2, bCA2, h);
  k_bnstats<<<dim3(512), dim3(256), 0, stream>>>(h, gamma2, beta2, scale2, shift2);

  // readout (BN2 folded)
  k_mkro<<<dim3(1), dim3(512), 0, stream>>>(scale2, shift2, w_ro, w2ro, Csh);
  k_final2<<<dim3(1024), dim3(256), 0, stream>>>(h, w2ro, Csh, cmix, out);
}

// Round 4
// 444.327 us; speedup vs baseline: 1.4420x; 1.1145x over previous
//
#include <hip/hip_runtime.h>

typedef unsigned long long u64;
typedef __attribute__((ext_vector_type(8))) short s8v;   // 8 bf16 = 4 VGPRs (MFMA A/B frag)
typedef __attribute__((ext_vector_type(4))) float f4v;   // MFMA C/D frag

__device__ __constant__ int c_pi[10]   = {0,1,2,3,0,1,2,3,3,3};
__device__ __constant__ int c_pj[10]   = {0,1,2,3,3,3,3,0,1,2};
__device__ __constant__ int c_dri[10]  = {1,5,8,10,4,7,9,4,7,9};
__device__ __constant__ int c_diag[10] = {1,1,1,1,0,0,0,0,0,0};
__device__ __constant__ int c_src[16]  = {-1,7,8,9,  4,-1,8,9,  5,5,-1,9,  6,6,6,-1};

// round-to-nearest bf16
__device__ inline unsigned short bf16rn(float v) {
  unsigned int u = __float_as_uint(v);
  unsigned int r = u + 0x7fffu + ((u >> 16) & 1u);
  return (unsigned short)(r >> 16);
}
__device__ inline void split2(float v, short& h, short& l) {
  unsigned short hs = bf16rn(v);
  float fh = __uint_as_float(((unsigned int)hs) << 16);
  h = (short)hs;
  l = (short)bf16rn(v - fh);
}
__device__ inline void split3(float v, short& h, short& m, short& l) {
  unsigned short hs = bf16rn(v);
  float fh = __uint_as_float(((unsigned int)hs) << 16);
  float r1 = v - fh;
  unsigned short ms = bf16rn(r1);
  float fm = __uint_as_float(((unsigned int)ms) << 16);
  h = (short)hs; m = (short)ms;
  l = (short)bf16rn(r1 - fm);
}

// ---------- 1. center+normalize rows -> y 3-split; feature 2-split ----------
__global__ __launch_bounds__(128) void k_rownorm(const float* __restrict__ f,
                                                 short* __restrict__ yh, short* __restrict__ ym,
                                                 short* __restrict__ yl,
                                                 short* __restrict__ fhi, short* __restrict__ flo) {
  int r = blockIdx.x, t = threadIdx.x;
  __shared__ float red[128];
  float v = f[r*128 + t];
  red[t] = v; __syncthreads();
  for (int s = 64; s > 0; s >>= 1) { if (t < s) red[t] += red[t+s]; __syncthreads(); }
  float mean = red[0] * (1.0f/128.0f);
  __syncthreads();
  float xc = v - mean;
  red[t] = xc*xc; __syncthreads();
  for (int s = 64; s > 0; s >>= 1) { if (t < s) red[t] += red[t+s]; __syncthreads(); }
  float inv = 1.0f / sqrtf(red[0]);
  short a, b, c;
  split3(xc*inv, a, b, c);
  yh[r*128 + t] = a; ym[r*128 + t] = b; yl[r*128 + t] = c;
  short fh, fl; split2(v, fh, fl);
  fhi[r*128 + t] = fh; flo[r*128 + t] = fl;
}

// ---------- 2. correlation bit blocks via MFMA, 6-chain (fp32-accurate) ----------
__global__ __launch_bounds__(256) void k_corr(const short* __restrict__ yh, const short* __restrict__ ym,
                                              const short* __restrict__ yl,
                                              const float* __restrict__ sparse, u64* __restrict__ bits) {
  int z = blockIdx.z;
  int a0 = c_pi[z]*1024 + blockIdx.x*64;
  int b0 = c_pj[z]*1024 + blockIdx.y*64;
  int tid = threadIdx.x, lane = tid & 63, wid = tid >> 6;
  int quad = lane >> 4, l15 = lane & 15;
  int arow = a0 + wid*16 + l15;
  f4v acc[4];
  #pragma unroll
  for (int i = 0; i < 4; ++i) { acc[i][0]=0.f; acc[i][1]=0.f; acc[i][2]=0.f; acc[i][3]=0.f; }
  #pragma unroll
  for (int ks = 0; ks < 4; ++ks) {
    size_t ao = (size_t)arow*128 + ks*32 + quad*8;
    s8v a_h = *(const s8v*)(yh + ao);
    s8v a_m = *(const s8v*)(ym + ao);
    s8v a_l = *(const s8v*)(yl + ao);
    #pragma unroll
    for (int nt = 0; nt < 4; ++nt) {
      size_t bo = (size_t)(b0 + nt*16 + l15)*128 + ks*32 + quad*8;
      s8v b_h = *(const s8v*)(yh + bo);
      s8v b_m = *(const s8v*)(ym + bo);
      s8v b_l = *(const s8v*)(yl + bo);
      acc[nt] = __builtin_amdgcn_mfma_f32_16x16x32_bf16(a_h, b_h, acc[nt], 0, 0, 0);
      acc[nt] = __builtin_amdgcn_mfma_f32_16x16x32_bf16(a_h, b_m, acc[nt], 0, 0, 0);
      acc[nt] = __builtin_amdgcn_mfma_f32_16x16x32_bf16(a_m, b_h, acc[nt], 0, 0, 0);
      acc[nt] = __builtin_amdgcn_mfma_f32_16x16x32_bf16(a_m, b_m, acc[nt], 0, 0, 0);
      acc[nt] = __builtin_amdgcn_mfma_f32_16x16x32_bf16(a_h, b_l, acc[nt], 0, 0, 0);
      acc[nt] = __builtin_amdgcn_mfma_f32_16x16x32_bf16(a_l, b_h, acc[nt], 0, 0, 0);
    }
  }
  __shared__ unsigned char lby[64*68];
  float sv = sparse[c_dri[z]];
  float dr = 1.0f / (1.0f + expf(-sv));
  int dg = c_diag[z];
  #pragma unroll
  for (int nt = 0; nt < 4; ++nt) {
    #pragma unroll
    for (int reg = 0; reg < 4; ++reg) {
      int lr = wid*16 + quad*4 + reg;
      int lc = nt*16 + l15;
      int ga = blockIdx.x*64 + lr, gb = blockIdx.y*64 + lc;
      int on = (fabsf(acc[nt][reg]) > dr) && !(dg && (ga == gb));
      lby[lr*68 + lc] = (unsigned char)on;
    }
  }
  __syncthreads();
  if (tid < 64) {
    u64 w = 0;
    for (int c2 = 0; c2 < 64; ++c2) w |= ((u64)lby[tid*68 + c2]) << c2;
    bits[z*16384 + (blockIdx.x*64 + tid)*16 + blockIdx.y] = w;
  }
}

// ---------- 3. mask rows (boolean A@C) + mask_wm + graph-2 degrees ----------
__global__ __launch_bounds__(64) void k_maskrows(const u64* __restrict__ bits, u64* __restrict__ mask,
                                                 u64* __restrict__ mask_wm, int* __restrict__ deg2) {
  int u = blockIdx.x;
  int i = u >> 10, a = u & 1023;
  int t = threadIdx.x;
  __shared__ u64 drow[16];
  if (t < 16) drow[t] = bits[i*16384 + a*16 + t];
  __syncthreads();
  int j = t >> 4, wl = t & 15;
  u64 out;
  if (j == i) {
    out = drow[wl];
  } else {
    const u64* S = bits + c_src[i*4 + j]*16384;
    out = 0;
    for (int w2 = 0; w2 < 16; ++w2) {
      u64 m = drow[w2];
      while (m) {
        int b = __builtin_ctzll(m); m &= m - 1;
        out |= S[(w2*64 + b)*16 + wl];
      }
    }
  }
  mask[(size_t)u*64 + t] = out;
  mask_wm[(size_t)t*4096 + u] = out;
  int cnt = __popcll(out);
  for (int off = 32; off > 0; off >>= 1) cnt += __shfl_down(cnt, off);
  if (t == 0) deg2[u] = cnt;
}

// ---------- 4. bit transpose -> maskT word-major + deg1 atomics ----------
__global__ __launch_bounds__(256) void k_bittrans2(const u64* __restrict__ mask, u64* __restrict__ wmT,
                                                   int* __restrict__ deg1) {
  __shared__ u64 tile[4096];   // 64 rows x 64 words = 32 KB
  int tI = blockIdx.x, tid = threadIdx.x;
  for (int e = tid; e < 4096; e += 256) tile[e] = mask[(size_t)tI*4096 + e];
  __syncthreads();
  int wv = tid >> 6, lane = tid & 63;
  int tJ0 = blockIdx.y*16;
  for (int j = 0; j < 4; ++j) {
    int tJ = tJ0 + wv*4 + j;
    u64 o = 0;
    #pragma unroll 8
    for (int k = 0; k < 64; ++k) o |= ((tile[k*64 + tJ] >> lane) & 1ULL) << k;
    wmT[(size_t)tI*4096 + tJ*64 + lane] = o;
    atomicAdd(&deg1[tJ*64 + lane], __popcll(o));
  }
}

// ---------- 5. per-(graph, m-tile) non-empty-chunk bitmask ----------
__global__ __launch_bounds__(64) void k_chunkmask(const u64* __restrict__ wmT, const u64* __restrict__ wmR,
                                                  u64* __restrict__ cmask) {
  int g = blockIdx.y, mt = blockIdx.x, kw = threadIdx.x;
  const u64* p = (g ? wmR : wmT) + (size_t)kw*4096 + mt*64;
  u64 o = 0;
  #pragma unroll 8
  for (int i = 0; i < 64; ++i) o |= p[i];
  unsigned long long b = __ballot(o != 0ULL);
  if (kw == 0) cmask[g*64 + mt] = b;
}

// ---------- 6. weight prep: [Wa|Wb] (Kx256 each) -> WT hi/lo [512 x K] ----------
__global__ __launch_bounds__(256) void k_prepWT(const float* __restrict__ Wa, const float* __restrict__ Wb,
                                                short* __restrict__ wthi, short* __restrict__ wtlo, int K) {
  __shared__ float lds[64*65];
  int tid = threadIdx.x;
  int k0 = blockIdx.x*64, n0 = blockIdx.y*64;
  const float* W = (n0 < 256) ? Wa : Wb;
  int nc0 = n0 & 255;
  for (int e = tid; e < 4096; e += 256) {
    int r = e >> 6, c = e & 63;
    lds[r*65 + c] = W[(size_t)(k0+r)*256 + nc0 + c];
  }
  __syncthreads();
  for (int e = tid; e < 4096; e += 256) {
    int nl = e >> 6, kc = e & 63;
    short h, l; split2(lds[kc*65 + nl], h, l);
    size_t o = (size_t)(n0+nl)*K + k0 + kc;
    wthi[o] = h; wtlo[o] = l;
  }
}

// ---------- 7. dense GEMM: Z[4096x512] = A(split) @ WT(split), 3-chain ----------
__global__ __launch_bounds__(256) void k_dense(const short* __restrict__ ahi, const short* __restrict__ alo,
                                               const short* __restrict__ wthi, const short* __restrict__ wtlo,
                                               float* __restrict__ Z, int K) {
  int tid = threadIdx.x, lane = tid & 63, wid = tid >> 6;
  int quad = lane >> 4, l15 = lane & 15;
  int m0 = blockIdx.x*64, n0 = blockIdx.y*64;
  int arow = m0 + wid*16 + l15;
  const s8v* ah = (const s8v*)(ahi + (size_t)arow*K);
  const s8v* al = (const s8v*)(alo + (size_t)arow*K);
  f4v acc[4];
  #pragma unroll
  for (int i = 0; i < 4; ++i) { acc[i][0]=0.f; acc[i][1]=0.f; acc[i][2]=0.f; acc[i][3]=0.f; }
  int ksteps = K >> 5;
  for (int ks = 0; ks < ksteps; ++ks) {
    s8v a_h = ah[ks*4 + quad];
    s8v a_l = al[ks*4 + quad];
    #pragma unroll
    for (int nt = 0; nt < 4; ++nt) {
      int nr = n0 + nt*16 + l15;
      s8v b_h = *(const s8v*)(wthi + (size_t)nr*K + ks*32 + quad*8);
      s8v b_l = *(const s8v*)(wtlo + (size_t)nr*K + ks*32 + quad*8);
      acc[nt] = __builtin_amdgcn_mfma_f32_16x16x32_bf16(a_h, b_h, acc[nt], 0, 0, 0);
      acc[nt] = __builtin_amdgcn_mfma_f32_16x16x32_bf16(a_h, b_l, acc[nt], 0, 0, 0);
      acc[nt] = __builtin_amdgcn_mfma_f32_16x16x32_bf16(a_l, b_h, acc[nt], 0, 0, 0);
    }
  }
  #pragma unroll
  for (int nt = 0; nt < 4; ++nt) {
    #pragma unroll
    for (int reg = 0; reg < 4; ++reg) {
      int row = m0 + wid*16 + quad*4 + reg;
      int col = n0 + nt*16 + l15;
      Z[(size_t)row*512 + col] = acc[nt][reg];
    }
  }
}

// ---------- 8. B prep: BT[512 x 4096]; nrm computed inline from degrees ----------
__global__ __launch_bounds__(256) void k_prepB(const float* __restrict__ Z, const int* __restrict__ deg1,
                                               const int* __restrict__ deg2,
                                               short* __restrict__ bthi, short* __restrict__ btlo) {
  __shared__ float lds[64*65];
  int tid = threadIdx.x;
  int u0 = blockIdx.x*64, c0 = blockIdx.y*64;
  const int* dg = (c0 < 256) ? deg1 : deg2;
  for (int e = tid; e < 4096; e += 256) {
    int r = e >> 6, c = e & 63;
    int d = dg[u0 + r];
    float nr = d > 0 ? (1.0f / sqrtf((float)d)) : 0.0f;
    lds[r*65 + c] = Z[(size_t)(u0+r)*512 + c0 + c] * nr;
  }
  __syncthreads();
  for (int e = tid; e < 4096; e += 256) {
    int cl = e >> 6, ul = e & 63;
    short h, l; split2(lds[ul*65 + cl], h, l);
    size_t o = (size_t)(c0+cl)*4096 + u0 + ul;
    bthi[o] = h; btlo[o] = l;
  }
}

// ---------- 9. mask GEMM v2: barrier-free, chunkmask-driven, coalesced bit loads ----------
// h[:, g*256+n] = relu(Z[:, g*256+n] + sfac_g[v]*(bits_g @ BT_g)[v][n] + bias_g[n])
__global__ __launch_bounds__(256) void k_mg2(const u64* __restrict__ wmT, const u64* __restrict__ wmR,
                                             const u64* __restrict__ cmask,
                                             const short* __restrict__ bthi, const short* __restrict__ btlo,
                                             const float* __restrict__ Z,
                                             const int* __restrict__ deg1, const int* __restrict__ deg2,
                                             const float* __restrict__ biasA, const float* __restrict__ biasB,
                                             float* __restrict__ h) {
  __shared__ s8v lut[256];   // byte -> 8 bf16 {0,1}
  int tid = threadIdx.x;
  {
    s8v e;
    #pragma unroll
    for (int j = 0; j < 8; ++j) e[j] = ((tid >> j) & 1) ? (short)0x3F80 : (short)0;
    lut[tid] = e;
  }
  __syncthreads();
  int g = blockIdx.z;
  const u64* wm = g ? wmR : wmT;
  u64 cm = cmask[g*64 + blockIdx.x];
  int m0 = blockIdx.x*64, n0 = blockIdx.y*64;
  int lane = tid & 63, wid = tid >> 6, quad = lane >> 4, l15 = lane & 15;
  int nrow = g*256 + n0 + wid*16 + l15;
  const short* bh = bthi + (size_t)nrow*4096;
  const short* bl = btlo + (size_t)nrow*4096;
  f4v acc[4];
  #pragma unroll
  for (int i = 0; i < 4; ++i) { acc[i][0]=0.f; acc[i][1]=0.f; acc[i][2]=0.f; acc[i][3]=0.f; }

  int kw = -1;
  u64 w0 = 0, w1 = 0, w2 = 0, w3 = 0;
  if (cm) {
    kw = __builtin_ctzll(cm); cm &= cm - 1;
    const u64* wp = wm + (size_t)kw*4096 + m0;
    w0 = wp[l15]; w1 = wp[16 + l15]; w2 = wp[32 + l15]; w3 = wp[48 + l15];
  }
  while (kw >= 0) {
    int kwn = -1;
    u64 nw0 = 0, nw1 = 0, nw2 = 0, nw3 = 0;
    if (cm) {                                  // prefetch next chunk's bit words
      kwn = __builtin_ctzll(cm); cm &= cm - 1;
      const u64* wp = wm + (size_t)kwn*4096 + m0;
      nw0 = wp[l15]; nw1 = wp[16 + l15]; nw2 = wp[32 + l15]; nw3 = wp[48 + l15];
    }
    const short* bhk = bh + kw*64;
    const short* blk = bl + kw*64;
    #pragma unroll
    for (int ks = 0; ks < 2; ++ks) {
      s8v b_h = *(const s8v*)(bhk + ks*32 + quad*8);
      s8v b_l = *(const s8v*)(blk + ks*32 + quad*8);
      unsigned sh = ks*32 + quad*8;
      s8v a0 = lut[(unsigned)(w0 >> sh) & 0xffu];
      s8v a1 = lut[(unsigned)(w1 >> sh) & 0xffu];
      s8v a2 = lut[(unsigned)(w2 >> sh) & 0xffu];
      s8v a3 = lut[(unsigned)(w3 >> sh) & 0xffu];
      acc[0] = __builtin_amdgcn_mfma_f32_16x16x32_bf16(a0, b_h, acc[0], 0, 0, 0);
      acc[0] = __builtin_amdgcn_mfma_f32_16x16x32_bf16(a0, b_l, acc[0], 0, 0, 0);
      acc[1] = __builtin_amdgcn_mfma_f32_16x16x32_bf16(a1, b_h, acc[1], 0, 0, 0);
      acc[1] = __builtin_amdgcn_mfma_f32_16x16x32_bf16(a1, b_l, acc[1], 0, 0, 0);
      acc[2] = __builtin_amdgcn_mfma_f32_16x16x32_bf16(a2, b_h, acc[2], 0, 0, 0);
      acc[2] = __builtin_amdgcn_mfma_f32_16x16x32_bf16(a2, b_l, acc[2], 0, 0, 0);
      acc[3] = __builtin_amdgcn_mfma_f32_16x16x32_bf16(a3, b_h, acc[3], 0, 0, 0);
      acc[3] = __builtin_amdgcn_mfma_f32_16x16x32_bf16(a3, b_l, acc[3], 0, 0, 0);
    }
    kw = kwn; w0 = nw0; w1 = nw1; w2 = nw2; w3 = nw3;
  }
  int n = n0 + wid*16 + l15;
  const int* dgp = g ? deg2 : deg1;
  float bn = (g ? biasB : biasA)[n];
  int zoff = g*256;
  #pragma unroll
  for (int mf = 0; mf < 4; ++mf) {
    #pragma unroll
    for (int reg = 0; reg < 4; ++reg) {
      int v = m0 + mf*16 + quad*4 + reg;
      int d = dgp[v];
      float sfac = 0.0f;
      if (d > 0) { float df = (float)d; sfac = (1.0f / sqrtf(df)) / df; }
      float val = Z[(size_t)v*512 + zoff + n] + sfac*acc[mf][reg] + bn;
      h[(size_t)v*512 + zoff + n] = fmaxf(val, 0.0f);
    }
  }
}

// ---------- 10. BN sums (coalesced one-pass, fp32 atomics): acc[col*2]=sum, [col*2+1]=sumsq ----------
__global__ __launch_bounds__(256) void k_bnsum(const float* __restrict__ h, float* __restrict__ acc) {
  int b = blockIdx.x, t = threadIdx.x;
  float s0 = 0.f, s1 = 0.f, q0 = 0.f, q1 = 0.f;
  const float2* hp = (const float2*)h;
  for (int r = b*16; r < b*16 + 16; ++r) {
    float2 v = hp[(size_t)r*256 + t];
    s0 += v.x; s1 += v.y; q0 += v.x*v.x; q1 += v.y*v.y;
  }
  int c0 = t*2;
  atomicAdd(&acc[c0*2 + 0], s0);
  atomicAdd(&acc[c0*2 + 1], q0);
  atomicAdd(&acc[c0*2 + 2], s1);
  atomicAdd(&acc[c0*2 + 3], q1);
}

// ---------- 11. BN apply (inline scale/shift from sums) + split to bf16 hi/lo ----------
__global__ __launch_bounds__(256) void k_bnapply_split(const float* __restrict__ h, const float* __restrict__ acc,
                                                       const float* __restrict__ gamma, const float* __restrict__ beta,
                                                       short* __restrict__ hnhi, short* __restrict__ hnlo) {
  int i = blockIdx.x*256 + threadIdx.x;       // 524288 float4s
  float4 v = ((const float4*)h)[i];
  int cb = (i & 127) * 4;
  float vv[4] = {v.x, v.y, v.z, v.w};
  short4 hh, ll;
  short* hp = (short*)&hh; short* lp = (short*)&ll;
  #pragma unroll
  for (int j = 0; j < 4; ++j) {
    int col = cb + j;
    float mean = acc[col*2] * (1.0f/4096.0f);
    float var  = acc[col*2 + 1] * (1.0f/4096.0f) - mean*mean;
    float inv  = rsqrtf(var + 1e-5f);
    float sc = gamma[col] * inv;
    float sh = beta[col] - mean * sc;
    split2(vv[j]*sc + sh, hp[j], lp[j]);
  }
  ((short4*)hnhi)[i] = hh; ((short4*)hnlo)[i] = ll;
}

// ---------- 12. final: inline BN2 + readout + modality softmax mix ----------
__global__ __launch_bounds__(256) void k_final2(const float* __restrict__ h, const float* __restrict__ acc2,
                                                const float* __restrict__ gamma2, const float* __restrict__ beta2,
                                                const float* __restrict__ w_ro, const float* __restrict__ cl,
                                                float* __restrict__ out) {
  int node = blockIdx.x;
  int t = threadIdx.x, m = t >> 6, lane = t & 63;
  const float* row = h + (size_t)(m*1024 + node)*512;
  float a0 = 0.f, a1 = 0.f, a2 = 0.f, a3 = 0.f;
  for (int it = 0; it < 8; ++it) {
    int k = lane + it*64;
    float mean = acc2[k*2] * (1.0f/4096.0f);
    float var  = acc2[k*2 + 1] * (1.0f/4096.0f) - mean*mean;
    float inv  = rsqrtf(var + 1e-5f);
    float sc = gamma2[k] * inv;
    float sh = beta2[k] - mean * sc;
    float hv = row[k]*sc + sh;
    float4 w = ((const float4*)w_ro)[k];
    a0 += hv*w.x; a1 += hv*w.y; a2 += hv*w.z; a3 += hv*w.w;
  }
  for (int off = 32; off > 0; off >>= 1) {
    a0 += __shfl_down(a0, off); a1 += __shfl_down(a1, off);
    a2 += __shfl_down(a2, off); a3 += __shfl_down(a3, off);
  }
  __shared__ float part[4][4];
  if (lane == 0) { part[m][0]=a0; part[m][1]=a1; part[m][2]=a2; part[m][3]=a3; }
  __syncthreads();
  if (t < 4) {
    float c0 = cl[0], c1 = cl[1], c2 = cl[2], c3 = cl[3];
    float mx = fmaxf(fmaxf(c0,c1), fmaxf(c2,c3));
    float e0 = expf(c0-mx), e1 = expf(c1-mx), e2 = expf(c2-mx), e3 = expf(c3-mx);
    float inv = 1.0f/(e0+e1+e2+e3);
    float r = (e0*part[0][t] + e1*part[1][t] + e2*part[2][t] + e3*part[3][t]) * inv;
    out[node*4 + t] = r;
  }
}

extern "C" void kernel_launch(void* const* d_in, const int* in_sizes, int n_in,
                              void* d_out, int out_size, void* d_ws, size_t ws_size,
                              hipStream_t stream) {
  const float* features = (const float*)d_in[0];
  const float* sparse   = (const float*)d_in[1];
  const float* cmix     = (const float*)d_in[2];
  const float* wAC1 = (const float*)d_in[3];
  const float* bAC1 = (const float*)d_in[4];
  const float* wCA1 = (const float*)d_in[5];
  const float* bCA1 = (const float*)d_in[6];
  const float* wAC2 = (const float*)d_in[7];
  const float* bAC2 = (const float*)d_in[8];
  const float* wCA2 = (const float*)d_in[9];
  const float* bCA2 = (const float*)d_in[10];
  const float* gamma1 = (const float*)d_in[11];
  const float* beta1  = (const float*)d_in[12];
  const float* gamma2 = (const float*)d_in[13];
  const float* beta2  = (const float*)d_in[14];
  const float* w_ro   = (const float*)d_in[15];
  float* out = (float*)d_out;

  char* ws = (char*)d_ws;
  const size_t MB = 1024ull*1024ull, KB = 1024ull;
  u64*   bits    = (u64*)(ws + 0);               // 1.25 MB
  u64*   mask    = (u64*)(ws + 2*MB);            // 2 MB (row-major)
  u64*   mask_wm = (u64*)(ws + 4*MB);            // 2 MB (word-major)
  u64*   maskT_wm= (u64*)(ws + 6*MB);            // 2 MB (word-major)
  int*   deg1    = (int*)(ws + 8*MB);            // 16 KB  [zeroed]
  float* bnacc1  = (float*)(ws + 8*MB + 16*KB);  // 4 KB   [zeroed]
  float* bnacc2  = (float*)(ws + 8*MB + 20*KB);  // 4 KB   [zeroed]
  int*   deg2    = (int*)(ws + 8*MB + 24*KB);    // 16 KB
  u64*   cmask   = (u64*)(ws + 8*MB + 40*KB);    // 1 KB
  short* WT1hi = (short*)(ws + 9*MB);            // 128 KB
  short* WT1lo = (short*)(ws + 9*MB + 128*KB);   // 128 KB
  short* WT2hi = (short*)(ws + 9*MB + 256*KB);   // 512 KB
  short* WT2lo = (short*)(ws + 9*MB + 768*KB);   // 512 KB
  // region [11MB,19MB): yh/ym/yl (dead after corr) -> BT hi/lo -> hn hi/lo -> BT hi/lo (L2)
  short* yh    = (short*)(ws + 11*MB);           // 1 MB
  short* ym    = (short*)(ws + 12*MB);           // 1 MB
  short* yl    = (short*)(ws + 13*MB);           // 1 MB
  short* BThi  = (short*)(ws + 11*MB);           // 4 MB
  short* BTlo  = (short*)(ws + 15*MB);           // 4 MB
  short* hnhi  = (short*)(ws + 11*MB);           // 4 MB
  short* hnlo  = (short*)(ws + 15*MB);           // 4 MB
  short* fhi   = (short*)(ws + 19*MB);           // 1 MB (dead after L1 dense)
  short* flo   = (short*)(ws + 20*MB);           // 1 MB
  float* Z     = (float*)(ws + 21*MB);           // 8 MB
  float* h     = (float*)(ws + 29*MB);           // 8 MB (total 37 MB)

  hipMemsetAsync(ws + 8*MB, 0, 24*KB, stream);   // deg1 + bnacc1 + bnacc2

  // graph prep
  k_rownorm<<<dim3(4096), dim3(128), 0, stream>>>(features, yh, ym, yl, fhi, flo);
  k_corr<<<dim3(16,16,10), dim3(256), 0, stream>>>(yh, ym, yl, sparse, bits);
  k_maskrows<<<dim3(4096), dim3(64), 0, stream>>>(bits, mask, mask_wm, deg2);
  k_bittrans2<<<dim3(64,4), dim3(256), 0, stream>>>(mask, maskT_wm, deg1);
  k_chunkmask<<<dim3(64,2), dim3(64), 0, stream>>>(maskT_wm, mask_wm, cmask);
  k_prepWT<<<dim3(2,8), dim3(256), 0, stream>>>(wAC1, wCA1, WT1hi, WT1lo, 128);
  k_prepWT<<<dim3(8,8), dim3(256), 0, stream>>>(wAC2, wCA2, WT2hi, WT2lo, 512);

  // layer 1:  h = relu(Z + sfac*(bits @ (nrm*Z)) + b)
  k_dense<<<dim3(64,8), dim3(256), 0, stream>>>(fhi, flo, WT1hi, WT1lo, Z, 128);
  k_prepB<<<dim3(64,8), dim3(256), 0, stream>>>(Z, deg1, deg2, BThi, BTlo);
  k_mg2<<<dim3(64,4,2), dim3(256), 0, stream>>>(maskT_wm, mask_wm, cmask, BThi, BTlo, Z,
                                                deg1, deg2, bAC1, bCA1, h);
  k_bnsum<<<dim3(256), dim3(256), 0, stream>>>(h, bnacc1);
  k_bnapply_split<<<dim3(2048), dim3(256), 0, stream>>>(h, bnacc1, gamma1, beta1, hnhi, hnlo);

  // layer 2
  k_dense<<<dim3(64,8), dim3(256), 0, stream>>>(hnhi, hnlo, WT2hi, WT2lo, Z, 512);
  k_prepB<<<dim3(64,8), dim3(256), 0, stream>>>(Z, deg1, deg2, BThi, BTlo);
  k_mg2<<<dim3(64,4,2), dim3(256), 0, stream>>>(maskT_wm, mask_wm, cmask, BThi, BTlo, Z,
                                                deg1, deg2, bAC2, bCA2, h);
  k_bnsum<<<dim3(256), dim3(256), 0, stream>>>(h, bnacc2);

  // readout (BN2 folded inline)
  k_final2<<<dim3(1024), dim3(256), 0, stream>>>(h, bnacc2, gamma2, beta2, w_ro, cmix, out);
}

// Round 5
// 422.483 us; speedup vs baseline: 1.5165x; 1.0517x over previous
//
#include <hip/hip_runtime.h>

typedef unsigned long long u64;
typedef __attribute__((ext_vector_type(8))) short s8v;   // 8 bf16 = 4 VGPRs (MFMA A/B frag)
typedef __attribute__((ext_vector_type(4))) float f4v;   // MFMA C/D frag

__device__ __constant__ int c_pi[10]   = {0,1,2,3,0,1,2,3,3,3};
__device__ __constant__ int c_pj[10]   = {0,1,2,3,3,3,3,0,1,2};
__device__ __constant__ int c_dri[10]  = {1,5,8,10,4,7,9,4,7,9};
__device__ __constant__ int c_diag[10] = {1,1,1,1,0,0,0,0,0,0};
__device__ __constant__ int c_src[16]  = {-1,7,8,9,  4,-1,8,9,  5,5,-1,9,  6,6,6,-1};

// round-to-nearest bf16
__device__ inline unsigned short bf16rn(float v) {
  unsigned int u = __float_as_uint(v);
  unsigned int r = u + 0x7fffu + ((u >> 16) & 1u);
  return (unsigned short)(r >> 16);
}
__device__ inline void split2(float v, short& h, short& l) {
  unsigned short hs = bf16rn(v);
  float fh = __uint_as_float(((unsigned int)hs) << 16);
  h = (short)hs;
  l = (short)bf16rn(v - fh);
}
__device__ inline void split3(float v, short& h, short& m, short& l) {
  unsigned short hs = bf16rn(v);
  float fh = __uint_as_float(((unsigned int)hs) << 16);
  float r1 = v - fh;
  unsigned short ms = bf16rn(r1);
  float fm = __uint_as_float(((unsigned int)ms) << 16);
  h = (short)hs; m = (short)ms;
  l = (short)bf16rn(r1 - fm);
}

// fragment-major pack offset for K=768: row r, k-index k
//   tile T=r>>4, rr=r&15, chunk c=k>>5, quad q=(k>>3)&3, j=k&7
//   off = ((T*24 + c)*64 + q*16 + rr)*8 + j   -> lane (q*16+rr) reads 16B at lane*16
__device__ inline size_t packoff(int row, int k) {
  int T = row >> 4, rr = row & 15;
  int c = k >> 5, q = (k >> 3) & 3, j = k & 7;
  return (((size_t)T*24 + c)*64 + q*16 + rr)*8 + j;
}

// ---------- 1. center+normalize rows -> frag-major K=768 split packs; feature 2-split ----------
__global__ __launch_bounds__(128) void k_rownorm(const float* __restrict__ f,
                                                 short* __restrict__ Apack, short* __restrict__ Bpack,
                                                 short* __restrict__ fhi, short* __restrict__ flo) {
  int r = blockIdx.x, t = threadIdx.x;
  __shared__ float red[128];
  float v = f[r*128 + t];
  red[t] = v; __syncthreads();
  for (int s = 64; s > 0; s >>= 1) { if (t < s) red[t] += red[t+s]; __syncthreads(); }
  float mean = red[0] * (1.0f/128.0f);
  __syncthreads();
  float xc = v - mean;
  red[t] = xc*xc; __syncthreads();
  for (int s = 64; s > 0; s >>= 1) { if (t < s) red[t] += red[t+s]; __syncthreads(); }
  float inv = 1.0f / sqrtf(red[0]);
  short h, m, l;
  split3(xc*inv, h, m, l);
  // chain slots: A=[h,m,h,m,h,l]  B=[h,m,m,h,l,h]  -> chunks give hh,mm,hm,mh,hl,lh
  short av[6] = {h, m, h, m, h, l};
  short bv[6] = {h, m, m, h, l, h};
  #pragma unroll
  for (int s = 0; s < 6; ++s) {
    Apack[packoff(r, s*128 + t)] = av[s];
    Bpack[packoff(r, s*128 + t)] = bv[s];
  }
  short fh, fl; split2(v, fh, fl);
  fhi[r*128 + t] = fh; flo[r*128 + t] = fl;
}

// ---------- 2. correlation bit blocks: frag-major packed GEMM, K=768 (6-chain exact) ----------
__global__ __launch_bounds__(256) void k_corr2(const short* __restrict__ Apack, const short* __restrict__ Bpack,
                                               const float* __restrict__ sparse, u64* __restrict__ bits) {
  int z = blockIdx.z;
  int bx = blockIdx.x, by = blockIdx.y;
  int dg = c_diag[z];
  if (dg && by < bx) return;          // symmetric diagonal blocks: upper triangle only
  int a0 = c_pi[z]*1024 + bx*64;
  int b0 = c_pj[z]*1024 + by*64;
  int tid = threadIdx.x, lane = tid & 63, wid = tid >> 6;
  int quad = lane >> 4, l15 = lane & 15;
  const s8v* Ap  = (const s8v*)Apack + ((size_t)((a0>>4) + wid))*24*64 + lane;
  const s8v* Bp0 = (const s8v*)Bpack + ((size_t)((b0>>4) + 0))*24*64 + lane;
  const s8v* Bp1 = (const s8v*)Bpack + ((size_t)((b0>>4) + 1))*24*64 + lane;
  const s8v* Bp2 = (const s8v*)Bpack + ((size_t)((b0>>4) + 2))*24*64 + lane;
  const s8v* Bp3 = (const s8v*)Bpack + ((size_t)((b0>>4) + 3))*24*64 + lane;
  f4v acc[4];
  #pragma unroll
  for (int i = 0; i < 4; ++i) { acc[i][0]=0.f; acc[i][1]=0.f; acc[i][2]=0.f; acc[i][3]=0.f; }
  #pragma unroll 4
  for (int c = 0; c < 24; ++c) {
    s8v af = Ap[c*64];
    acc[0] = __builtin_amdgcn_mfma_f32_16x16x32_bf16(af, Bp0[c*64], acc[0], 0, 0, 0);
    acc[1] = __builtin_amdgcn_mfma_f32_16x16x32_bf16(af, Bp1[c*64], acc[1], 0, 0, 0);
    acc[2] = __builtin_amdgcn_mfma_f32_16x16x32_bf16(af, Bp2[c*64], acc[2], 0, 0, 0);
    acc[3] = __builtin_amdgcn_mfma_f32_16x16x32_bf16(af, Bp3[c*64], acc[3], 0, 0, 0);
  }
  __shared__ unsigned char lby[64*68];
  float sv = sparse[c_dri[z]];
  float dr = 1.0f / (1.0f + expf(-sv));
  #pragma unroll
  for (int nt = 0; nt < 4; ++nt) {
    #pragma unroll
    for (int reg = 0; reg < 4; ++reg) {
      int lr = wid*16 + quad*4 + reg;
      int lc = nt*16 + l15;
      int ga = bx*64 + lr, gb = by*64 + lc;
      int on = (fabsf(acc[nt][reg]) > dr) && !(dg && (ga == gb));
      lby[lr*68 + lc] = (unsigned char)on;
    }
  }
  __syncthreads();
  if (tid < 64) {
    u64 w = 0;
    for (int c2 = 0; c2 < 64; ++c2) w |= ((u64)lby[tid*68 + c2]) << c2;
    bits[z*16384 + (bx*64 + tid)*16 + by] = w;
    if (dg && bx != by) {             // mirror tile for the skipped lower triangle
      u64 wt = 0;
      for (int c2 = 0; c2 < 64; ++c2) wt |= ((u64)lby[c2*68 + tid]) << c2;
      bits[z*16384 + (by*64 + tid)*16 + bx] = wt;
    }
  }
}

// ---------- 3. mask rows (boolean A@C) + mask_wm + graph-2 degrees ----------
__global__ __launch_bounds__(64) void k_maskrows(const u64* __restrict__ bits, u64* __restrict__ mask,
                                                 u64* __restrict__ mask_wm, int* __restrict__ deg2) {
  int u = blockIdx.x;
  int i = u >> 10, a = u & 1023;
  int t = threadIdx.x;
  __shared__ u64 drow[16];
  if (t < 16) drow[t] = bits[i*16384 + a*16 + t];
  __syncthreads();
  int j = t >> 4, wl = t & 15;
  u64 out;
  if (j == i) {
    out = drow[wl];
  } else {
    const u64* S = bits + c_src[i*4 + j]*16384;
    out = 0;
    for (int w2 = 0; w2 < 16; ++w2) {
      u64 m = drow[w2];
      while (m) {
        int b = __builtin_ctzll(m); m &= m - 1;
        out |= S[(w2*64 + b)*16 + wl];
      }
    }
  }
  mask[(size_t)u*64 + t] = out;
  mask_wm[(size_t)t*4096 + u] = out;
  int cnt = __popcll(out);
  for (int off = 32; off > 0; off >>= 1) cnt += __shfl_down(cnt, off);
  if (t == 0) deg2[u] = cnt;
}

// ---------- 4. bit transpose -> maskT word-major + deg1 atomics ----------
__global__ __launch_bounds__(256) void k_bittrans2(const u64* __restrict__ mask, u64* __restrict__ wmT,
                                                   int* __restrict__ deg1) {
  __shared__ u64 tile[4096];   // 64 rows x 64 words = 32 KB
  int tI = blockIdx.x, tid = threadIdx.x;
  for (int e = tid; e < 4096; e += 256) tile[e] = mask[(size_t)tI*4096 + e];
  __syncthreads();
  int wv = tid >> 6, lane = tid & 63;
  int tJ0 = blockIdx.y*16;
  for (int j = 0; j < 4; ++j) {
    int tJ = tJ0 + wv*4 + j;
    u64 o = 0;
    #pragma unroll 8
    for (int k = 0; k < 64; ++k) o |= ((tile[k*64 + tJ] >> lane) & 1ULL) << k;
    wmT[(size_t)tI*4096 + tJ*64 + lane] = o;
    atomicAdd(&deg1[tJ*64 + lane], __popcll(o));
  }
}

// ---------- 5. per-(graph, m-tile) non-empty-chunk bitmask ----------
__global__ __launch_bounds__(64) void k_chunkmask(const u64* __restrict__ wmT, const u64* __restrict__ wmR,
                                                  u64* __restrict__ cmask) {
  int g = blockIdx.y, mt = blockIdx.x, kw = threadIdx.x;
  const u64* p = (g ? wmR : wmT) + (size_t)kw*4096 + mt*64;
  u64 o = 0;
  #pragma unroll 8
  for (int i = 0; i < 64; ++i) o |= p[i];
  unsigned long long b = __ballot(o != 0ULL);
  if (kw == 0) cmask[g*64 + mt] = b;
}

// ---------- 6. weight prep: [Wa|Wb] (Kx256 each) -> WT hi/lo [512 x K] ----------
__global__ __launch_bounds__(256) void k_prepWT(const float* __restrict__ Wa, const float* __restrict__ Wb,
                                                short* __restrict__ wthi, short* __restrict__ wtlo, int K) {
  __shared__ float lds[64*65];
  int tid = threadIdx.x;
  int k0 = blockIdx.x*64, n0 = blockIdx.y*64;
  const float* W = (n0 < 256) ? Wa : Wb;
  int nc0 = n0 & 255;
  for (int e = tid; e < 4096; e += 256) {
    int r = e >> 6, c = e & 63;
    lds[r*65 + c] = W[(size_t)(k0+r)*256 + nc0 + c];
  }
  __syncthreads();
  for (int e = tid; e < 4096; e += 256) {
    int nl = e >> 6, kc = e & 63;
    short h, l; split2(lds[kc*65 + nl], h, l);
    size_t o = (size_t)(n0+nl)*K + k0 + kc;
    wthi[o] = h; wtlo[o] = l;
  }
}

// ---------- 7. dense GEMM: Z[4096x512] = A(split) @ WT(split), 3-chain ----------
__global__ __launch_bounds__(256) void k_dense(const short* __restrict__ ahi, const short* __restrict__ alo,
                                               const short* __restrict__ wthi, const short* __restrict__ wtlo,
                                               float* __restrict__ Z, int K) {
  int tid = threadIdx.x, lane = tid & 63, wid = tid >> 6;
  int quad = lane >> 4, l15 = lane & 15;
  int m0 = blockIdx.x*64, n0 = blockIdx.y*64;
  int arow = m0 + wid*16 + l15;
  const s8v* ah = (const s8v*)(ahi + (size_t)arow*K);
  const s8v* al = (const s8v*)(alo + (size_t)arow*K);
  f4v acc[4];
  #pragma unroll
  for (int i = 0; i < 4; ++i) { acc[i][0]=0.f; acc[i][1]=0.f; acc[i][2]=0.f; acc[i][3]=0.f; }
  int ksteps = K >> 5;
  for (int ks = 0; ks < ksteps; ++ks) {
    s8v a_h = ah[ks*4 + quad];
    s8v a_l = al[ks*4 + quad];
    #pragma unroll
    for (int nt = 0; nt < 4; ++nt) {
      int nr = n0 + nt*16 + l15;
      s8v b_h = *(const s8v*)(wthi + (size_t)nr*K + ks*32 + quad*8);
      s8v b_l = *(const s8v*)(wtlo + (size_t)nr*K + ks*32 + quad*8);
      acc[nt] = __builtin_amdgcn_mfma_f32_16x16x32_bf16(a_h, b_h, acc[nt], 0, 0, 0);
      acc[nt] = __builtin_amdgcn_mfma_f32_16x16x32_bf16(a_h, b_l, acc[nt], 0, 0, 0);
      acc[nt] = __builtin_amdgcn_mfma_f32_16x16x32_bf16(a_l, b_h, acc[nt], 0, 0, 0);
    }
  }
  #pragma unroll
  for (int nt = 0; nt < 4; ++nt) {
    #pragma unroll
    for (int reg = 0; reg < 4; ++reg) {
      int row = m0 + wid*16 + quad*4 + reg;
      int col = n0 + nt*16 + l15;
      Z[(size_t)row*512 + col] = acc[nt][reg];
    }
  }
}

// ---------- 8. B prep: BT[512 x 4096]; nrm computed inline from degrees ----------
__global__ __launch_bounds__(256) void k_prepB(const float* __restrict__ Z, const int* __restrict__ deg1,
                                               const int* __restrict__ deg2,
                                               short* __restrict__ bthi, short* __restrict__ btlo) {
  __shared__ float lds[64*65];
  int tid = threadIdx.x;
  int u0 = blockIdx.x*64, c0 = blockIdx.y*64;
  const int* dg = (c0 < 256) ? deg1 : deg2;
  for (int e = tid; e < 4096; e += 256) {
    int r = e >> 6, c = e & 63;
    int d = dg[u0 + r];
    float nr = d > 0 ? (1.0f / sqrtf((float)d)) : 0.0f;
    lds[r*65 + c] = Z[(size_t)(u0+r)*512 + c0 + c] * nr;
  }
  __syncthreads();
  for (int e = tid; e < 4096; e += 256) {
    int cl = e >> 6, ul = e & 63;
    short h, l; split2(lds[ul*65 + cl], h, l);
    size_t o = (size_t)(c0+cl)*4096 + u0 + ul;
    bthi[o] = h; btlo[o] = l;
  }
}

// ---------- 9. mask GEMM v2: barrier-free, chunkmask-driven, coalesced bit loads ----------
__global__ __launch_bounds__(256) void k_mg2(const u64* __restrict__ wmT, const u64* __restrict__ wmR,
                                             const u64* __restrict__ cmask,
                                             const short* __restrict__ bthi, const short* __restrict__ btlo,
                                             const float* __restrict__ Z,
                                             const int* __restrict__ deg1, const int* __restrict__ deg2,
                                             const float* __restrict__ biasA, const float* __restrict__ biasB,
                                             float* __restrict__ h) {
  __shared__ s8v lut[256];   // byte -> 8 bf16 {0,1}
  int tid = threadIdx.x;
  {
    s8v e;
    #pragma unroll
    for (int j = 0; j < 8; ++j) e[j] = ((tid >> j) & 1) ? (short)0x3F80 : (short)0;
    lut[tid] = e;
  }
  __syncthreads();
  int g = blockIdx.z;
  const u64* wm = g ? wmR : wmT;
  u64 cm = cmask[g*64 + blockIdx.x];
  int m0 = blockIdx.x*64, n0 = blockIdx.y*64;
  int lane = tid & 63, wid = tid >> 6, quad = lane >> 4, l15 = lane & 15;
  int nrow = g*256 + n0 + wid*16 + l15;
  const short* bh = bthi + (size_t)nrow*4096;
  const short* bl = btlo + (size_t)nrow*4096;
  f4v acc[4];
  #pragma unroll
  for (int i = 0; i < 4; ++i) { acc[i][0]=0.f; acc[i][1]=0.f; acc[i][2]=0.f; acc[i][3]=0.f; }

  int kw = -1;
  u64 w0 = 0, w1 = 0, w2 = 0, w3 = 0;
  if (cm) {
    kw = __builtin_ctzll(cm); cm &= cm - 1;
    const u64* wp = wm + (size_t)kw*4096 + m0;
    w0 = wp[l15]; w1 = wp[16 + l15]; w2 = wp[32 + l15]; w3 = wp[48 + l15];
  }
  while (kw >= 0) {
    int kwn = -1;
    u64 nw0 = 0, nw1 = 0, nw2 = 0, nw3 = 0;
    if (cm) {
      kwn = __builtin_ctzll(cm); cm &= cm - 1;
      const u64* wp = wm + (size_t)kwn*4096 + m0;
      nw0 = wp[l15]; nw1 = wp[16 + l15]; nw2 = wp[32 + l15]; nw3 = wp[48 + l15];
    }
    const short* bhk = bh + kw*64;
    const short* blk = bl + kw*64;
    #pragma unroll
    for (int ks = 0; ks < 2; ++ks) {
      s8v b_h = *(const s8v*)(bhk + ks*32 + quad*8);
      s8v b_l = *(const s8v*)(blk + ks*32 + quad*8);
      unsigned sh = ks*32 + quad*8;
      s8v a0 = lut[(unsigned)(w0 >> sh) & 0xffu];
      s8v a1 = lut[(unsigned)(w1 >> sh) & 0xffu];
      s8v a2 = lut[(unsigned)(w2 >> sh) & 0xffu];
      s8v a3 = lut[(unsigned)(w3 >> sh) & 0xffu];
      acc[0] = __builtin_amdgcn_mfma_f32_16x16x32_bf16(a0, b_h, acc[0], 0, 0, 0);
      acc[0] = __builtin_amdgcn_mfma_f32_16x16x32_bf16(a0, b_l, acc[0], 0, 0, 0);
      acc[1] = __builtin_amdgcn_mfma_f32_16x16x32_bf16(a1, b_h, acc[1], 0, 0, 0);
      acc[1] = __builtin_amdgcn_mfma_f32_16x16x32_bf16(a1, b_l, acc[1], 0, 0, 0);
      acc[2] = __builtin_amdgcn_mfma_f32_16x16x32_bf16(a2, b_h, acc[2], 0, 0, 0);
      acc[2] = __builtin_amdgcn_mfma_f32_16x16x32_bf16(a2, b_l, acc[2], 0, 0, 0);
      acc[3] = __builtin_amdgcn_mfma_f32_16x16x32_bf16(a3, b_h, acc[3], 0, 0, 0);
      acc[3] = __builtin_amdgcn_mfma_f32_16x16x32_bf16(a3, b_l, acc[3], 0, 0, 0);
    }
    kw = kwn; w0 = nw0; w1 = nw1; w2 = nw2; w3 = nw3;
  }
  int n = n0 + wid*16 + l15;
  const int* dgp = g ? deg2 : deg1;
  float bn = (g ? biasB : biasA)[n];
  int zoff = g*256;
  #pragma unroll
  for (int mf = 0; mf < 4; ++mf) {
    #pragma unroll
    for (int reg = 0; reg < 4; ++reg) {
      int v = m0 + mf*16 + quad*4 + reg;
      int d = dgp[v];
      float sfac = 0.0f;
      if (d > 0) { float df = (float)d; sfac = (1.0f / sqrtf(df)) / df; }
      float val = Z[(size_t)v*512 + zoff + n] + sfac*acc[mf][reg] + bn;
      h[(size_t)v*512 + zoff + n] = fmaxf(val, 0.0f);
    }
  }
}

// ---------- 10. BN sums (coalesced one-pass, fp32 atomics) ----------
__global__ __launch_bounds__(256) void k_bnsum(const float* __restrict__ h, float* __restrict__ acc) {
  int b = blockIdx.x, t = threadIdx.x;
  float s0 = 0.f, s1 = 0.f, q0 = 0.f, q1 = 0.f;
  const float2* hp = (const float2*)h;
  for (int r = b*16; r < b*16 + 16; ++r) {
    float2 v = hp[(size_t)r*256 + t];
    s0 += v.x; s1 += v.y; q0 += v.x*v.x; q1 += v.y*v.y;
  }
  int c0 = t*2;
  atomicAdd(&acc[c0*2 + 0], s0);
  atomicAdd(&acc[c0*2 + 1], q0);
  atomicAdd(&acc[c0*2 + 2], s1);
  atomicAdd(&acc[c0*2 + 3], q1);
}

// ---------- 11. BN apply + split to bf16 hi/lo ----------
__global__ __launch_bounds__(256) void k_bnapply_split(const float* __restrict__ h, const float* __restrict__ acc,
                                                       const float* __restrict__ gamma, const float* __restrict__ beta,
                                                       short* __restrict__ hnhi, short* __restrict__ hnlo) {
  int i = blockIdx.x*256 + threadIdx.x;       // 524288 float4s
  float4 v = ((const float4*)h)[i];
  int cb = (i & 127) * 4;
  float vv[4] = {v.x, v.y, v.z, v.w};
  short4 hh, ll;
  short* hp = (short*)&hh; short* lp = (short*)&ll;
  #pragma unroll
  for (int j = 0; j < 4; ++j) {
    int col = cb + j;
    float mean = acc[col*2] * (1.0f/4096.0f);
    float var  = acc[col*2 + 1] * (1.0f/4096.0f) - mean*mean;
    float inv  = rsqrtf(var + 1e-5f);
    float sc = gamma[col] * inv;
    float sh = beta[col] - mean * sc;
    split2(vv[j]*sc + sh, hp[j], lp[j]);
  }
  ((short4*)hnhi)[i] = hh; ((short4*)hnlo)[i] = ll;
}

// ---------- 12. final: inline BN2 + readout + modality softmax mix ----------
__global__ __launch_bounds__(256) void k_final2(const float* __restrict__ h, const float* __restrict__ acc2,
                                                const float* __restrict__ gamma2, const float* __restrict__ beta2,
                                                const float* __restrict__ w_ro, const float* __restrict__ cl,
                                                float* __restrict__ out) {
  int node = blockIdx.x;
  int t = threadIdx.x, m = t >> 6, lane = t & 63;
  const float* row = h + (size_t)(m*1024 + node)*512;
  float a0 = 0.f, a1 = 0.f, a2 = 0.f, a3 = 0.f;
  for (int it = 0; it < 8; ++it) {
    int k = lane + it*64;
    float mean = acc2[k*2] * (1.0f/4096.0f);
    float var  = acc2[k*2 + 1] * (1.0f/4096.0f) - mean*mean;
    float inv  = rsqrtf(var + 1e-5f);
    float sc = gamma2[k] * inv;
    float sh = beta2[k] - mean * sc;
    float hv = row[k]*sc + sh;
    float4 w = ((const float4*)w_ro)[k];
    a0 += hv*w.x; a1 += hv*w.y; a2 += hv*w.z; a3 += hv*w.w;
  }
  for (int off = 32; off > 0; off >>= 1) {
    a0 += __shfl_down(a0, off); a1 += __shfl_down(a1, off);
    a2 += __shfl_down(a2, off); a3 += __shfl_down(a3, off);
  }
  __shared__ float part[4][4];
  if (lane == 0) { part[m][0]=a0; part[m][1]=a1; part[m][2]=a2; part[m][3]=a3; }
  __syncthreads();
  if (t < 4) {
    float c0 = cl[0], c1 = cl[1], c2 = cl[2], c3 = cl[3];
    float mx = fmaxf(fmaxf(c0,c1), fmaxf(c2,c3));
    float e0 = expf(c0-mx), e1 = expf(c1-mx), e2 = expf(c2-mx), e3 = expf(c3-mx);
    float inv = 1.0f/(e0+e1+e2+e3);
    float r = (e0*part[0][t] + e1*part[1][t] + e2*part[2][t] + e3*part[3][t]) * inv;
    out[node*4 + t] = r;
  }
}

extern "C" void kernel_launch(void* const* d_in, const int* in_sizes, int n_in,
                              void* d_out, int out_size, void* d_ws, size_t ws_size,
                              hipStream_t stream) {
  const float* features = (const float*)d_in[0];
  const float* sparse   = (const float*)d_in[1];
  const float* cmix     = (const float*)d_in[2];
  const float* wAC1 = (const float*)d_in[3];
  const float* bAC1 = (const float*)d_in[4];
  const float* wCA1 = (const float*)d_in[5];
  const float* bCA1 = (const float*)d_in[6];
  const float* wAC2 = (const float*)d_in[7];
  const float* bAC2 = (const float*)d_in[8];
  const float* wCA2 = (const float*)d_in[9];
  const float* bCA2 = (const float*)d_in[10];
  const float* gamma1 = (const float*)d_in[11];
  const float* beta1  = (const float*)d_in[12];
  const float* gamma2 = (const float*)d_in[13];
  const float* beta2  = (const float*)d_in[14];
  const float* w_ro   = (const float*)d_in[15];
  float* out = (float*)d_out;

  char* ws = (char*)d_ws;
  const size_t MB = 1024ull*1024ull, KB = 1024ull;
  u64*   bits    = (u64*)(ws + 0);               // 1.25 MB
  u64*   mask    = (u64*)(ws + 2*MB);            // 2 MB (row-major)
  u64*   mask_wm = (u64*)(ws + 4*MB);            // 2 MB (word-major)
  u64*   maskT_wm= (u64*)(ws + 6*MB);            // 2 MB (word-major)
  int*   deg1    = (int*)(ws + 8*MB);            // 16 KB  [zeroed]
  float* bnacc1  = (float*)(ws + 8*MB + 16*KB);  // 4 KB   [zeroed]
  float* bnacc2  = (float*)(ws + 8*MB + 20*KB);  // 4 KB   [zeroed]
  int*   deg2    = (int*)(ws + 8*MB + 24*KB);    // 16 KB
  u64*   cmask   = (u64*)(ws + 8*MB + 40*KB);    // 1 KB
  short* WT1hi = (short*)(ws + 9*MB);            // 128 KB
  short* WT1lo = (short*)(ws + 9*MB + 128*KB);   // 128 KB
  short* WT2hi = (short*)(ws + 9*MB + 256*KB);   // 512 KB
  short* WT2lo = (short*)(ws + 9*MB + 768*KB);   // 512 KB
  // region [11MB,23MB): Apack/Bpack (dead after corr) -> BT hi/lo -> hn hi/lo -> BT hi/lo (L2)
  short* Apack = (short*)(ws + 11*MB);           // 6 MB (11-17)
  short* Bpack = (short*)(ws + 17*MB);           // 6 MB (17-23)
  short* BThi  = (short*)(ws + 11*MB);           // 4 MB
  short* BTlo  = (short*)(ws + 15*MB);           // 4 MB
  short* hnhi  = (short*)(ws + 11*MB);           // 4 MB
  short* hnlo  = (short*)(ws + 15*MB);           // 4 MB
  short* fhi   = (short*)(ws + 23*MB);           // 1 MB (dead after L1 dense)
  short* flo   = (short*)(ws + 24*MB);           // 1 MB
  float* Z     = (float*)(ws + 25*MB);           // 8 MB
  float* h     = (float*)(ws + 33*MB);           // 8 MB (total 41 MB)

  hipMemsetAsync(ws + 8*MB, 0, 24*KB, stream);   // deg1 + bnacc1 + bnacc2

  // graph prep
  k_rownorm<<<dim3(4096), dim3(128), 0, stream>>>(features, Apack, Bpack, fhi, flo);
  k_corr2<<<dim3(16,16,10), dim3(256), 0, stream>>>(Apack, Bpack, sparse, bits);
  k_maskrows<<<dim3(4096), dim3(64), 0, stream>>>(bits, mask, mask_wm, deg2);
  k_bittrans2<<<dim3(64,4), dim3(256), 0, stream>>>(mask, maskT_wm, deg1);
  k_chunkmask<<<dim3(64,2), dim3(64), 0, stream>>>(maskT_wm, mask_wm, cmask);
  k_prepWT<<<dim3(2,8), dim3(256), 0, stream>>>(wAC1, wCA1, WT1hi, WT1lo, 128);
  k_prepWT<<<dim3(8,8), dim3(256), 0, stream>>>(wAC2, wCA2, WT2hi, WT2lo, 512);

  // layer 1:  h = relu(Z + sfac*(bits @ (nrm*Z)) + b)
  k_dense<<<dim3(64,8), dim3(256), 0, stream>>>(fhi, flo, WT1hi, WT1lo, Z, 128);
  k_prepB<<<dim3(64,8), dim3(256), 0, stream>>>(Z, deg1, deg2, BThi, BTlo);
  k_mg2<<<dim3(64,4,2), dim3(256), 0, stream>>>(maskT_wm, mask_wm, cmask, BThi, BTlo, Z,
                                                deg1, deg2, bAC1, bCA1, h);
  k_bnsum<<<dim3(256), dim3(256), 0, stream>>>(h, bnacc1);
  k_bnapply_split<<<dim3(2048), dim3(256), 0, stream>>>(h, bnacc1, gamma1, beta1, hnhi, hnlo);

  // layer 2
  k_dense<<<dim3(64,8), dim3(256), 0, stream>>>(hnhi, hnlo, WT2hi, WT2lo, Z, 512);
  k_prepB<<<dim3(64,8), dim3(256), 0, stream>>>(Z, deg1, deg2, BThi, BTlo);
  k_mg2<<<dim3(64,4,2), dim3(256), 0, stream>>>(maskT_wm, mask_wm, cmask, BThi, BTlo, Z,
                                                deg1, deg2, bAC2, bCA2, h);
  k_bnsum<<<dim3(256), dim3(256), 0, stream>>>(h, bnacc2);

  // readout (BN2 folded inline)
  k_final2<<<dim3(1024), dim3(256), 0, stream>>>(h, bnacc2, gamma2, beta2, w_ro, cmix, out);
}

// Round 6
// 381.280 us; speedup vs baseline: 1.6804x; 1.1081x over previous
//
#include <hip/hip_runtime.h>

typedef unsigned long long u64;
typedef __attribute__((ext_vector_type(8))) short s8v;   // 8 bf16 = 4 VGPRs (MFMA A/B frag)
typedef __attribute__((ext_vector_type(4))) float f4v;   // MFMA C/D frag

__device__ __constant__ int c_pi[10]   = {0,1,2,3,0,1,2,3,3,3};
__device__ __constant__ int c_pj[10]   = {0,1,2,3,3,3,3,0,1,2};
__device__ __constant__ int c_dri[10]  = {1,5,8,10,4,7,9,4,7,9};
__device__ __constant__ int c_diag[10] = {1,1,1,1,0,0,0,0,0,0};
__device__ __constant__ int c_src[16]  = {-1,7,8,9,  4,-1,8,9,  5,5,-1,9,  6,6,6,-1};

// round-to-nearest bf16
__device__ inline unsigned short bf16rn(float v) {
  unsigned int u = __float_as_uint(v);
  unsigned int r = u + 0x7fffu + ((u >> 16) & 1u);
  return (unsigned short)(r >> 16);
}
__device__ inline void split2(float v, short& h, short& l) {
  unsigned short hs = bf16rn(v);
  float fh = __uint_as_float(((unsigned int)hs) << 16);
  h = (short)hs;
  l = (short)bf16rn(v - fh);
}
__device__ inline void split3(float v, short& h, short& m, short& l) {
  unsigned short hs = bf16rn(v);
  float fh = __uint_as_float(((unsigned int)hs) << 16);
  float r1 = v - fh;
  unsigned short ms = bf16rn(r1);
  float fm = __uint_as_float(((unsigned int)ms) << 16);
  h = (short)hs; m = (short)ms;
  l = (short)bf16rn(r1 - fm);
}

// fragment-major pack offset: row r, k-index k, KC = K/32 chunks
//   tile T=r>>4, rr=r&15, chunk c=k>>5, quad q=(k>>3)&3, j=k&7
//   off = ((T*KC + c)*64 + q*16 + rr)*8 + j  -> lane (q*16+rr) reads 16B at +lane*16
__device__ inline size_t packoff(int row, int k, int KC) {
  int T = row >> 4, rr = row & 15;
  int c = k >> 5, q = (k >> 3) & 3, j = k & 7;
  return (((size_t)T*KC + c)*64 + q*16 + rr)*8 + j;
}

// ---------- 1. center+normalize rows -> corr packs (K=768); feature pack (K=128) ----------
__global__ __launch_bounds__(128) void k_rownorm(const float* __restrict__ f,
                                                 short* __restrict__ Apack, short* __restrict__ Bpack,
                                                 short* __restrict__ fPh, short* __restrict__ fPl) {
  int r = blockIdx.x, t = threadIdx.x;
  __shared__ float red[128];
  float v = f[r*128 + t];
  red[t] = v; __syncthreads();
  for (int s = 64; s > 0; s >>= 1) { if (t < s) red[t] += red[t+s]; __syncthreads(); }
  float mean = red[0] * (1.0f/128.0f);
  __syncthreads();
  float xc = v - mean;
  red[t] = xc*xc; __syncthreads();
  for (int s = 64; s > 0; s >>= 1) { if (t < s) red[t] += red[t+s]; __syncthreads(); }
  float inv = 1.0f / sqrtf(red[0]);
  short h, m, l;
  split3(xc*inv, h, m, l);
  // chain slots: A=[h,m,h,m,h,l]  B=[h,m,m,h,l,h]  -> chunks give hh,mm,hm,mh,hl,lh
  short av[6] = {h, m, h, m, h, l};
  short bv[6] = {h, m, m, h, l, h};
  #pragma unroll
  for (int s = 0; s < 6; ++s) {
    Apack[packoff(r, s*128 + t, 24)] = av[s];
    Bpack[packoff(r, s*128 + t, 24)] = bv[s];
  }
  short fh, fl; split2(v, fh, fl);
  size_t fo = packoff(r, t, 4);
  fPh[fo] = fh; fPl[fo] = fl;
}

// ---------- 2. correlation bit blocks: frag-major packed GEMM, K=768 (6-chain exact) ----------
__global__ __launch_bounds__(256) void k_corr2(const short* __restrict__ Apack, const short* __restrict__ Bpack,
                                               const float* __restrict__ sparse, u64* __restrict__ bits) {
  int z = blockIdx.z;
  int bx = blockIdx.x, by = blockIdx.y;
  int dg = c_diag[z];
  if (dg && by < bx) return;          // symmetric diagonal blocks: upper triangle only
  int a0 = c_pi[z]*1024 + bx*64;
  int b0 = c_pj[z]*1024 + by*64;
  int tid = threadIdx.x, lane = tid & 63, wid = tid >> 6;
  int quad = lane >> 4, l15 = lane & 15;
  const s8v* Ap  = (const s8v*)Apack + ((size_t)((a0>>4) + wid))*24*64 + lane;
  const s8v* Bp0 = (const s8v*)Bpack + ((size_t)((b0>>4) + 0))*24*64 + lane;
  const s8v* Bp1 = (const s8v*)Bpack + ((size_t)((b0>>4) + 1))*24*64 + lane;
  const s8v* Bp2 = (const s8v*)Bpack + ((size_t)((b0>>4) + 2))*24*64 + lane;
  const s8v* Bp3 = (const s8v*)Bpack + ((size_t)((b0>>4) + 3))*24*64 + lane;
  f4v acc[4];
  #pragma unroll
  for (int i = 0; i < 4; ++i) { acc[i][0]=0.f; acc[i][1]=0.f; acc[i][2]=0.f; acc[i][3]=0.f; }
  #pragma unroll 4
  for (int c = 0; c < 24; ++c) {
    s8v af = Ap[c*64];
    acc[0] = __builtin_amdgcn_mfma_f32_16x16x32_bf16(af, Bp0[c*64], acc[0], 0, 0, 0);
    acc[1] = __builtin_amdgcn_mfma_f32_16x16x32_bf16(af, Bp1[c*64], acc[1], 0, 0, 0);
    acc[2] = __builtin_amdgcn_mfma_f32_16x16x32_bf16(af, Bp2[c*64], acc[2], 0, 0, 0);
    acc[3] = __builtin_amdgcn_mfma_f32_16x16x32_bf16(af, Bp3[c*64], acc[3], 0, 0, 0);
  }
  __shared__ unsigned char lby[64*68];
  float sv = sparse[c_dri[z]];
  float dr = 1.0f / (1.0f + expf(-sv));
  #pragma unroll
  for (int nt = 0; nt < 4; ++nt) {
    #pragma unroll
    for (int reg = 0; reg < 4; ++reg) {
      int lr = wid*16 + quad*4 + reg;
      int lc = nt*16 + l15;
      int ga = bx*64 + lr, gb = by*64 + lc;
      int on = (fabsf(acc[nt][reg]) > dr) && !(dg && (ga == gb));
      lby[lr*68 + lc] = (unsigned char)on;
    }
  }
  __syncthreads();
  if (tid < 64) {
    u64 w = 0;
    for (int c2 = 0; c2 < 64; ++c2) w |= ((u64)lby[tid*68 + c2]) << c2;
    bits[z*16384 + (bx*64 + tid)*16 + by] = w;
    if (dg && bx != by) {             // mirror tile for the skipped lower triangle
      u64 wt = 0;
      for (int c2 = 0; c2 < 64; ++c2) wt |= ((u64)lby[c2*68 + tid]) << c2;
      bits[z*16384 + (by*64 + tid)*16 + bx] = wt;
    }
  }
}

// ---------- 3. mask rows (boolean A@C) + mask_wm + graph-2 degrees ----------
__global__ __launch_bounds__(64) void k_maskrows(const u64* __restrict__ bits, u64* __restrict__ mask,
                                                 u64* __restrict__ mask_wm, int* __restrict__ deg2) {
  int u = blockIdx.x;
  int i = u >> 10, a = u & 1023;
  int t = threadIdx.x;
  __shared__ u64 drow[16];
  if (t < 16) drow[t] = bits[i*16384 + a*16 + t];
  __syncthreads();
  int j = t >> 4, wl = t & 15;
  u64 out;
  if (j == i) {
    out = drow[wl];
  } else {
    const u64* S = bits + c_src[i*4 + j]*16384;
    out = 0;
    for (int w2 = 0; w2 < 16; ++w2) {
      u64 m = drow[w2];
      while (m) {
        int b = __builtin_ctzll(m); m &= m - 1;
        out |= S[(w2*64 + b)*16 + wl];
      }
    }
  }
  mask[(size_t)u*64 + t] = out;
  mask_wm[(size_t)t*4096 + u] = out;
  int cnt = __popcll(out);
  for (int off = 32; off > 0; off >>= 1) cnt += __shfl_down(cnt, off);
  if (t == 0) deg2[u] = cnt;
}

// ---------- 4. bit transpose -> maskT word-major + deg1 atomics ----------
__global__ __launch_bounds__(256) void k_bittrans2(const u64* __restrict__ mask, u64* __restrict__ wmT,
                                                   int* __restrict__ deg1) {
  __shared__ u64 tile[4096];   // 64 rows x 64 words = 32 KB
  int tI = blockIdx.x, tid = threadIdx.x;
  for (int e = tid; e < 4096; e += 256) tile[e] = mask[(size_t)tI*4096 + e];
  __syncthreads();
  int wv = tid >> 6, lane = tid & 63;
  int tJ0 = blockIdx.y*16;
  for (int j = 0; j < 4; ++j) {
    int tJ = tJ0 + wv*4 + j;
    u64 o = 0;
    #pragma unroll 8
    for (int k = 0; k < 64; ++k) o |= ((tile[k*64 + tJ] >> lane) & 1ULL) << k;
    wmT[(size_t)tI*4096 + tJ*64 + lane] = o;
    atomicAdd(&deg1[tJ*64 + lane], __popcll(o));
  }
}

// ---------- 5. per-(graph, m-tile) non-empty-chunk bitmask ----------
__global__ __launch_bounds__(64) void k_chunkmask(const u64* __restrict__ wmT, const u64* __restrict__ wmR,
                                                  u64* __restrict__ cmask) {
  int g = blockIdx.y, mt = blockIdx.x, kw = threadIdx.x;
  const u64* p = (g ? wmR : wmT) + (size_t)kw*4096 + mt*64;
  u64 o = 0;
  #pragma unroll 8
  for (int i = 0; i < 64; ++i) o |= p[i];
  unsigned long long b = __ballot(o != 0ULL);
  if (kw == 0) cmask[g*64 + mt] = b;
}

// ---------- 6. weight prep: [Wa|Wb] (Kx256 each) -> frag-major packs [512 rows x K] ----------
__global__ __launch_bounds__(256) void k_prepWT(const float* __restrict__ Wa, const float* __restrict__ Wb,
                                                short* __restrict__ wph, short* __restrict__ wpl, int K) {
  __shared__ float lds[64*65];
  int tid = threadIdx.x;
  int k0 = blockIdx.x*64, n0 = blockIdx.y*64;
  const float* W = (n0 < 256) ? Wa : Wb;
  int nc0 = n0 & 255;
  for (int e = tid; e < 4096; e += 256) {
    int r = e >> 6, c = e & 63;           // r = k-local, c = n-local
    lds[r*65 + c] = W[(size_t)(k0+r)*256 + nc0 + c];
  }
  __syncthreads();
  int KC = K >> 5;
  for (int e = tid; e < 4096; e += 256) {  // pack-major write order (coalesced)
    int j = e & 7, ln = (e >> 3) & 63, cp = (e >> 9) & 1, Tp = e >> 10;
    int q = ln >> 4, rr = ln & 15;
    float v = lds[(cp*32 + q*8 + j)*65 + (Tp*16 + rr)];
    short h, l; split2(v, h, l);
    size_t off = (((size_t)((n0>>4)+Tp)*KC + (k0>>5)+cp)*64 + ln)*8 + j;
    wph[off] = h; wpl[off] = l;
  }
}

// ---------- 7. dense GEMM on frag-major packs: Z[4096x512] = A @ W^T, 3-chain ----------
__global__ __launch_bounds__(256) void k_dense2(const short* __restrict__ Ah, const short* __restrict__ Al,
                                                const short* __restrict__ Bh, const short* __restrict__ Bl,
                                                float* __restrict__ Z, int KC) {
  int tid = threadIdx.x, lane = tid & 63, wid = tid >> 6;
  int quad = lane >> 4, l15 = lane & 15;
  int m0 = blockIdx.x*64, n0 = blockIdx.y*64;
  const s8v* ah = (const s8v*)Ah + ((size_t)((m0>>4) + wid))*KC*64 + lane;
  const s8v* al = (const s8v*)Al + ((size_t)((m0>>4) + wid))*KC*64 + lane;
  const s8v* bh0 = (const s8v*)Bh + ((size_t)((n0>>4) + 0))*KC*64 + lane;
  const s8v* bh1 = (const s8v*)Bh + ((size_t)((n0>>4) + 1))*KC*64 + lane;
  const s8v* bh2 = (const s8v*)Bh + ((size_t)((n0>>4) + 2))*KC*64 + lane;
  const s8v* bh3 = (const s8v*)Bh + ((size_t)((n0>>4) + 3))*KC*64 + lane;
  const s8v* bl0 = (const s8v*)Bl + ((size_t)((n0>>4) + 0))*KC*64 + lane;
  const s8v* bl1 = (const s8v*)Bl + ((size_t)((n0>>4) + 1))*KC*64 + lane;
  const s8v* bl2 = (const s8v*)Bl + ((size_t)((n0>>4) + 2))*KC*64 + lane;
  const s8v* bl3 = (const s8v*)Bl + ((size_t)((n0>>4) + 3))*KC*64 + lane;
  f4v acc[4];
  #pragma unroll
  for (int i = 0; i < 4; ++i) { acc[i][0]=0.f; acc[i][1]=0.f; acc[i][2]=0.f; acc[i][3]=0.f; }
  for (int c = 0; c < KC; ++c) {
    s8v a_h = ah[c*64];
    s8v a_l = al[c*64];
    acc[0] = __builtin_amdgcn_mfma_f32_16x16x32_bf16(a_h, bh0[c*64], acc[0], 0, 0, 0);
    acc[0] = __builtin_amdgcn_mfma_f32_16x16x32_bf16(a_h, bl0[c*64], acc[0], 0, 0, 0);
    acc[0] = __builtin_amdgcn_mfma_f32_16x16x32_bf16(a_l, bh0[c*64], acc[0], 0, 0, 0);
    acc[1] = __builtin_amdgcn_mfma_f32_16x16x32_bf16(a_h, bh1[c*64], acc[1], 0, 0, 0);
    acc[1] = __builtin_amdgcn_mfma_f32_16x16x32_bf16(a_h, bl1[c*64], acc[1], 0, 0, 0);
    acc[1] = __builtin_amdgcn_mfma_f32_16x16x32_bf16(a_l, bh1[c*64], acc[1], 0, 0, 0);
    acc[2] = __builtin_amdgcn_mfma_f32_16x16x32_bf16(a_h, bh2[c*64], acc[2], 0, 0, 0);
    acc[2] = __builtin_amdgcn_mfma_f32_16x16x32_bf16(a_h, bl2[c*64], acc[2], 0, 0, 0);
    acc[2] = __builtin_amdgcn_mfma_f32_16x16x32_bf16(a_l, bh2[c*64], acc[2], 0, 0, 0);
    acc[3] = __builtin_amdgcn_mfma_f32_16x16x32_bf16(a_h, bh3[c*64], acc[3], 0, 0, 0);
    acc[3] = __builtin_amdgcn_mfma_f32_16x16x32_bf16(a_h, bl3[c*64], acc[3], 0, 0, 0);
    acc[3] = __builtin_amdgcn_mfma_f32_16x16x32_bf16(a_l, bh3[c*64], acc[3], 0, 0, 0);
  }
  #pragma unroll
  for (int nt = 0; nt < 4; ++nt) {
    #pragma unroll
    for (int reg = 0; reg < 4; ++reg) {
      int row = m0 + wid*16 + quad*4 + reg;
      int col = n0 + nt*16 + l15;
      Z[(size_t)row*512 + col] = acc[nt][reg];
    }
  }
}

// ---------- 8. B prep: frag-major BT packs [512 rows x 4096 k]; nrm inline from degrees ----------
__global__ __launch_bounds__(256) void k_prepB(const float* __restrict__ Z, const int* __restrict__ deg1,
                                               const int* __restrict__ deg2,
                                               short* __restrict__ bph, short* __restrict__ bpl) {
  __shared__ float lds[64*65];
  int tid = threadIdx.x;
  int u0 = blockIdx.x*64, c0 = blockIdx.y*64;   // u = k-dim (node), c = BT row (n)
  const int* dg = (c0 < 256) ? deg1 : deg2;
  for (int e = tid; e < 4096; e += 256) {
    int r = e >> 6, c = e & 63;
    int d = dg[u0 + r];
    float nr = d > 0 ? (1.0f / sqrtf((float)d)) : 0.0f;
    lds[r*65 + c] = Z[(size_t)(u0+r)*512 + c0 + c] * nr;
  }
  __syncthreads();
  for (int e = tid; e < 4096; e += 256) {  // pack-major write order (coalesced)
    int j = e & 7, ln = (e >> 3) & 63, cp = (e >> 9) & 1, Tp = e >> 10;
    int q = ln >> 4, rr = ln & 15;
    float v = lds[(cp*32 + q*8 + j)*65 + (Tp*16 + rr)];
    short h, l; split2(v, h, l);
    size_t off = (((size_t)((c0>>4)+Tp)*128 + (u0>>5)+cp)*64 + ln)*8 + j;
    bph[off] = h; bpl[off] = l;
  }
}

// ---------- 9. mask GEMM v3: frag-major B, 8-wave K-split, 1-chunk-deep pipeline ----------
__global__ __launch_bounds__(512) void k_mg3(const u64* __restrict__ wmT, const u64* __restrict__ wmR,
                                             const u64* __restrict__ cmask,
                                             const short* __restrict__ bph, const short* __restrict__ bpl,
                                             const float* __restrict__ Z,
                                             const int* __restrict__ deg1, const int* __restrict__ deg2,
                                             const float* __restrict__ biasA, const float* __restrict__ biasB,
                                             float* __restrict__ h) {
  __shared__ s8v lut[256];   // byte -> 8 bf16 {0,1}
  __shared__ float tile[64*65];
  int tid = threadIdx.x;
  if (tid < 256) {
    s8v e;
    #pragma unroll
    for (int j = 0; j < 8; ++j) e[j] = ((tid >> j) & 1) ? (short)0x3F80 : (short)0;
    lut[tid] = e;
  }
  __syncthreads();
  int g = blockIdx.z;
  const u64* wm = g ? wmR : wmT;
  u64 cm = cmask[g*64 + blockIdx.x];
  int m0 = blockIdx.x*64, n0 = blockIdx.y*64;
  int lane = tid & 63, wid = tid >> 6, quad = lane >> 4, l15 = lane & 15;
  int nw = wid & 3, ks = wid >> 2;
  u64 cmw = ks ? (cm >> 32) : (cm & 0xffffffffULL);
  int kwb = ks << 5;
  int T = g*16 + (n0 >> 4) + nw;
  const s8v* BH = (const s8v*)bph + (size_t)T*128*64 + lane;
  const s8v* BL = (const s8v*)bpl + (size_t)T*128*64 + lane;
  f4v acc[4];
  #pragma unroll
  for (int i = 0; i < 4; ++i) { acc[i][0]=0.f; acc[i][1]=0.f; acc[i][2]=0.f; acc[i][3]=0.f; }
  s8v z8;
  #pragma unroll
  for (int j = 0; j < 8; ++j) z8[j] = 0;

  int kw = -1;
  u64 w0 = 0, w1 = 0, w2 = 0, w3 = 0;
  s8v b0h = z8, b0l = z8, b1h = z8, b1l = z8;
  if (cmw) {
    kw = kwb + __builtin_ctzll(cmw); cmw &= cmw - 1;
    const u64* wp = wm + (size_t)kw*4096 + m0;
    w0 = wp[l15]; w1 = wp[16 + l15]; w2 = wp[32 + l15]; w3 = wp[48 + l15];
    b0h = BH[(kw*2)*64];   b0l = BL[(kw*2)*64];
    b1h = BH[(kw*2+1)*64]; b1l = BL[(kw*2+1)*64];
  }
  while (kw >= 0) {
    int kwn = -1;
    u64 nw0 = 0, nw1 = 0, nw2 = 0, nw3 = 0;
    s8v nb0h = z8, nb0l = z8, nb1h = z8, nb1l = z8;
    if (cmw) {                                  // prefetch next chunk (mask words + B frags)
      kwn = kwb + __builtin_ctzll(cmw); cmw &= cmw - 1;
      const u64* wp = wm + (size_t)kwn*4096 + m0;
      nw0 = wp[l15]; nw1 = wp[16 + l15]; nw2 = wp[32 + l15]; nw3 = wp[48 + l15];
      nb0h = BH[(kwn*2)*64];   nb0l = BL[(kwn*2)*64];
      nb1h = BH[(kwn*2+1)*64]; nb1l = BL[(kwn*2+1)*64];
    }
    {
      unsigned sh = quad*8;
      s8v a0 = lut[(unsigned)(w0 >> sh) & 0xffu];
      s8v a1 = lut[(unsigned)(w1 >> sh) & 0xffu];
      s8v a2 = lut[(unsigned)(w2 >> sh) & 0xffu];
      s8v a3 = lut[(unsigned)(w3 >> sh) & 0xffu];
      acc[0] = __builtin_amdgcn_mfma_f32_16x16x32_bf16(a0, b0h, acc[0], 0, 0, 0);
      acc[0] = __builtin_amdgcn_mfma_f32_16x16x32_bf16(a0, b0l, acc[0], 0, 0, 0);
      acc[1] = __builtin_amdgcn_mfma_f32_16x16x32_bf16(a1, b0h, acc[1], 0, 0, 0);
      acc[1] = __builtin_amdgcn_mfma_f32_16x16x32_bf16(a1, b0l, acc[1], 0, 0, 0);
      acc[2] = __builtin_amdgcn_mfma_f32_16x16x32_bf16(a2, b0h, acc[2], 0, 0, 0);
      acc[2] = __builtin_amdgcn_mfma_f32_16x16x32_bf16(a2, b0l, acc[2], 0, 0, 0);
      acc[3] = __builtin_amdgcn_mfma_f32_16x16x32_bf16(a3, b0h, acc[3], 0, 0, 0);
      acc[3] = __builtin_amdgcn_mfma_f32_16x16x32_bf16(a3, b0l, acc[3], 0, 0, 0);
      sh = 32 + quad*8;
      a0 = lut[(unsigned)(w0 >> sh) & 0xffu];
      a1 = lut[(unsigned)(w1 >> sh) & 0xffu];
      a2 = lut[(unsigned)(w2 >> sh) & 0xffu];
      a3 = lut[(unsigned)(w3 >> sh) & 0xffu];
      acc[0] = __builtin_amdgcn_mfma_f32_16x16x32_bf16(a0, b1h, acc[0], 0, 0, 0);
      acc[0] = __builtin_amdgcn_mfma_f32_16x16x32_bf16(a0, b1l, acc[0], 0, 0, 0);
      acc[1] = __builtin_amdgcn_mfma_f32_16x16x32_bf16(a1, b1h, acc[1], 0, 0, 0);
      acc[1] = __builtin_amdgcn_mfma_f32_16x16x32_bf16(a1, b1l, acc[1], 0, 0, 0);
      acc[2] = __builtin_amdgcn_mfma_f32_16x16x32_bf16(a2, b1h, acc[2], 0, 0, 0);
      acc[2] = __builtin_amdgcn_mfma_f32_16x16x32_bf16(a2, b1l, acc[2], 0, 0, 0);
      acc[3] = __builtin_amdgcn_mfma_f32_16x16x32_bf16(a3, b1h, acc[3], 0, 0, 0);
      acc[3] = __builtin_amdgcn_mfma_f32_16x16x32_bf16(a3, b1l, acc[3], 0, 0, 0);
    }
    kw = kwn;
    w0 = nw0; w1 = nw1; w2 = nw2; w3 = nw3;
    b0h = nb0h; b0l = nb0l; b1h = nb1h; b1l = nb1l;
  }
  // combine K-halves through LDS; epilogue by ks==0 waves
  int nl = nw*16 + l15;
  if (ks == 1) {
    #pragma unroll
    for (int mf = 0; mf < 4; ++mf) {
      #pragma unroll
      for (int reg = 0; reg < 4; ++reg)
        tile[(mf*16 + quad*4 + reg)*65 + nl] = acc[mf][reg];
    }
  }
  __syncthreads();
  if (ks == 0) {
    int n = n0 + nl;
    const int* dgp = g ? deg2 : deg1;
    float bn = (g ? biasB : biasA)[n];
    int zoff = g*256;
    #pragma unroll
    for (int mf = 0; mf < 4; ++mf) {
      #pragma unroll
      for (int reg = 0; reg < 4; ++reg) {
        int v = m0 + mf*16 + quad*4 + reg;
        float s = acc[mf][reg] + tile[(mf*16 + quad*4 + reg)*65 + nl];
        int d = dgp[v];
        float sfac = 0.0f;
        if (d > 0) { float df = (float)d; sfac = (1.0f / sqrtf(df)) / df; }
        float val = Z[(size_t)v*512 + zoff + n] + sfac*s + bn;
        h[(size_t)v*512 + zoff + n] = fmaxf(val, 0.0f);
      }
    }
  }
}

// ---------- 10. BN sums (coalesced one-pass, fp32 atomics) ----------
__global__ __launch_bounds__(256) void k_bnsum(const float* __restrict__ h, float* __restrict__ acc) {
  int b = blockIdx.x, t = threadIdx.x;
  float s0 = 0.f, s1 = 0.f, q0 = 0.f, q1 = 0.f;
  const float2* hp = (const float2*)h;
  for (int r = b*16; r < b*16 + 16; ++r) {
    float2 v = hp[(size_t)r*256 + t];
    s0 += v.x; s1 += v.y; q0 += v.x*v.x; q1 += v.y*v.y;
  }
  int c0 = t*2;
  atomicAdd(&acc[c0*2 + 0], s0);
  atomicAdd(&acc[c0*2 + 1], q0);
  atomicAdd(&acc[c0*2 + 2], s1);
  atomicAdd(&acc[c0*2 + 3], q1);
}

// ---------- 11. BN apply + split to frag-major hn packs (K=512) ----------
__global__ __launch_bounds__(256) void k_bnapply_split(const float* __restrict__ h, const float* __restrict__ acc,
                                                       const float* __restrict__ gamma, const float* __restrict__ beta,
                                                       short* __restrict__ hPh, short* __restrict__ hPl) {
  int i = blockIdx.x*256 + threadIdx.x;       // 524288 float4s
  float4 v = ((const float4*)h)[i];
  int r = i >> 7;
  int colb = (i & 127) * 4;
  float vv[4] = {v.x, v.y, v.z, v.w};
  short4 hh, ll;
  short* hp = (short*)&hh; short* lp = (short*)&ll;
  #pragma unroll
  for (int j = 0; j < 4; ++j) {
    int col = colb + j;
    float mean = acc[col*2] * (1.0f/4096.0f);
    float var  = acc[col*2 + 1] * (1.0f/4096.0f) - mean*mean;
    float inv  = rsqrtf(var + 1e-5f);
    float sc = gamma[col] * inv;
    float sh = beta[col] - mean * sc;
    split2(vv[j]*sc + sh, hp[j], lp[j]);
  }
  size_t off = packoff(r, colb, 16);          // colb%8 in {0,4}: 4 contiguous shorts
  ((short4*)hPh)[off >> 2] = hh;
  ((short4*)hPl)[off >> 2] = ll;
}

// ---------- 12. final: inline BN2 + readout + modality softmax mix ----------
__global__ __launch_bounds__(256) void k_final2(const float* __restrict__ h, const float* __restrict__ acc2,
                                                const float* __restrict__ gamma2, const float* __restrict__ beta2,
                                                const float* __restrict__ w_ro, const float* __restrict__ cl,
                                                float* __restrict__ out) {
  int node = blockIdx.x;
  int t = threadIdx.x, m = t >> 6, lane = t & 63;
  const float* row = h + (size_t)(m*1024 + node)*512;
  float a0 = 0.f, a1 = 0.f, a2 = 0.f, a3 = 0.f;
  for (int it = 0; it < 8; ++it) {
    int k = lane + it*64;
    float mean = acc2[k*2] * (1.0f/4096.0f);
    float var  = acc2[k*2 + 1] * (1.0f/4096.0f) - mean*mean;
    float inv  = rsqrtf(var + 1e-5f);
    float sc = gamma2[k] * inv;
    float sh = beta2[k] - mean * sc;
    float hv = row[k]*sc + sh;
    float4 w = ((const float4*)w_ro)[k];
    a0 += hv*w.x; a1 += hv*w.y; a2 += hv*w.z; a3 += hv*w.w;
  }
  for (int off = 32; off > 0; off >>= 1) {
    a0 += __shfl_down(a0, off); a1 += __shfl_down(a1, off);
    a2 += __shfl_down(a2, off); a3 += __shfl_down(a3, off);
  }
  __shared__ float part[4][4];
  if (lane == 0) { part[m][0]=a0; part[m][1]=a1; part[m][2]=a2; part[m][3]=a3; }
  __syncthreads();
  if (t < 4) {
    float c0 = cl[0], c1 = cl[1], c2 = cl[2], c3 = cl[3];
    float mx = fmaxf(fmaxf(c0,c1), fmaxf(c2,c3));
    float e0 = expf(c0-mx), e1 = expf(c1-mx), e2 = expf(c2-mx), e3 = expf(c3-mx);
    float inv = 1.0f/(e0+e1+e2+e3);
    float r = (e0*part[0][t] + e1*part[1][t] + e2*part[2][t] + e3*part[3][t]) * inv;
    out[node*4 + t] = r;
  }
}

extern "C" void kernel_launch(void* const* d_in, const int* in_sizes, int n_in,
                              void* d_out, int out_size, void* d_ws, size_t ws_size,
                              hipStream_t stream) {
  const float* features = (const float*)d_in[0];
  const float* sparse   = (const float*)d_in[1];
  const float* cmix     = (const float*)d_in[2];
  const float* wAC1 = (const float*)d_in[3];
  const float* bAC1 = (const float*)d_in[4];
  const float* wCA1 = (const float*)d_in[5];
  const float* bCA1 = (const float*)d_in[6];
  const float* wAC2 = (const float*)d_in[7];
  const float* bAC2 = (const float*)d_in[8];
  const float* wCA2 = (const float*)d_in[9];
  const float* bCA2 = (const float*)d_in[10];
  const float* gamma1 = (const float*)d_in[11];
  const float* beta1  = (const float*)d_in[12];
  const float* gamma2 = (const float*)d_in[13];
  const float* beta2  = (const float*)d_in[14];
  const float* w_ro   = (const float*)d_in[15];
  float* out = (float*)d_out;

  char* ws = (char*)d_ws;
  const size_t MB = 1024ull*1024ull, KB = 1024ull;
  u64*   bits    = (u64*)(ws + 0);               // 1.25 MB
  u64*   mask    = (u64*)(ws + 2*MB);            // 2 MB (row-major)
  u64*   mask_wm = (u64*)(ws + 4*MB);            // 2 MB (word-major)
  u64*   maskT_wm= (u64*)(ws + 6*MB);            // 2 MB (word-major)
  int*   deg1    = (int*)(ws + 8*MB);            // 16 KB  [zeroed]
  float* bnacc1  = (float*)(ws + 8*MB + 16*KB);  // 4 KB   [zeroed]
  float* bnacc2  = (float*)(ws + 8*MB + 20*KB);  // 4 KB   [zeroed]
  int*   deg2    = (int*)(ws + 8*MB + 24*KB);    // 16 KB
  u64*   cmask   = (u64*)(ws + 8*MB + 40*KB);    // 1 KB
  short* WT1h  = (short*)(ws + 9*MB);            // 128 KB (frag-major pack)
  short* WT1l  = (short*)(ws + 9*MB + 128*KB);   // 128 KB
  short* WT2h  = (short*)(ws + 9*MB + 256*KB);   // 512 KB
  short* WT2l  = (short*)(ws + 9*MB + 768*KB);   // 512 KB
  // region [11MB,23MB): Apack/Bpack (dead after corr) -> BT packs -> hn packs -> BT packs (L2)
  short* Apack = (short*)(ws + 11*MB);           // 6 MB (11-17)
  short* Bpack = (short*)(ws + 17*MB);           // 6 MB (17-23)
  short* BTh   = (short*)(ws + 11*MB);           // 4 MB (frag-major)
  short* BTl   = (short*)(ws + 15*MB);           // 4 MB
  short* hnPh  = (short*)(ws + 11*MB);           // 4 MB (frag-major, K=512)
  short* hnPl  = (short*)(ws + 15*MB);           // 4 MB
  short* fPh   = (short*)(ws + 23*MB);           // 1 MB (frag-major, K=128; dead after L1 dense)
  short* fPl   = (short*)(ws + 24*MB);           // 1 MB
  float* Z     = (float*)(ws + 25*MB);           // 8 MB
  float* h     = (float*)(ws + 33*MB);           // 8 MB (total 41 MB)

  hipMemsetAsync(ws + 8*MB, 0, 24*KB, stream);   // deg1 + bnacc1 + bnacc2

  // graph prep
  k_rownorm<<<dim3(4096), dim3(128), 0, stream>>>(features, Apack, Bpack, fPh, fPl);
  k_corr2<<<dim3(16,16,10), dim3(256), 0, stream>>>(Apack, Bpack, sparse, bits);
  k_maskrows<<<dim3(4096), dim3(64), 0, stream>>>(bits, mask, mask_wm, deg2);
  k_bittrans2<<<dim3(64,4), dim3(256), 0, stream>>>(mask, maskT_wm, deg1);
  k_chunkmask<<<dim3(64,2), dim3(64), 0, stream>>>(maskT_wm, mask_wm, cmask);
  k_prepWT<<<dim3(2,8), dim3(256), 0, stream>>>(wAC1, wCA1, WT1h, WT1l, 128);
  k_prepWT<<<dim3(8,8), dim3(256), 0, stream>>>(wAC2, wCA2, WT2h, WT2l, 512);

  // layer 1:  h = relu(Z + sfac*(bits @ (nrm*Z)) + b)
  k_dense2<<<dim3(64,8), dim3(256), 0, stream>>>(fPh, fPl, WT1h, WT1l, Z, 4);
  k_prepB<<<dim3(64,8), dim3(256), 0, stream>>>(Z, deg1, deg2, BTh, BTl);
  k_mg3<<<dim3(64,4,2), dim3(512), 0, stream>>>(maskT_wm, mask_wm, cmask, BTh, BTl, Z,
                                                deg1, deg2, bAC1, bCA1, h);
  k_bnsum<<<dim3(256), dim3(256), 0, stream>>>(h, bnacc1);
  k_bnapply_split<<<dim3(2048), dim3(256), 0, stream>>>(h, bnacc1, gamma1, beta1, hnPh, hnPl);

  // layer 2
  k_dense2<<<dim3(64,8), dim3(256), 0, stream>>>(hnPh, hnPl, WT2h, WT2l, Z, 16);
  k_prepB<<<dim3(64,8), dim3(256), 0, stream>>>(Z, deg1, deg2, BTh, BTl);
  k_mg3<<<dim3(64,4,2), dim3(512), 0, stream>>>(maskT_wm, mask_wm, cmask, BTh, BTl, Z,
                                                deg1, deg2, bAC2, bCA2, h);
  k_bnsum<<<dim3(256), dim3(256), 0, stream>>>(h, bnacc2);

  // readout (BN2 folded inline)
  k_final2<<<dim3(1024), dim3(256), 0, stream>>>(h, bnacc2, gamma2, beta2, w_ro, cmix, out);
}

// Round 7
// 353.777 us; speedup vs baseline: 1.8110x; 1.0777x over previous
//
#include <hip/hip_runtime.h>

typedef unsigned long long u64;
typedef __attribute__((ext_vector_type(8))) short s8v;   // 8 bf16 = 4 VGPRs (MFMA A/B frag)
typedef __attribute__((ext_vector_type(4))) float f4v;   // MFMA C/D frag

__device__ __constant__ int c_pi[10]   = {0,1,2,3,0,1,2,3,3,3};
__device__ __constant__ int c_pj[10]   = {0,1,2,3,3,3,3,0,1,2};
__device__ __constant__ int c_dri[10]  = {1,5,8,10,4,7,9,4,7,9};
__device__ __constant__ int c_diag[10] = {1,1,1,1,0,0,0,0,0,0};
__device__ __constant__ int c_src[16]  = {-1,7,8,9,  4,-1,8,9,  5,5,-1,9,  6,6,6,-1};

// round-to-nearest bf16
__device__ inline unsigned short bf16rn(float v) {
  unsigned int u = __float_as_uint(v);
  unsigned int r = u + 0x7fffu + ((u >> 16) & 1u);
  return (unsigned short)(r >> 16);
}
__device__ inline void split2(float v, short& h, short& l) {
  unsigned short hs = bf16rn(v);
  float fh = __uint_as_float(((unsigned int)hs) << 16);
  h = (short)hs;
  l = (short)bf16rn(v - fh);
}
__device__ inline void split3(float v, short& h, short& m, short& l) {
  unsigned short hs = bf16rn(v);
  float fh = __uint_as_float(((unsigned int)hs) << 16);
  float r1 = v - fh;
  unsigned short ms = bf16rn(r1);
  float fm = __uint_as_float(((unsigned int)ms) << 16);
  h = (short)hs; m = (short)ms;
  l = (short)bf16rn(r1 - fm);
}

// fragment-major pack offset: row r, k-index k, KC = K/32 chunks
//   tile T=r>>4, rr=r&15, chunk c=k>>5, quad q=(k>>3)&3, j=k&7
//   off = ((T*KC + c)*64 + q*16 + rr)*8 + j  -> lane (q*16+rr) reads 16B at +lane*16
__device__ inline size_t packoff(int row, int k, int KC) {
  int T = row >> 4, rr = row & 15;
  int c = k >> 5, q = (k >> 3) & 3, j = k & 7;
  return (((size_t)T*KC + c)*64 + q*16 + rr)*8 + j;
}

// ---------- 1. center+normalize rows -> 3 base split packs (K=128); feature pack (K=128) ----------
__global__ __launch_bounds__(128) void k_rownorm(const float* __restrict__ f,
                                                 short* __restrict__ yhP, short* __restrict__ ymP,
                                                 short* __restrict__ ylP,
                                                 short* __restrict__ fPh, short* __restrict__ fPl) {
  int r = blockIdx.x, t = threadIdx.x;
  __shared__ float red[128];
  float v = f[r*128 + t];
  red[t] = v; __syncthreads();
  for (int s = 64; s > 0; s >>= 1) { if (t < s) red[t] += red[t+s]; __syncthreads(); }
  float mean = red[0] * (1.0f/128.0f);
  __syncthreads();
  float xc = v - mean;
  red[t] = xc*xc; __syncthreads();
  for (int s = 64; s > 0; s >>= 1) { if (t < s) red[t] += red[t+s]; __syncthreads(); }
  float inv = 1.0f / sqrtf(red[0]);
  short h, m, l;
  split3(xc*inv, h, m, l);
  size_t o = packoff(r, t, 4);
  yhP[o] = h; ymP[o] = m; ylP[o] = l;
  short fh, fl; split2(v, fh, fl);
  fPh[o] = fh; fPl[o] = fl;
}

// ---------- 2. correlation bit blocks: base-pack GEMM, 6 chain combos from registers ----------
__global__ __launch_bounds__(256) void k_corr3(const short* __restrict__ yhP, const short* __restrict__ ymP,
                                               const short* __restrict__ ylP,
                                               const float* __restrict__ sparse, u64* __restrict__ bits) {
  int z = blockIdx.z;
  int bx = blockIdx.x, by = blockIdx.y;
  int dg = c_diag[z];
  if (dg && by < bx) return;          // symmetric diagonal blocks: upper triangle only
  int a0 = c_pi[z]*1024 + bx*64;
  int b0 = c_pj[z]*1024 + by*64;
  int tid = threadIdx.x, lane = tid & 63, wid = tid >> 6;
  int quad = lane >> 4, l15 = lane & 15;
  const s8v* AH = (const s8v*)yhP + ((size_t)((a0>>4) + wid))*4*64 + lane;
  const s8v* AM = (const s8v*)ymP + ((size_t)((a0>>4) + wid))*4*64 + lane;
  const s8v* AL = (const s8v*)ylP + ((size_t)((a0>>4) + wid))*4*64 + lane;
  const s8v* BH = (const s8v*)yhP + ((size_t)(b0>>4))*4*64 + lane;
  const s8v* BM = (const s8v*)ymP + ((size_t)(b0>>4))*4*64 + lane;
  const s8v* BL = (const s8v*)ylP + ((size_t)(b0>>4))*4*64 + lane;
  f4v acc[4];
  #pragma unroll
  for (int i = 0; i < 4; ++i) { acc[i][0]=0.f; acc[i][1]=0.f; acc[i][2]=0.f; acc[i][3]=0.f; }
  for (int c = 0; c < 4; ++c) {
    s8v a_h = AH[c*64];
    s8v a_m = AM[c*64];
    s8v a_l = AL[c*64];
    #pragma unroll
    for (int nt = 0; nt < 4; ++nt) {
      s8v b_h = BH[(nt*4 + c)*64];
      s8v b_m = BM[(nt*4 + c)*64];
      s8v b_l = BL[(nt*4 + c)*64];
      acc[nt] = __builtin_amdgcn_mfma_f32_16x16x32_bf16(a_h, b_h, acc[nt], 0, 0, 0);
      acc[nt] = __builtin_amdgcn_mfma_f32_16x16x32_bf16(a_m, b_m, acc[nt], 0, 0, 0);
      acc[nt] = __builtin_amdgcn_mfma_f32_16x16x32_bf16(a_h, b_m, acc[nt], 0, 0, 0);
      acc[nt] = __builtin_amdgcn_mfma_f32_16x16x32_bf16(a_m, b_h, acc[nt], 0, 0, 0);
      acc[nt] = __builtin_amdgcn_mfma_f32_16x16x32_bf16(a_h, b_l, acc[nt], 0, 0, 0);
      acc[nt] = __builtin_amdgcn_mfma_f32_16x16x32_bf16(a_l, b_h, acc[nt], 0, 0, 0);
    }
  }
  __shared__ unsigned char lby[64*68];
  float sv = sparse[c_dri[z]];
  float dr = 1.0f / (1.0f + expf(-sv));
  #pragma unroll
  for (int nt = 0; nt < 4; ++nt) {
    #pragma unroll
    for (int reg = 0; reg < 4; ++reg) {
      int lr = wid*16 + quad*4 + reg;
      int lc = nt*16 + l15;
      int ga = bx*64 + lr, gb = by*64 + lc;
      int on = (fabsf(acc[nt][reg]) > dr) && !(dg && (ga == gb));
      lby[lr*68 + lc] = (unsigned char)on;
    }
  }
  __syncthreads();
  if (tid < 64) {
    u64 w = 0;
    for (int c2 = 0; c2 < 64; ++c2) w |= ((u64)lby[tid*68 + c2]) << c2;
    bits[z*16384 + (bx*64 + tid)*16 + by] = w;
    if (dg && bx != by) {             // mirror tile for the skipped lower triangle
      u64 wt = 0;
      for (int c2 = 0; c2 < 64; ++c2) wt |= ((u64)lby[c2*68 + tid]) << c2;
      bits[z*16384 + (by*64 + tid)*16 + bx] = wt;
    }
  }
}

// ---------- 3. mask rows (boolean A@C) + mask_wm + graph-2 degrees ----------
__global__ __launch_bounds__(64) void k_maskrows(const u64* __restrict__ bits, u64* __restrict__ mask,
                                                 u64* __restrict__ mask_wm, int* __restrict__ deg2) {
  int u = blockIdx.x;
  int i = u >> 10, a = u & 1023;
  int t = threadIdx.x;
  __shared__ u64 drow[16];
  if (t < 16) drow[t] = bits[i*16384 + a*16 + t];
  __syncthreads();
  int j = t >> 4, wl = t & 15;
  u64 out;
  if (j == i) {
    out = drow[wl];
  } else {
    const u64* S = bits + c_src[i*4 + j]*16384;
    out = 0;
    for (int w2 = 0; w2 < 16; ++w2) {
      u64 m = drow[w2];
      while (m) {
        int b = __builtin_ctzll(m); m &= m - 1;
        out |= S[(w2*64 + b)*16 + wl];
      }
    }
  }
  mask[(size_t)u*64 + t] = out;
  mask_wm[(size_t)t*4096 + u] = out;
  int cnt = __popcll(out);
  for (int off = 32; off > 0; off >>= 1) cnt += __shfl_down(cnt, off);
  if (t == 0) deg2[u] = cnt;
}

// ---------- 4. bit transpose -> maskT word-major + deg1 atomics ----------
__global__ __launch_bounds__(256) void k_bittrans2(const u64* __restrict__ mask, u64* __restrict__ wmT,
                                                   int* __restrict__ deg1) {
  __shared__ u64 tile[4096];   // 64 rows x 64 words = 32 KB
  int tI = blockIdx.x, tid = threadIdx.x;
  for (int e = tid; e < 4096; e += 256) tile[e] = mask[(size_t)tI*4096 + e];
  __syncthreads();
  int wv = tid >> 6, lane = tid & 63;
  int tJ0 = blockIdx.y*16;
  for (int j = 0; j < 4; ++j) {
    int tJ = tJ0 + wv*4 + j;
    u64 o = 0;
    #pragma unroll 8
    for (int k = 0; k < 64; ++k) o |= ((tile[k*64 + tJ] >> lane) & 1ULL) << k;
    wmT[(size_t)tI*4096 + tJ*64 + lane] = o;
    atomicAdd(&deg1[tJ*64 + lane], __popcll(o));
  }
}

// ---------- 5. per-(graph, m-tile) non-empty-chunk bitmask ----------
__global__ __launch_bounds__(64) void k_chunkmask(const u64* __restrict__ wmT, const u64* __restrict__ wmR,
                                                  u64* __restrict__ cmask) {
  int g = blockIdx.y, mt = blockIdx.x, kw = threadIdx.x;
  const u64* p = (g ? wmR : wmT) + (size_t)kw*4096 + mt*64;
  u64 o = 0;
  #pragma unroll 8
  for (int i = 0; i < 64; ++i) o |= p[i];
  unsigned long long b = __ballot(o != 0ULL);
  if (kw == 0) cmask[g*64 + mt] = b;
}

// ---------- 6. weight prep: [Wa|Wb] (Kx256 each) -> frag-major packs [512 rows x K] ----------
__global__ __launch_bounds__(256) void k_prepWT(const float* __restrict__ Wa, const float* __restrict__ Wb,
                                                short* __restrict__ wph, short* __restrict__ wpl, int K) {
  __shared__ float lds[64*65];
  int tid = threadIdx.x;
  int k0 = blockIdx.x*64, n0 = blockIdx.y*64;
  const float* W = (n0 < 256) ? Wa : Wb;
  int nc0 = n0 & 255;
  for (int e = tid; e < 4096; e += 256) {
    int r = e >> 6, c = e & 63;           // r = k-local, c = n-local
    lds[r*65 + c] = W[(size_t)(k0+r)*256 + nc0 + c];
  }
  __syncthreads();
  int KC = K >> 5;
  for (int e = tid; e < 4096; e += 256) {  // pack-major write order (coalesced)
    int j = e & 7, ln = (e >> 3) & 63, cp = (e >> 9) & 1, Tp = e >> 10;
    int q = ln >> 4, rr = ln & 15;
    float v = lds[(cp*32 + q*8 + j)*65 + (Tp*16 + rr)];
    short h, l; split2(v, h, l);
    size_t off = (((size_t)((n0>>4)+Tp)*KC + (k0>>5)+cp)*64 + ln)*8 + j;
    wph[off] = h; wpl[off] = l;
  }
}

// ---------- 7. dense GEMM on frag-major packs: Z[4096x512] = A @ W^T, 3-chain ----------
__global__ __launch_bounds__(256) void k_dense2(const short* __restrict__ Ah, const short* __restrict__ Al,
                                                const short* __restrict__ Bh, const short* __restrict__ Bl,
                                                float* __restrict__ Z, int KC) {
  int tid = threadIdx.x, lane = tid & 63, wid = tid >> 6;
  int quad = lane >> 4, l15 = lane & 15;
  int m0 = blockIdx.x*64, n0 = blockIdx.y*64;
  const s8v* ah = (const s8v*)Ah + ((size_t)((m0>>4) + wid))*KC*64 + lane;
  const s8v* al = (const s8v*)Al + ((size_t)((m0>>4) + wid))*KC*64 + lane;
  const s8v* bh0 = (const s8v*)Bh + ((size_t)((n0>>4) + 0))*KC*64 + lane;
  const s8v* bh1 = (const s8v*)Bh + ((size_t)((n0>>4) + 1))*KC*64 + lane;
  const s8v* bh2 = (const s8v*)Bh + ((size_t)((n0>>4) + 2))*KC*64 + lane;
  const s8v* bh3 = (const s8v*)Bh + ((size_t)((n0>>4) + 3))*KC*64 + lane;
  const s8v* bl0 = (const s8v*)Bl + ((size_t)((n0>>4) + 0))*KC*64 + lane;
  const s8v* bl1 = (const s8v*)Bl + ((size_t)((n0>>4) + 1))*KC*64 + lane;
  const s8v* bl2 = (const s8v*)Bl + ((size_t)((n0>>4) + 2))*KC*64 + lane;
  const s8v* bl3 = (const s8v*)Bl + ((size_t)((n0>>4) + 3))*KC*64 + lane;
  f4v acc[4];
  #pragma unroll
  for (int i = 0; i < 4; ++i) { acc[i][0]=0.f; acc[i][1]=0.f; acc[i][2]=0.f; acc[i][3]=0.f; }
  for (int c = 0; c < KC; ++c) {
    s8v a_h = ah[c*64];
    s8v a_l = al[c*64];
    acc[0] = __builtin_amdgcn_mfma_f32_16x16x32_bf16(a_h, bh0[c*64], acc[0], 0, 0, 0);
    acc[0] = __builtin_amdgcn_mfma_f32_16x16x32_bf16(a_h, bl0[c*64], acc[0], 0, 0, 0);
    acc[0] = __builtin_amdgcn_mfma_f32_16x16x32_bf16(a_l, bh0[c*64], acc[0], 0, 0, 0);
    acc[1] = __builtin_amdgcn_mfma_f32_16x16x32_bf16(a_h, bh1[c*64], acc[1], 0, 0, 0);
    acc[1] = __builtin_amdgcn_mfma_f32_16x16x32_bf16(a_h, bl1[c*64], acc[1], 0, 0, 0);
    acc[1] = __builtin_amdgcn_mfma_f32_16x16x32_bf16(a_l, bh1[c*64], acc[1], 0, 0, 0);
    acc[2] = __builtin_amdgcn_mfma_f32_16x16x32_bf16(a_h, bh2[c*64], acc[2], 0, 0, 0);
    acc[2] = __builtin_amdgcn_mfma_f32_16x16x32_bf16(a_h, bl2[c*64], acc[2], 0, 0, 0);
    acc[2] = __builtin_amdgcn_mfma_f32_16x16x32_bf16(a_l, bh2[c*64], acc[2], 0, 0, 0);
    acc[3] = __builtin_amdgcn_mfma_f32_16x16x32_bf16(a_h, bh3[c*64], acc[3], 0, 0, 0);
    acc[3] = __builtin_amdgcn_mfma_f32_16x16x32_bf16(a_h, bl3[c*64], acc[3], 0, 0, 0);
    acc[3] = __builtin_amdgcn_mfma_f32_16x16x32_bf16(a_l, bh3[c*64], acc[3], 0, 0, 0);
  }
  #pragma unroll
  for (int nt = 0; nt < 4; ++nt) {
    #pragma unroll
    for (int reg = 0; reg < 4; ++reg) {
      int row = m0 + wid*16 + quad*4 + reg;
      int col = n0 + nt*16 + l15;
      Z[(size_t)row*512 + col] = acc[nt][reg];
    }
  }
}

// ---------- 8. B prep: frag-major BT packs [512 rows x 4096 k]; nrm inline from degrees ----------
__global__ __launch_bounds__(256) void k_prepB(const float* __restrict__ Z, const int* __restrict__ deg1,
                                               const int* __restrict__ deg2,
                                               short* __restrict__ bph, short* __restrict__ bpl) {
  __shared__ float lds[64*65];
  int tid = threadIdx.x;
  int u0 = blockIdx.x*64, c0 = blockIdx.y*64;   // u = k-dim (node), c = BT row (n)
  const int* dg = (c0 < 256) ? deg1 : deg2;
  for (int e = tid; e < 4096; e += 256) {
    int r = e >> 6, c = e & 63;
    int d = dg[u0 + r];
    float nr = d > 0 ? (1.0f / sqrtf((float)d)) : 0.0f;
    lds[r*65 + c] = Z[(size_t)(u0+r)*512 + c0 + c] * nr;
  }
  __syncthreads();
  for (int e = tid; e < 4096; e += 256) {  // pack-major write order (coalesced)
    int j = e & 7, ln = (e >> 3) & 63, cp = (e >> 9) & 1, Tp = e >> 10;
    int q = ln >> 4, rr = ln & 15;
    float v = lds[(cp*32 + q*8 + j)*65 + (Tp*16 + rr)];
    short h, l; split2(v, h, l);
    size_t off = (((size_t)((c0>>4)+Tp)*128 + (u0>>5)+cp)*64 + ln)*8 + j;
    bph[off] = h; bpl[off] = l;
  }
}

// ---------- 9. mask GEMM v3: frag-major B, 8-wave K-split, 1-chunk-deep pipeline ----------
__global__ __launch_bounds__(512) void k_mg3(const u64* __restrict__ wmT, const u64* __restrict__ wmR,
                                             const u64* __restrict__ cmask,
                                             const short* __restrict__ bph, const short* __restrict__ bpl,
                                             const float* __restrict__ Z,
                                             const int* __restrict__ deg1, const int* __restrict__ deg2,
                                             const float* __restrict__ biasA, const float* __restrict__ biasB,
                                             float* __restrict__ h) {
  __shared__ s8v lut[256];   // byte -> 8 bf16 {0,1}
  __shared__ float tile[64*65];
  int tid = threadIdx.x;
  if (tid < 256) {
    s8v e;
    #pragma unroll
    for (int j = 0; j < 8; ++j) e[j] = ((tid >> j) & 1) ? (short)0x3F80 : (short)0;
    lut[tid] = e;
  }
  __syncthreads();
  int g = blockIdx.z;
  const u64* wm = g ? wmR : wmT;
  u64 cm = cmask[g*64 + blockIdx.x];
  int m0 = blockIdx.x*64, n0 = blockIdx.y*64;
  int lane = tid & 63, wid = tid >> 6, quad = lane >> 4, l15 = lane & 15;
  int nw = wid & 3, ks = wid >> 2;
  u64 cmw = ks ? (cm >> 32) : (cm & 0xffffffffULL);
  int kwb = ks << 5;
  int T = g*16 + (n0 >> 4) + nw;
  const s8v* BH = (const s8v*)bph + (size_t)T*128*64 + lane;
  const s8v* BL = (const s8v*)bpl + (size_t)T*128*64 + lane;
  f4v acc[4];
  #pragma unroll
  for (int i = 0; i < 4; ++i) { acc[i][0]=0.f; acc[i][1]=0.f; acc[i][2]=0.f; acc[i][3]=0.f; }
  s8v z8;
  #pragma unroll
  for (int j = 0; j < 8; ++j) z8[j] = 0;

  int kw = -1;
  u64 w0 = 0, w1 = 0, w2 = 0, w3 = 0;
  s8v b0h = z8, b0l = z8, b1h = z8, b1l = z8;
  if (cmw) {
    kw = kwb + __builtin_ctzll(cmw); cmw &= cmw - 1;
    const u64* wp = wm + (size_t)kw*4096 + m0;
    w0 = wp[l15]; w1 = wp[16 + l15]; w2 = wp[32 + l15]; w3 = wp[48 + l15];
    b0h = BH[(kw*2)*64];   b0l = BL[(kw*2)*64];
    b1h = BH[(kw*2+1)*64]; b1l = BL[(kw*2+1)*64];
  }
  while (kw >= 0) {
    int kwn = -1;
    u64 nw0 = 0, nw1 = 0, nw2 = 0, nw3 = 0;
    s8v nb0h = z8, nb0l = z8, nb1h = z8, nb1l = z8;
    if (cmw) {                                  // prefetch next chunk (mask words + B frags)
      kwn = kwb + __builtin_ctzll(cmw); cmw &= cmw - 1;
      const u64* wp = wm + (size_t)kwn*4096 + m0;
      nw0 = wp[l15]; nw1 = wp[16 + l15]; nw2 = wp[32 + l15]; nw3 = wp[48 + l15];
      nb0h = BH[(kwn*2)*64];   nb0l = BL[(kwn*2)*64];
      nb1h = BH[(kwn*2+1)*64]; nb1l = BL[(kwn*2+1)*64];
    }
    {
      unsigned sh = quad*8;
      s8v a0 = lut[(unsigned)(w0 >> sh) & 0xffu];
      s8v a1 = lut[(unsigned)(w1 >> sh) & 0xffu];
      s8v a2 = lut[(unsigned)(w2 >> sh) & 0xffu];
      s8v a3 = lut[(unsigned)(w3 >> sh) & 0xffu];
      acc[0] = __builtin_amdgcn_mfma_f32_16x16x32_bf16(a0, b0h, acc[0], 0, 0, 0);
      acc[0] = __builtin_amdgcn_mfma_f32_16x16x32_bf16(a0, b0l, acc[0], 0, 0, 0);
      acc[1] = __builtin_amdgcn_mfma_f32_16x16x32_bf16(a1, b0h, acc[1], 0, 0, 0);
      acc[1] = __builtin_amdgcn_mfma_f32_16x16x32_bf16(a1, b0l, acc[1], 0, 0, 0);
      acc[2] = __builtin_amdgcn_mfma_f32_16x16x32_bf16(a2, b0h, acc[2], 0, 0, 0);
      acc[2] = __builtin_amdgcn_mfma_f32_16x16x32_bf16(a2, b0l, acc[2], 0, 0, 0);
      acc[3] = __builtin_amdgcn_mfma_f32_16x16x32_bf16(a3, b0h, acc[3], 0, 0, 0);
      acc[3] = __builtin_amdgcn_mfma_f32_16x16x32_bf16(a3, b0l, acc[3], 0, 0, 0);
      sh = 32 + quad*8;
      a0 = lut[(unsigned)(w0 >> sh) & 0xffu];
      a1 = lut[(unsigned)(w1 >> sh) & 0xffu];
      a2 = lut[(unsigned)(w2 >> sh) & 0xffu];
      a3 = lut[(unsigned)(w3 >> sh) & 0xffu];
      acc[0] = __builtin_amdgcn_mfma_f32_16x16x32_bf16(a0, b1h, acc[0], 0, 0, 0);
      acc[0] = __builtin_amdgcn_mfma_f32_16x16x32_bf16(a0, b1l, acc[0], 0, 0, 0);
      acc[1] = __builtin_amdgcn_mfma_f32_16x16x32_bf16(a1, b1h, acc[1], 0, 0, 0);
      acc[1] = __builtin_amdgcn_mfma_f32_16x16x32_bf16(a1, b1l, acc[1], 0, 0, 0);
      acc[2] = __builtin_amdgcn_mfma_f32_16x16x32_bf16(a2, b1h, acc[2], 0, 0, 0);
      acc[2] = __builtin_amdgcn_mfma_f32_16x16x32_bf16(a2, b1l, acc[2], 0, 0, 0);
      acc[3] = __builtin_amdgcn_mfma_f32_16x16x32_bf16(a3, b1h, acc[3], 0, 0, 0);
      acc[3] = __builtin_amdgcn_mfma_f32_16x16x32_bf16(a3, b1l, acc[3], 0, 0, 0);
    }
    kw = kwn;
    w0 = nw0; w1 = nw1; w2 = nw2; w3 = nw3;
    b0h = nb0h; b0l = nb0l; b1h = nb1h; b1l = nb1l;
  }
  // combine K-halves through LDS; epilogue by ks==0 waves
  int nl = nw*16 + l15;
  if (ks == 1) {
    #pragma unroll
    for (int mf = 0; mf < 4; ++mf) {
      #pragma unroll
      for (int reg = 0; reg < 4; ++reg)
        tile[(mf*16 + quad*4 + reg)*65 + nl] = acc[mf][reg];
    }
  }
  __syncthreads();
  if (ks == 0) {
    int n = n0 + nl;
    const int* dgp = g ? deg2 : deg1;
    float bn = (g ? biasB : biasA)[n];
    int zoff = g*256;
    #pragma unroll
    for (int mf = 0; mf < 4; ++mf) {
      #pragma unroll
      for (int reg = 0; reg < 4; ++reg) {
        int v = m0 + mf*16 + quad*4 + reg;
        float s = acc[mf][reg] + tile[(mf*16 + quad*4 + reg)*65 + nl];
        int d = dgp[v];
        float sfac = 0.0f;
        if (d > 0) { float df = (float)d; sfac = (1.0f / sqrtf(df)) / df; }
        float val = Z[(size_t)v*512 + zoff + n] + sfac*s + bn;
        h[(size_t)v*512 + zoff + n] = fmaxf(val, 0.0f);
      }
    }
  }
}

// ---------- 10. BN sums (coalesced one-pass, fp32 atomics) ----------
__global__ __launch_bounds__(256) void k_bnsum(const float* __restrict__ h, float* __restrict__ acc) {
  int b = blockIdx.x, t = threadIdx.x;
  float s0 = 0.f, s1 = 0.f, q0 = 0.f, q1 = 0.f;
  const float2* hp = (const float2*)h;
  for (int r = b*16; r < b*16 + 16; ++r) {
    float2 v = hp[(size_t)r*256 + t];
    s0 += v.x; s1 += v.y; q0 += v.x*v.x; q1 += v.y*v.y;
  }
  int c0 = t*2;
  atomicAdd(&acc[c0*2 + 0], s0);
  atomicAdd(&acc[c0*2 + 1], q0);
  atomicAdd(&acc[c0*2 + 2], s1);
  atomicAdd(&acc[c0*2 + 3], q1);
}

// ---------- 11. BN apply + split to frag-major hn packs (K=512) ----------
__global__ __launch_bounds__(256) void k_bnapply_split(const float* __restrict__ h, const float* __restrict__ acc,
                                                       const float* __restrict__ gamma, const float* __restrict__ beta,
                                                       short* __restrict__ hPh, short* __restrict__ hPl) {
  int i = blockIdx.x*256 + threadIdx.x;       // 524288 float4s
  float4 v = ((const float4*)h)[i];
  int r = i >> 7;
  int colb = (i & 127) * 4;
  float vv[4] = {v.x, v.y, v.z, v.w};
  short4 hh, ll;
  short* hp = (short*)&hh; short* lp = (short*)&ll;
  #pragma unroll
  for (int j = 0; j < 4; ++j) {
    int col = colb + j;
    float mean = acc[col*2] * (1.0f/4096.0f);
    float var  = acc[col*2 + 1] * (1.0f/4096.0f) - mean*mean;
    float inv  = rsqrtf(var + 1e-5f);
    float sc = gamma[col] * inv;
    float sh = beta[col] - mean * sc;
    split2(vv[j]*sc + sh, hp[j], lp[j]);
  }
  size_t off = packoff(r, colb, 16);          // colb%8 in {0,4}: 4 contiguous shorts
  ((short4*)hPh)[off >> 2] = hh;
  ((short4*)hPl)[off >> 2] = ll;
}

// ---------- 12. final: inline BN2 + readout + modality softmax mix ----------
__global__ __launch_bounds__(256) void k_final2(const float* __restrict__ h, const float* __restrict__ acc2,
                                                const float* __restrict__ gamma2, const float* __restrict__ beta2,
                                                const float* __restrict__ w_ro, const float* __restrict__ cl,
                                                float* __restrict__ out) {
  int node = blockIdx.x;
  int t = threadIdx.x, m = t >> 6, lane = t & 63;
  const float* row = h + (size_t)(m*1024 + node)*512;
  float a0 = 0.f, a1 = 0.f, a2 = 0.f, a3 = 0.f;
  for (int it = 0; it < 8; ++it) {
    int k = lane + it*64;
    float mean = acc2[k*2] * (1.0f/4096.0f);
    float var  = acc2[k*2 + 1] * (1.0f/4096.0f) - mean*mean;
    float inv  = rsqrtf(var + 1e-5f);
    float sc = gamma2[k] * inv;
    float sh = beta2[k] - mean * sc;
    float hv = row[k]*sc + sh;
    float4 w = ((const float4*)w_ro)[k];
    a0 += hv*w.x; a1 += hv*w.y; a2 += hv*w.z; a3 += hv*w.w;
  }
  for (int off = 32; off > 0; off >>= 1) {
    a0 += __shfl_down(a0, off); a1 += __shfl_down(a1, off);
    a2 += __shfl_down(a2, off); a3 += __shfl_down(a3, off);
  }
  __shared__ float part[4][4];
  if (lane == 0) { part[m][0]=a0; part[m][1]=a1; part[m][2]=a2; part[m][3]=a3; }
  __syncthreads();
  if (t < 4) {
    float c0 = cl[0], c1 = cl[1], c2 = cl[2], c3 = cl[3];
    float mx = fmaxf(fmaxf(c0,c1), fmaxf(c2,c3));
    float e0 = expf(c0-mx), e1 = expf(c1-mx), e2 = expf(c2-mx), e3 = expf(c3-mx);
    float inv = 1.0f/(e0+e1+e2+e3);
    float r = (e0*part[0][t] + e1*part[1][t] + e2*part[2][t] + e3*part[3][t]) * inv;
    out[node*4 + t] = r;
  }
}

extern "C" void kernel_launch(void* const* d_in, const int* in_sizes, int n_in,
                              void* d_out, int out_size, void* d_ws, size_t ws_size,
                              hipStream_t stream) {
  const float* features = (const float*)d_in[0];
  const float* sparse   = (const float*)d_in[1];
  const float* cmix     = (const float*)d_in[2];
  const float* wAC1 = (const float*)d_in[3];
  const float* bAC1 = (const float*)d_in[4];
  const float* wCA1 = (const float*)d_in[5];
  const float* bCA1 = (const float*)d_in[6];
  const float* wAC2 = (const float*)d_in[7];
  const float* bAC2 = (const float*)d_in[8];
  const float* wCA2 = (const float*)d_in[9];
  const float* bCA2 = (const float*)d_in[10];
  const float* gamma1 = (const float*)d_in[11];
  const float* beta1  = (const float*)d_in[12];
  const float* gamma2 = (const float*)d_in[13];
  const float* beta2  = (const float*)d_in[14];
  const float* w_ro   = (const float*)d_in[15];
  float* out = (float*)d_out;

  char* ws = (char*)d_ws;
  const size_t MB = 1024ull*1024ull, KB = 1024ull;
  u64*   bits    = (u64*)(ws + 0);               // 1.25 MB
  u64*   mask    = (u64*)(ws + 2*MB);            // 2 MB (row-major)
  u64*   mask_wm = (u64*)(ws + 4*MB);            // 2 MB (word-major)
  u64*   maskT_wm= (u64*)(ws + 6*MB);            // 2 MB (word-major)
  int*   deg1    = (int*)(ws + 8*MB);            // 16 KB  [zeroed]
  float* bnacc1  = (float*)(ws + 8*MB + 16*KB);  // 4 KB   [zeroed]
  float* bnacc2  = (float*)(ws + 8*MB + 20*KB);  // 4 KB   [zeroed]
  int*   deg2    = (int*)(ws + 8*MB + 24*KB);    // 16 KB
  u64*   cmask   = (u64*)(ws + 8*MB + 40*KB);    // 1 KB
  short* WT1h  = (short*)(ws + 9*MB);            // 128 KB (frag-major pack)
  short* WT1l  = (short*)(ws + 9*MB + 128*KB);   // 128 KB
  short* WT2h  = (short*)(ws + 9*MB + 256*KB);   // 512 KB
  short* WT2l  = (short*)(ws + 9*MB + 768*KB);   // 512 KB
  // region [11MB,23MB): y base packs (dead after corr) -> BT packs -> hn packs -> BT packs (L2)
  short* yhP   = (short*)(ws + 11*MB);           // 1 MB
  short* ymP   = (short*)(ws + 12*MB);           // 1 MB
  short* ylP   = (short*)(ws + 13*MB);           // 1 MB
  short* BTh   = (short*)(ws + 11*MB);           // 4 MB (frag-major)
  short* BTl   = (short*)(ws + 15*MB);           // 4 MB
  short* hnPh  = (short*)(ws + 11*MB);           // 4 MB (frag-major, K=512)
  short* hnPl  = (short*)(ws + 15*MB);           // 4 MB
  short* fPh   = (short*)(ws + 23*MB);           // 1 MB (frag-major, K=128; dead after L1 dense)
  short* fPl   = (short*)(ws + 24*MB);           // 1 MB
  float* Z     = (float*)(ws + 25*MB);           // 8 MB
  float* h     = (float*)(ws + 33*MB);           // 8 MB (total 41 MB)

  hipMemsetAsync(ws + 8*MB, 0, 24*KB, stream);   // deg1 + bnacc1 + bnacc2

  // graph prep
  k_rownorm<<<dim3(4096), dim3(128), 0, stream>>>(features, yhP, ymP, ylP, fPh, fPl);
  k_corr3<<<dim3(16,16,10), dim3(256), 0, stream>>>(yhP, ymP, ylP, sparse, bits);
  k_maskrows<<<dim3(4096), dim3(64), 0, stream>>>(bits, mask, mask_wm, deg2);
  k_bittrans2<<<dim3(64,4), dim3(256), 0, stream>>>(mask, maskT_wm, deg1);
  k_chunkmask<<<dim3(64,2), dim3(64), 0, stream>>>(maskT_wm, mask_wm, cmask);
  k_prepWT<<<dim3(2,8), dim3(256), 0, stream>>>(wAC1, wCA1, WT1h, WT1l, 128);
  k_prepWT<<<dim3(8,8), dim3(256), 0, stream>>>(wAC2, wCA2, WT2h, WT2l, 512);

  // layer 1:  h = relu(Z + sfac*(bits @ (nrm*Z)) + b)
  k_dense2<<<dim3(64,8), dim3(256), 0, stream>>>(fPh, fPl, WT1h, WT1l, Z, 4);
  k_prepB<<<dim3(64,8), dim3(256), 0, stream>>>(Z, deg1, deg2, BTh, BTl);
  k_mg3<<<dim3(64,4,2), dim3(512), 0, stream>>>(maskT_wm, mask_wm, cmask, BTh, BTl, Z,
                                                deg1, deg2, bAC1, bCA1, h);
  k_bnsum<<<dim3(256), dim3(256), 0, stream>>>(h, bnacc1);
  k_bnapply_split<<<dim3(2048), dim3(256), 0, stream>>>(h, bnacc1, gamma1, beta1, hnPh, hnPl);

  // layer 2
  k_dense2<<<dim3(64,8), dim3(256), 0, stream>>>(hnPh, hnPl, WT2h, WT2l, Z, 16);
  k_prepB<<<dim3(64,8), dim3(256), 0, stream>>>(Z, deg1, deg2, BTh, BTl);
  k_mg3<<<dim3(64,4,2), dim3(512), 0, stream>>>(maskT_wm, mask_wm, cmask, BTh, BTl, Z,
                                                deg1, deg2, bAC2, bCA2, h);
  k_bnsum<<<dim3(256), dim3(256), 0, stream>>>(h, bnacc2);

  // readout (BN2 folded inline)
  k_final2<<<dim3(1024), dim3(256), 0, stream>>>(h, bnacc2, gamma2, beta2, w_ro, cmix, out);
}

// Round 8
// 290.259 us; speedup vs baseline: 2.2073x; 1.2188x over previous
//
#include <hip/hip_runtime.h>

typedef unsigned long long u64;
typedef __attribute__((ext_vector_type(8))) short s8v;   // 8 bf16 = 4 VGPRs (MFMA A/B frag)
typedef __attribute__((ext_vector_type(4))) float f4v;   // MFMA C/D frag

__device__ __constant__ int c_pi[10]   = {0,1,2,3,0,1,2,3,3,3};
__device__ __constant__ int c_pj[10]   = {0,1,2,3,3,3,3,0,1,2};
__device__ __constant__ int c_dri[10]  = {1,5,8,10,4,7,9,4,7,9};
__device__ __constant__ int c_diag[10] = {1,1,1,1,0,0,0,0,0,0};
__device__ __constant__ int c_src[16]  = {-1,7,8,9,  4,-1,8,9,  5,5,-1,9,  6,6,6,-1};

// round-to-nearest bf16
__device__ inline unsigned short bf16rn(float v) {
  unsigned int u = __float_as_uint(v);
  unsigned int r = u + 0x7fffu + ((u >> 16) & 1u);
  return (unsigned short)(r >> 16);
}
__device__ inline void split2(float v, short& h, short& l) {
  unsigned short hs = bf16rn(v);
  float fh = __uint_as_float(((unsigned int)hs) << 16);
  h = (short)hs;
  l = (short)bf16rn(v - fh);
}
__device__ inline void split3(float v, short& h, short& m, short& l) {
  unsigned short hs = bf16rn(v);
  float fh = __uint_as_float(((unsigned int)hs) << 16);
  float r1 = v - fh;
  unsigned short ms = bf16rn(r1);
  float fm = __uint_as_float(((unsigned int)ms) << 16);
  h = (short)hs; m = (short)ms;
  l = (short)bf16rn(r1 - fm);
}

// fragment-major pack offset: row r, k-index k, KC = K/32 chunks
__device__ inline size_t packoff(int row, int k, int KC) {
  int T = row >> 4, rr = row & 15;
  int c = k >> 5, q = (k >> 3) & 3, j = k & 7;
  return (((size_t)T*KC + c)*64 + q*16 + rr)*8 + j;
}

// ---------- 1. center+normalize rows -> 3 base split packs; feature pack ----------
__global__ __launch_bounds__(128) void k_rownorm(const float* __restrict__ f,
                                                 short* __restrict__ yhP, short* __restrict__ ymP,
                                                 short* __restrict__ ylP,
                                                 short* __restrict__ fPh, short* __restrict__ fPl) {
  int r = blockIdx.x, t = threadIdx.x;
  __shared__ float red[128];
  float v = f[r*128 + t];
  red[t] = v; __syncthreads();
  for (int s = 64; s > 0; s >>= 1) { if (t < s) red[t] += red[t+s]; __syncthreads(); }
  float mean = red[0] * (1.0f/128.0f);
  __syncthreads();
  float xc = v - mean;
  red[t] = xc*xc; __syncthreads();
  for (int s = 64; s > 0; s >>= 1) { if (t < s) red[t] += red[t+s]; __syncthreads(); }
  float inv = 1.0f / sqrtf(red[0]);
  short h, m, l;
  split3(xc*inv, h, m, l);
  size_t o = packoff(r, t, 4);
  yhP[o] = h; ymP[o] = m; ylP[o] = l;
  short fh, fl; split2(v, fh, fl);
  fPh[o] = fh; fPl[o] = fl;
}

// ---------- 2. correlation bit blocks: base-pack GEMM, 6 chain combos from registers ----------
__global__ __launch_bounds__(256) void k_corr3(const short* __restrict__ yhP, const short* __restrict__ ymP,
                                               const short* __restrict__ ylP,
                                               const float* __restrict__ sparse, u64* __restrict__ bits) {
  int z = blockIdx.z;
  int bx = blockIdx.x, by = blockIdx.y;
  int dg = c_diag[z];
  if (dg && by < bx) return;
  int a0 = c_pi[z]*1024 + bx*64;
  int b0 = c_pj[z]*1024 + by*64;
  int tid = threadIdx.x, lane = tid & 63, wid = tid >> 6;
  int quad = lane >> 4, l15 = lane & 15;
  const s8v* AH = (const s8v*)yhP + ((size_t)((a0>>4) + wid))*4*64 + lane;
  const s8v* AM = (const s8v*)ymP + ((size_t)((a0>>4) + wid))*4*64 + lane;
  const s8v* AL = (const s8v*)ylP + ((size_t)((a0>>4) + wid))*4*64 + lane;
  const s8v* BH = (const s8v*)yhP + ((size_t)(b0>>4))*4*64 + lane;
  const s8v* BM = (const s8v*)ymP + ((size_t)(b0>>4))*4*64 + lane;
  const s8v* BL = (const s8v*)ylP + ((size_t)(b0>>4))*4*64 + lane;
  f4v acc[4];
  #pragma unroll
  for (int i = 0; i < 4; ++i) { acc[i][0]=0.f; acc[i][1]=0.f; acc[i][2]=0.f; acc[i][3]=0.f; }
  for (int c = 0; c < 4; ++c) {
    s8v a_h = AH[c*64];
    s8v a_m = AM[c*64];
    s8v a_l = AL[c*64];
    #pragma unroll
    for (int nt = 0; nt < 4; ++nt) {
      s8v b_h = BH[(nt*4 + c)*64];
      s8v b_m = BM[(nt*4 + c)*64];
      s8v b_l = BL[(nt*4 + c)*64];
      acc[nt] = __builtin_amdgcn_mfma_f32_16x16x32_bf16(a_h, b_h, acc[nt], 0, 0, 0);
      acc[nt] = __builtin_amdgcn_mfma_f32_16x16x32_bf16(a_m, b_m, acc[nt], 0, 0, 0);
      acc[nt] = __builtin_amdgcn_mfma_f32_16x16x32_bf16(a_h, b_m, acc[nt], 0, 0, 0);
      acc[nt] = __builtin_amdgcn_mfma_f32_16x16x32_bf16(a_m, b_h, acc[nt], 0, 0, 0);
      acc[nt] = __builtin_amdgcn_mfma_f32_16x16x32_bf16(a_h, b_l, acc[nt], 0, 0, 0);
      acc[nt] = __builtin_amdgcn_mfma_f32_16x16x32_bf16(a_l, b_h, acc[nt], 0, 0, 0);
    }
  }
  __shared__ unsigned char lby[64*68];
  float sv = sparse[c_dri[z]];
  float dr = 1.0f / (1.0f + expf(-sv));
  #pragma unroll
  for (int nt = 0; nt < 4; ++nt) {
    #pragma unroll
    for (int reg = 0; reg < 4; ++reg) {
      int lr = wid*16 + quad*4 + reg;
      int lc = nt*16 + l15;
      int ga = bx*64 + lr, gb = by*64 + lc;
      int on = (fabsf(acc[nt][reg]) > dr) && !(dg && (ga == gb));
      lby[lr*68 + lc] = (unsigned char)on;
    }
  }
  __syncthreads();
  if (tid < 64) {
    u64 w = 0;
    for (int c2 = 0; c2 < 64; ++c2) w |= ((u64)lby[tid*68 + c2]) << c2;
    bits[z*16384 + (bx*64 + tid)*16 + by] = w;
    if (dg && bx != by) {
      u64 wt = 0;
      for (int c2 = 0; c2 < 64; ++c2) wt |= ((u64)lby[c2*68 + tid]) << c2;
      bits[z*16384 + (by*64 + tid)*16 + bx] = wt;
    }
  }
}

// ---------- 3. mask rows (boolean A@C) + mask_wm + graph-2 degrees + cmask[g=1] ----------
__global__ __launch_bounds__(64) void k_maskrows(const u64* __restrict__ bits, u64* __restrict__ mask,
                                                 u64* __restrict__ mask_wm, int* __restrict__ deg2,
                                                 u64* __restrict__ cmask) {
  int u = blockIdx.x;
  int i = u >> 10, a = u & 1023;
  int t = threadIdx.x;
  __shared__ u64 drow[16];
  if (t < 16) drow[t] = bits[i*16384 + a*16 + t];
  __syncthreads();
  int j = t >> 4, wl = t & 15;
  u64 out;
  if (j == i) {
    out = drow[wl];
  } else {
    const u64* S = bits + c_src[i*4 + j]*16384;
    out = 0;
    for (int w2 = 0; w2 < 16; ++w2) {
      u64 m = drow[w2];
      while (m) {
        int b = __builtin_ctzll(m); m &= m - 1;
        out |= S[(w2*64 + b)*16 + wl];
      }
    }
  }
  mask[(size_t)u*64 + t] = out;
  mask_wm[(size_t)t*4096 + u] = out;
  u64 bal = __ballot(out != 0ULL);            // bit t == word kw nonzero for node u
  if (t == 0 && bal) atomicOr((unsigned long long*)&cmask[64 + (u >> 6)], bal);
  int cnt = __popcll(out);
  for (int off = 32; off > 0; off >>= 1) cnt += __shfl_down(cnt, off);
  if (t == 0) deg2[u] = cnt;
}

// ---------- 4. bit transpose -> maskT word-major + deg1 atomics + cmask[g=0] ----------
__global__ __launch_bounds__(256) void k_bittrans2(const u64* __restrict__ mask, u64* __restrict__ wmT,
                                                   int* __restrict__ deg1, u64* __restrict__ cmask) {
  __shared__ u64 tile[4096];   // 64 rows x 64 words = 32 KB
  int tI = blockIdx.x, tid = threadIdx.x;
  for (int e = tid; e < 4096; e += 256) tile[e] = mask[(size_t)tI*4096 + e];
  __syncthreads();
  int wv = tid >> 6, lane = tid & 63;
  int tJ0 = blockIdx.y*16;
  for (int j = 0; j < 4; ++j) {
    int tJ = tJ0 + wv*4 + j;
    u64 o = 0;
    #pragma unroll 8
    for (int k = 0; k < 64; ++k) o |= ((tile[k*64 + tJ] >> lane) & 1ULL) << k;
    wmT[(size_t)tI*4096 + tJ*64 + lane] = o;
    atomicAdd(&deg1[tJ*64 + lane], __popcll(o));
    u64 bal = __ballot(o != 0ULL);
    if (lane == 0 && bal) atomicOr((unsigned long long*)&cmask[tJ], 1ULL << tI);
  }
}

// ---------- 5. weight prep (both layers in one dispatch) ----------
__global__ __launch_bounds__(256) void k_prepWTall(const float* __restrict__ wAC1, const float* __restrict__ wCA1,
                                                   const float* __restrict__ wAC2, const float* __restrict__ wCA2,
                                                   short* __restrict__ w1h, short* __restrict__ w1l,
                                                   short* __restrict__ w2h, short* __restrict__ w2l) {
  __shared__ float lds[64*65];
  int z = blockIdx.z;
  int bx = blockIdx.x;
  if (z == 0 && bx >= 2) return;
  int K = z ? 512 : 128;
  const float* Wa = z ? wAC2 : wAC1;
  const float* Wb = z ? wCA2 : wCA1;
  short* wph = z ? w2h : w1h;
  short* wpl = z ? w2l : w1l;
  int tid = threadIdx.x;
  int k0 = bx*64, n0 = blockIdx.y*64;
  const float* W = (n0 < 256) ? Wa : Wb;
  int nc0 = n0 & 255;
  for (int e = tid; e < 4096; e += 256) {
    int r = e >> 6, c = e & 63;
    lds[r*65 + c] = W[(size_t)(k0+r)*256 + nc0 + c];
  }
  __syncthreads();
  int KC = K >> 5;
  for (int e = tid; e < 4096; e += 256) {
    int j = e & 7, ln = (e >> 3) & 63, cp = (e >> 9) & 1, Tp = e >> 10;
    int q = ln >> 4, rr = ln & 15;
    float v = lds[(cp*32 + q*8 + j)*65 + (Tp*16 + rr)];
    short h, l; split2(v, h, l);
    size_t off = (((size_t)((n0>>4)+Tp)*KC + (k0>>5)+cp)*64 + ln)*8 + j;
    wph[off] = h; wpl[off] = l;
  }
}

// ---------- 6. dense GEMM + fused B-prep: Z tile + nrm-scaled frag-major BT packs ----------
__global__ __launch_bounds__(256) void k_dense3(const short* __restrict__ Ah, const short* __restrict__ Al,
                                                const short* __restrict__ Bh, const short* __restrict__ Bl,
                                                float* __restrict__ Z, int KC,
                                                const int* __restrict__ deg1, const int* __restrict__ deg2,
                                                short* __restrict__ bph, short* __restrict__ bpl) {
  __shared__ float tile[64*65];
  int tid = threadIdx.x, lane = tid & 63, wid = tid >> 6;
  int quad = lane >> 4, l15 = lane & 15;
  int m0 = blockIdx.x*64, n0 = blockIdx.y*64;
  const s8v* ah = (const s8v*)Ah + ((size_t)((m0>>4) + wid))*KC*64 + lane;
  const s8v* al = (const s8v*)Al + ((size_t)((m0>>4) + wid))*KC*64 + lane;
  const s8v* bh0 = (const s8v*)Bh + ((size_t)((n0>>4) + 0))*KC*64 + lane;
  const s8v* bh1 = (const s8v*)Bh + ((size_t)((n0>>4) + 1))*KC*64 + lane;
  const s8v* bh2 = (const s8v*)Bh + ((size_t)((n0>>4) + 2))*KC*64 + lane;
  const s8v* bh3 = (const s8v*)Bh + ((size_t)((n0>>4) + 3))*KC*64 + lane;
  const s8v* bl0 = (const s8v*)Bl + ((size_t)((n0>>4) + 0))*KC*64 + lane;
  const s8v* bl1 = (const s8v*)Bl + ((size_t)((n0>>4) + 1))*KC*64 + lane;
  const s8v* bl2 = (const s8v*)Bl + ((size_t)((n0>>4) + 2))*KC*64 + lane;
  const s8v* bl3 = (const s8v*)Bl + ((size_t)((n0>>4) + 3))*KC*64 + lane;
  f4v acc[4];
  #pragma unroll
  for (int i = 0; i < 4; ++i) { acc[i][0]=0.f; acc[i][1]=0.f; acc[i][2]=0.f; acc[i][3]=0.f; }
  for (int c = 0; c < KC; ++c) {
    s8v a_h = ah[c*64];
    s8v a_l = al[c*64];
    acc[0] = __builtin_amdgcn_mfma_f32_16x16x32_bf16(a_h, bh0[c*64], acc[0], 0, 0, 0);
    acc[0] = __builtin_amdgcn_mfma_f32_16x16x32_bf16(a_h, bl0[c*64], acc[0], 0, 0, 0);
    acc[0] = __builtin_amdgcn_mfma_f32_16x16x32_bf16(a_l, bh0[c*64], acc[0], 0, 0, 0);
    acc[1] = __builtin_amdgcn_mfma_f32_16x16x32_bf16(a_h, bh1[c*64], acc[1], 0, 0, 0);
    acc[1] = __builtin_amdgcn_mfma_f32_16x16x32_bf16(a_h, bl1[c*64], acc[1], 0, 0, 0);
    acc[1] = __builtin_amdgcn_mfma_f32_16x16x32_bf16(a_l, bh1[c*64], acc[1], 0, 0, 0);
    acc[2] = __builtin_amdgcn_mfma_f32_16x16x32_bf16(a_h, bh2[c*64], acc[2], 0, 0, 0);
    acc[2] = __builtin_amdgcn_mfma_f32_16x16x32_bf16(a_h, bl2[c*64], acc[2], 0, 0, 0);
    acc[2] = __builtin_amdgcn_mfma_f32_16x16x32_bf16(a_l, bh2[c*64], acc[2], 0, 0, 0);
    acc[3] = __builtin_amdgcn_mfma_f32_16x16x32_bf16(a_h, bh3[c*64], acc[3], 0, 0, 0);
    acc[3] = __builtin_amdgcn_mfma_f32_16x16x32_bf16(a_h, bl3[c*64], acc[3], 0, 0, 0);
    acc[3] = __builtin_amdgcn_mfma_f32_16x16x32_bf16(a_l, bh3[c*64], acc[3], 0, 0, 0);
  }
  #pragma unroll
  for (int nt = 0; nt < 4; ++nt) {
    #pragma unroll
    for (int reg = 0; reg < 4; ++reg) {
      int rl = wid*16 + quad*4 + reg;
      int cl = nt*16 + l15;
      float v = acc[nt][reg];
      Z[(size_t)(m0+rl)*512 + n0 + cl] = v;
      tile[rl*65 + cl] = v;
    }
  }
  __syncthreads();
  const int* dg = (n0 < 256) ? deg1 : deg2;
  for (int e = tid; e < 4096; e += 256) {   // pack-major write order (coalesced)
    int j = e & 7, ln = (e >> 3) & 63, cp = (e >> 9) & 1, Tp = e >> 10;
    int q = ln >> 4, rr = ln & 15;
    int krow = cp*32 + q*8 + j;             // node-local row
    int d = dg[m0 + krow];
    float nr = d > 0 ? (1.0f / sqrtf((float)d)) : 0.0f;
    float v = tile[krow*65 + (Tp*16 + rr)] * nr;
    short h, l; split2(v, h, l);
    size_t off = (((size_t)((n0>>4)+Tp)*128 + (m0>>5)+cp)*64 + ln)*8 + j;
    bph[off] = h; bpl[off] = l;
  }
}

// ---------- 7. mask GEMM v3 + fused BN partial sums ----------
__global__ __launch_bounds__(512) void k_mg3(const u64* __restrict__ wmT, const u64* __restrict__ wmR,
                                             const u64* __restrict__ cmask,
                                             const short* __restrict__ bph, const short* __restrict__ bpl,
                                             const float* __restrict__ Z,
                                             const int* __restrict__ deg1, const int* __restrict__ deg2,
                                             const float* __restrict__ biasA, const float* __restrict__ biasB,
                                             float* __restrict__ h, float* __restrict__ bnacc) {
  __shared__ s8v lut[256];   // byte -> 8 bf16 {0,1}
  __shared__ float tile[64*65];
  int tid = threadIdx.x;
  if (tid < 256) {
    s8v e;
    #pragma unroll
    for (int j = 0; j < 8; ++j) e[j] = ((tid >> j) & 1) ? (short)0x3F80 : (short)0;
    lut[tid] = e;
  }
  __syncthreads();
  int g = blockIdx.z;
  const u64* wm = g ? wmR : wmT;
  u64 cm = cmask[g*64 + blockIdx.x];
  int m0 = blockIdx.x*64, n0 = blockIdx.y*64;
  int lane = tid & 63, wid = tid >> 6, quad = lane >> 4, l15 = lane & 15;
  int nw = wid & 3, ks = wid >> 2;
  u64 cmw = ks ? (cm >> 32) : (cm & 0xffffffffULL);
  int kwb = ks << 5;
  int T = g*16 + (n0 >> 4) + nw;
  const s8v* BH = (const s8v*)bph + (size_t)T*128*64 + lane;
  const s8v* BL = (const s8v*)bpl + (size_t)T*128*64 + lane;
  f4v acc[4];
  #pragma unroll
  for (int i = 0; i < 4; ++i) { acc[i][0]=0.f; acc[i][1]=0.f; acc[i][2]=0.f; acc[i][3]=0.f; }
  s8v z8;
  #pragma unroll
  for (int j = 0; j < 8; ++j) z8[j] = 0;

  int kw = -1;
  u64 w0 = 0, w1 = 0, w2 = 0, w3 = 0;
  s8v b0h = z8, b0l = z8, b1h = z8, b1l = z8;
  if (cmw) {
    kw = kwb + __builtin_ctzll(cmw); cmw &= cmw - 1;
    const u64* wp = wm + (size_t)kw*4096 + m0;
    w0 = wp[l15]; w1 = wp[16 + l15]; w2 = wp[32 + l15]; w3 = wp[48 + l15];
    b0h = BH[(kw*2)*64];   b0l = BL[(kw*2)*64];
    b1h = BH[(kw*2+1)*64]; b1l = BL[(kw*2+1)*64];
  }
  while (kw >= 0) {
    int kwn = -1;
    u64 nw0 = 0, nw1 = 0, nw2 = 0, nw3 = 0;
    s8v nb0h = z8, nb0l = z8, nb1h = z8, nb1l = z8;
    if (cmw) {                                  // prefetch next chunk (mask words + B frags)
      kwn = kwb + __builtin_ctzll(cmw); cmw &= cmw - 1;
      const u64* wp = wm + (size_t)kwn*4096 + m0;
      nw0 = wp[l15]; nw1 = wp[16 + l15]; nw2 = wp[32 + l15]; nw3 = wp[48 + l15];
      nb0h = BH[(kwn*2)*64];   nb0l = BL[(kwn*2)*64];
      nb1h = BH[(kwn*2+1)*64]; nb1l = BL[(kwn*2+1)*64];
    }
    {
      unsigned sh = quad*8;
      s8v a0 = lut[(unsigned)(w0 >> sh) & 0xffu];
      s8v a1 = lut[(unsigned)(w1 >> sh) & 0xffu];
      s8v a2 = lut[(unsigned)(w2 >> sh) & 0xffu];
      s8v a3 = lut[(unsigned)(w3 >> sh) & 0xffu];
      acc[0] = __builtin_amdgcn_mfma_f32_16x16x32_bf16(a0, b0h, acc[0], 0, 0, 0);
      acc[0] = __builtin_amdgcn_mfma_f32_16x16x32_bf16(a0, b0l, acc[0], 0, 0, 0);
      acc[1] = __builtin_amdgcn_mfma_f32_16x16x32_bf16(a1, b0h, acc[1], 0, 0, 0);
      acc[1] = __builtin_amdgcn_mfma_f32_16x16x32_bf16(a1, b0l, acc[1], 0, 0, 0);
      acc[2] = __builtin_amdgcn_mfma_f32_16x16x32_bf16(a2, b0h, acc[2], 0, 0, 0);
      acc[2] = __builtin_amdgcn_mfma_f32_16x16x32_bf16(a2, b0l, acc[2], 0, 0, 0);
      acc[3] = __builtin_amdgcn_mfma_f32_16x16x32_bf16(a3, b0h, acc[3], 0, 0, 0);
      acc[3] = __builtin_amdgcn_mfma_f32_16x16x32_bf16(a3, b0l, acc[3], 0, 0, 0);
      sh = 32 + quad*8;
      a0 = lut[(unsigned)(w0 >> sh) & 0xffu];
      a1 = lut[(unsigned)(w1 >> sh) & 0xffu];
      a2 = lut[(unsigned)(w2 >> sh) & 0xffu];
      a3 = lut[(unsigned)(w3 >> sh) & 0xffu];
      acc[0] = __builtin_amdgcn_mfma_f32_16x16x32_bf16(a0, b1h, acc[0], 0, 0, 0);
      acc[0] = __builtin_amdgcn_mfma_f32_16x16x32_bf16(a0, b1l, acc[0], 0, 0, 0);
      acc[1] = __builtin_amdgcn_mfma_f32_16x16x32_bf16(a1, b1h, acc[1], 0, 0, 0);
      acc[1] = __builtin_amdgcn_mfma_f32_16x16x32_bf16(a1, b1l, acc[1], 0, 0, 0);
      acc[2] = __builtin_amdgcn_mfma_f32_16x16x32_bf16(a2, b1h, acc[2], 0, 0, 0);
      acc[2] = __builtin_amdgcn_mfma_f32_16x16x32_bf16(a2, b1l, acc[2], 0, 0, 0);
      acc[3] = __builtin_amdgcn_mfma_f32_16x16x32_bf16(a3, b1h, acc[3], 0, 0, 0);
      acc[3] = __builtin_amdgcn_mfma_f32_16x16x32_bf16(a3, b1l, acc[3], 0, 0, 0);
    }
    kw = kwn;
    w0 = nw0; w1 = nw1; w2 = nw2; w3 = nw3;
    b0h = nb0h; b0l = nb0l; b1h = nb1h; b1l = nb1l;
  }
  // combine K-halves through LDS; epilogue + BN partial sums by ks==0 waves
  int nl = nw*16 + l15;
  if (ks == 1) {
    #pragma unroll
    for (int mf = 0; mf < 4; ++mf) {
      #pragma unroll
      for (int reg = 0; reg < 4; ++reg)
        tile[(mf*16 + quad*4 + reg)*65 + nl] = acc[mf][reg];
    }
  }
  __syncthreads();
  if (ks == 0) {
    int n = n0 + nl;
    const int* dgp = g ? deg2 : deg1;
    float bn = (g ? biasB : biasA)[n];
    int zoff = g*256;
    float sv = 0.0f, qv = 0.0f;
    #pragma unroll
    for (int mf = 0; mf < 4; ++mf) {
      #pragma unroll
      for (int reg = 0; reg < 4; ++reg) {
        int v = m0 + mf*16 + quad*4 + reg;
        float s = acc[mf][reg] + tile[(mf*16 + quad*4 + reg)*65 + nl];
        int d = dgp[v];
        float sfac = 0.0f;
        if (d > 0) { float df = (float)d; sfac = (1.0f / sqrtf(df)) / df; }
        float val = Z[(size_t)v*512 + zoff + n] + sfac*s + bn;
        val = fmaxf(val, 0.0f);
        h[(size_t)v*512 + zoff + n] = val;
        sv += val; qv += val*val;
      }
    }
    // reduce over the 4 quads sharing column n (lanes l15, +16, +32, +48)
    sv += __shfl_down(sv, 32); qv += __shfl_down(qv, 32);
    sv += __shfl_down(sv, 16); qv += __shfl_down(qv, 16);
    if (quad == 0) {
      int col = zoff + n;
      atomicAdd(&bnacc[col*2 + 0], sv);
      atomicAdd(&bnacc[col*2 + 1], qv);
    }
  }
}

// ---------- 8. BN apply + split to frag-major hn packs (K=512) ----------
__global__ __launch_bounds__(256) void k_bnapply_split(const float* __restrict__ h, const float* __restrict__ acc,
                                                       const float* __restrict__ gamma, const float* __restrict__ beta,
                                                       short* __restrict__ hPh, short* __restrict__ hPl) {
  int i = blockIdx.x*256 + threadIdx.x;       // 524288 float4s
  float4 v = ((const float4*)h)[i];
  int r = i >> 7;
  int colb = (i & 127) * 4;
  float vv[4] = {v.x, v.y, v.z, v.w};
  short4 hh, ll;
  short* hp = (short*)&hh; short* lp = (short*)&ll;
  #pragma unroll
  for (int j = 0; j < 4; ++j) {
    int col = colb + j;
    float mean = acc[col*2] * (1.0f/4096.0f);
    float var  = acc[col*2 + 1] * (1.0f/4096.0f) - mean*mean;
    float inv  = rsqrtf(var + 1e-5f);
    float sc = gamma[col] * inv;
    float sh = beta[col] - mean * sc;
    split2(vv[j]*sc + sh, hp[j], lp[j]);
  }
  size_t off = packoff(r, colb, 16);
  ((short4*)hPh)[off >> 2] = hh;
  ((short4*)hPl)[off >> 2] = ll;
}

// ---------- 9. final: inline BN2 + readout + modality softmax mix ----------
__global__ __launch_bounds__(256) void k_final2(const float* __restrict__ h, const float* __restrict__ acc2,
                                                const float* __restrict__ gamma2, const float* __restrict__ beta2,
                                                const float* __restrict__ w_ro, const float* __restrict__ cl,
                                                float* __restrict__ out) {
  int node = blockIdx.x;
  int t = threadIdx.x, m = t >> 6, lane = t & 63;
  const float* row = h + (size_t)(m*1024 + node)*512;
  float a0 = 0.f, a1 = 0.f, a2 = 0.f, a3 = 0.f;
  for (int it = 0; it < 8; ++it) {
    int k = lane + it*64;
    float mean = acc2[k*2] * (1.0f/4096.0f);
    float var  = acc2[k*2 + 1] * (1.0f/4096.0f) - mean*mean;
    float inv  = rsqrtf(var + 1e-5f);
    float sc = gamma2[k] * inv;
    float sh = beta2[k] - mean * sc;
    float hv = row[k]*sc + sh;
    float4 w = ((const float4*)w_ro)[k];
    a0 += hv*w.x; a1 += hv*w.y; a2 += hv*w.z; a3 += hv*w.w;
  }
  for (int off = 32; off > 0; off >>= 1) {
    a0 += __shfl_down(a0, off); a1 += __shfl_down(a1, off);
    a2 += __shfl_down(a2, off); a3 += __shfl_down(a3, off);
  }
  __shared__ float part[4][4];
  if (lane == 0) { part[m][0]=a0; part[m][1]=a1; part[m][2]=a2; part[m][3]=a3; }
  __syncthreads();
  if (t < 4) {
    float c0 = cl[0], c1 = cl[1], c2 = cl[2], c3 = cl[3];
    float mx = fmaxf(fmaxf(c0,c1), fmaxf(c2,c3));
    float e0 = expf(c0-mx), e1 = expf(c1-mx), e2 = expf(c2-mx), e3 = expf(c3-mx);
    float inv = 1.0f/(e0+e1+e2+e3);
    float r = (e0*part[0][t] + e1*part[1][t] + e2*part[2][t] + e3*part[3][t]) * inv;
    out[node*4 + t] = r;
  }
}

extern "C" void kernel_launch(void* const* d_in, const int* in_sizes, int n_in,
                              void* d_out, int out_size, void* d_ws, size_t ws_size,
                              hipStream_t stream) {
  const float* features = (const float*)d_in[0];
  const float* sparse   = (const float*)d_in[1];
  const float* cmix     = (const float*)d_in[2];
  const float* wAC1 = (const float*)d_in[3];
  const float* bAC1 = (const float*)d_in[4];
  const float* wCA1 = (const float*)d_in[5];
  const float* bCA1 = (const float*)d_in[6];
  const float* wAC2 = (const float*)d_in[7];
  const float* bAC2 = (const float*)d_in[8];
  const float* wCA2 = (const float*)d_in[9];
  const float* bCA2 = (const float*)d_in[10];
  const float* gamma1 = (const float*)d_in[11];
  const float* beta1  = (const float*)d_in[12];
  const float* gamma2 = (const float*)d_in[13];
  const float* beta2  = (const float*)d_in[14];
  const float* w_ro   = (const float*)d_in[15];
  float* out = (float*)d_out;

  char* ws = (char*)d_ws;
  const size_t MB = 1024ull*1024ull, KB = 1024ull;
  u64*   bits    = (u64*)(ws + 0);               // 1.25 MB
  u64*   mask    = (u64*)(ws + 2*MB);            // 2 MB (row-major)
  u64*   mask_wm = (u64*)(ws + 4*MB);            // 2 MB (word-major)
  u64*   maskT_wm= (u64*)(ws + 6*MB);            // 2 MB (word-major)
  int*   deg1    = (int*)(ws + 8*MB);            // 16 KB  [zeroed]
  float* bnacc1  = (float*)(ws + 8*MB + 16*KB);  // 4 KB   [zeroed]
  float* bnacc2  = (float*)(ws + 8*MB + 20*KB);  // 4 KB   [zeroed]
  u64*   cmask   = (u64*)(ws + 8*MB + 24*KB);    // 1 KB   [zeroed]
  int*   deg2    = (int*)(ws + 8*MB + 28*KB);    // 16 KB
  short* WT1h  = (short*)(ws + 9*MB);            // 128 KB (frag-major pack)
  short* WT1l  = (short*)(ws + 9*MB + 128*KB);   // 128 KB
  short* WT2h  = (short*)(ws + 9*MB + 256*KB);   // 512 KB
  short* WT2l  = (short*)(ws + 9*MB + 768*KB);   // 512 KB
  short* yhP   = (short*)(ws + 11*MB);           // 1 MB (dead after corr3)
  short* ymP   = (short*)(ws + 12*MB);           // 1 MB
  short* ylP   = (short*)(ws + 13*MB);           // 1 MB
  short* fPh   = (short*)(ws + 14*MB);           // 1 MB (dead after L1 dense)
  short* fPl   = (short*)(ws + 15*MB);           // 1 MB
  short* hnPh  = (short*)(ws + 16*MB);           // 4 MB (frag-major, K=512)
  short* hnPl  = (short*)(ws + 20*MB);           // 4 MB
  short* BTh   = (short*)(ws + 24*MB);           // 4 MB (frag-major, distinct from hnP!)
  short* BTl   = (short*)(ws + 28*MB);           // 4 MB
  float* Z     = (float*)(ws + 32*MB);           // 8 MB
  float* h     = (float*)(ws + 40*MB);           // 8 MB (total 48 MB)

  hipMemsetAsync(ws + 8*MB, 0, 25*KB, stream);   // deg1 + bnacc1 + bnacc2 + cmask

  // graph prep
  k_rownorm<<<dim3(4096), dim3(128), 0, stream>>>(features, yhP, ymP, ylP, fPh, fPl);
  k_corr3<<<dim3(16,16,10), dim3(256), 0, stream>>>(yhP, ymP, ylP, sparse, bits);
  k_maskrows<<<dim3(4096), dim3(64), 0, stream>>>(bits, mask, mask_wm, deg2, cmask);
  k_bittrans2<<<dim3(64,4), dim3(256), 0, stream>>>(mask, maskT_wm, deg1, cmask);
  k_prepWTall<<<dim3(8,8,2), dim3(256), 0, stream>>>(wAC1, wCA1, wAC2, wCA2, WT1h, WT1l, WT2h, WT2l);

  // layer 1:  h = relu(Z + sfac*(bits @ (nrm*Z)) + b)  [dense3 also emits BT packs]
  k_dense3<<<dim3(64,8), dim3(256), 0, stream>>>(fPh, fPl, WT1h, WT1l, Z, 4, deg1, deg2, BTh, BTl);
  k_mg3<<<dim3(64,4,2), dim3(512), 0, stream>>>(maskT_wm, mask_wm, cmask, BTh, BTl, Z,
                                                deg1, deg2, bAC1, bCA1, h, bnacc1);
  k_bnapply_split<<<dim3(2048), dim3(256), 0, stream>>>(h, bnacc1, gamma1, beta1, hnPh, hnPl);

  // layer 2
  k_dense3<<<dim3(64,8), dim3(256), 0, stream>>>(hnPh, hnPl, WT2h, WT2l, Z, 16, deg1, deg2, BTh, BTl);
  k_mg3<<<dim3(64,4,2), dim3(512), 0, stream>>>(maskT_wm, mask_wm, cmask, BTh, BTl, Z,
                                                deg1, deg2, bAC2, bCA2, h, bnacc2);

  // readout (BN2 folded inline)
  k_final2<<<dim3(1024), dim3(256), 0, stream>>>(h, bnacc2, gamma2, beta2, w_ro, cmix, out);
}

// Round 9
// 267.952 us; speedup vs baseline: 2.3911x; 1.0832x over previous
//
#include <hip/hip_runtime.h>

typedef unsigned long long u64;
typedef __attribute__((ext_vector_type(8))) short s8v;   // 8 bf16 = 4 VGPRs (MFMA A/B frag)
typedef __attribute__((ext_vector_type(4))) float f4v;   // MFMA C/D frag

__device__ __constant__ int c_pi[10]   = {0,1,2,3,0,1,2,3,3,3};
__device__ __constant__ int c_pj[10]   = {0,1,2,3,3,3,3,0,1,2};
__device__ __constant__ int c_dri[10]  = {1,5,8,10,4,7,9,4,7,9};
__device__ __constant__ int c_diag[10] = {1,1,1,1,0,0,0,0,0,0};
__device__ __constant__ int c_src[16]  = {-1,7,8,9,  4,-1,8,9,  5,5,-1,9,  6,6,6,-1};

// round-to-nearest bf16
__device__ inline unsigned short bf16rn(float v) {
  unsigned int u = __float_as_uint(v);
  unsigned int r = u + 0x7fffu + ((u >> 16) & 1u);
  return (unsigned short)(r >> 16);
}
__device__ inline void split2(float v, short& h, short& l) {
  unsigned short hs = bf16rn(v);
  float fh = __uint_as_float(((unsigned int)hs) << 16);
  h = (short)hs;
  l = (short)bf16rn(v - fh);
}
__device__ inline void split3(float v, short& h, short& m, short& l) {
  unsigned short hs = bf16rn(v);
  float fh = __uint_as_float(((unsigned int)hs) << 16);
  float r1 = v - fh;
  unsigned short ms = bf16rn(r1);
  float fm = __uint_as_float(((unsigned int)ms) << 16);
  h = (short)hs; m = (short)ms;
  l = (short)bf16rn(r1 - fm);
}

// fragment-major pack offset: row r, k-index k, KC = K/32 chunks
__device__ inline size_t packoff(int row, int k, int KC) {
  int T = row >> 4, rr = row & 15;
  int c = k >> 5, q = (k >> 3) & 3, j = k & 7;
  return (((size_t)T*KC + c)*64 + q*16 + rr)*8 + j;
}

// ---------- 1. center+normalize rows -> 3 base split packs; feature pack ----------
__global__ __launch_bounds__(128) void k_rownorm(const float* __restrict__ f,
                                                 short* __restrict__ yhP, short* __restrict__ ymP,
                                                 short* __restrict__ ylP,
                                                 short* __restrict__ fPh, short* __restrict__ fPl) {
  int r = blockIdx.x, t = threadIdx.x;
  __shared__ float red[128];
  float v = f[r*128 + t];
  red[t] = v; __syncthreads();
  for (int s = 64; s > 0; s >>= 1) { if (t < s) red[t] += red[t+s]; __syncthreads(); }
  float mean = red[0] * (1.0f/128.0f);
  __syncthreads();
  float xc = v - mean;
  red[t] = xc*xc; __syncthreads();
  for (int s = 64; s > 0; s >>= 1) { if (t < s) red[t] += red[t+s]; __syncthreads(); }
  float inv = 1.0f / sqrtf(red[0]);
  short h, m, l;
  split3(xc*inv, h, m, l);
  size_t o = packoff(r, t, 4);
  yhP[o] = h; ymP[o] = m; ylP[o] = l;
  short fh, fl; split2(v, fh, fl);
  fPh[o] = fh; fPl[o] = fl;
}

// ---------- 2. correlation bit blocks: base-pack GEMM, 6 chain combos from registers ----------
__global__ __launch_bounds__(256) void k_corr3(const short* __restrict__ yhP, const short* __restrict__ ymP,
                                               const short* __restrict__ ylP,
                                               const float* __restrict__ sparse, u64* __restrict__ bits) {
  int z = blockIdx.z;
  int bx = blockIdx.x, by = blockIdx.y;
  int dg = c_diag[z];
  if (dg && by < bx) return;
  int a0 = c_pi[z]*1024 + bx*64;
  int b0 = c_pj[z]*1024 + by*64;
  int tid = threadIdx.x, lane = tid & 63, wid = tid >> 6;
  int quad = lane >> 4, l15 = lane & 15;
  const s8v* AH = (const s8v*)yhP + ((size_t)((a0>>4) + wid))*4*64 + lane;
  const s8v* AM = (const s8v*)ymP + ((size_t)((a0>>4) + wid))*4*64 + lane;
  const s8v* AL = (const s8v*)ylP + ((size_t)((a0>>4) + wid))*4*64 + lane;
  const s8v* BH = (const s8v*)yhP + ((size_t)(b0>>4))*4*64 + lane;
  const s8v* BM = (const s8v*)ymP + ((size_t)(b0>>4))*4*64 + lane;
  const s8v* BL = (const s8v*)ylP + ((size_t)(b0>>4))*4*64 + lane;
  f4v acc[4];
  #pragma unroll
  for (int i = 0; i < 4; ++i) { acc[i][0]=0.f; acc[i][1]=0.f; acc[i][2]=0.f; acc[i][3]=0.f; }
  for (int c = 0; c < 4; ++c) {
    s8v a_h = AH[c*64];
    s8v a_m = AM[c*64];
    s8v a_l = AL[c*64];
    #pragma unroll
    for (int nt = 0; nt < 4; ++nt) {
      s8v b_h = BH[(nt*4 + c)*64];
      s8v b_m = BM[(nt*4 + c)*64];
      s8v b_l = BL[(nt*4 + c)*64];
      acc[nt] = __builtin_amdgcn_mfma_f32_16x16x32_bf16(a_h, b_h, acc[nt], 0, 0, 0);
      acc[nt] = __builtin_amdgcn_mfma_f32_16x16x32_bf16(a_m, b_m, acc[nt], 0, 0, 0);
      acc[nt] = __builtin_amdgcn_mfma_f32_16x16x32_bf16(a_h, b_m, acc[nt], 0, 0, 0);
      acc[nt] = __builtin_amdgcn_mfma_f32_16x16x32_bf16(a_m, b_h, acc[nt], 0, 0, 0);
      acc[nt] = __builtin_amdgcn_mfma_f32_16x16x32_bf16(a_h, b_l, acc[nt], 0, 0, 0);
      acc[nt] = __builtin_amdgcn_mfma_f32_16x16x32_bf16(a_l, b_h, acc[nt], 0, 0, 0);
    }
  }
  __shared__ unsigned char lby[64*68];
  float sv = sparse[c_dri[z]];
  float dr = 1.0f / (1.0f + expf(-sv));
  #pragma unroll
  for (int nt = 0; nt < 4; ++nt) {
    #pragma unroll
    for (int reg = 0; reg < 4; ++reg) {
      int lr = wid*16 + quad*4 + reg;
      int lc = nt*16 + l15;
      int ga = bx*64 + lr, gb = by*64 + lc;
      int on = (fabsf(acc[nt][reg]) > dr) && !(dg && (ga == gb));
      lby[lr*68 + lc] = (unsigned char)on;
    }
  }
  __syncthreads();
  if (tid < 64) {
    u64 w = 0;
    for (int c2 = 0; c2 < 64; ++c2) w |= ((u64)lby[tid*68 + c2]) << c2;
    bits[z*16384 + (bx*64 + tid)*16 + by] = w;
    if (dg && bx != by) {
      u64 wt = 0;
      for (int c2 = 0; c2 < 64; ++c2) wt |= ((u64)lby[c2*68 + tid]) << c2;
      bits[z*16384 + (by*64 + tid)*16 + bx] = wt;
    }
  }
}

// ---------- 3. mask rows: 8-deep pipelined bit-walk (8 gathers in flight per drain) ----------
__global__ __launch_bounds__(64) void k_maskrows(const u64* __restrict__ bits, u64* __restrict__ mask,
                                                 u64* __restrict__ mask_wm, int* __restrict__ deg2,
                                                 u64* __restrict__ cmask) {
  int u = blockIdx.x;
  int i = u >> 10, a = u & 1023;
  int t = threadIdx.x;
  __shared__ u64 drow[16];
  if (t < 16) drow[t] = bits[i*16384 + a*16 + t];
  __syncthreads();
  int j = t >> 4, wl = t & 15;
  u64 out;
  if (j == i) {
    out = drow[wl];
  } else {
    const u64* S = bits + c_src[i*4 + j]*16384;
    out = 0;
    for (int w2 = 0; w2 < 16; ++w2) {
      u64 m = drow[w2];
      const u64* base = S + (size_t)w2*1024 + wl;   // row k=w2*64+b lives at base + b*16
      while (m) {
        // peel up to 8 set bits; all 8 loads issue before the OR forces one waitcnt
        u64 v0 = 0, v1 = 0, v2 = 0, v3 = 0, v4 = 0, v5 = 0, v6 = 0, v7 = 0;
        int b = __builtin_ctzll(m); m &= m - 1; v0 = base[b*16];
        if (m) { b = __builtin_ctzll(m); m &= m - 1; v1 = base[b*16]; }
        if (m) { b = __builtin_ctzll(m); m &= m - 1; v2 = base[b*16]; }
        if (m) { b = __builtin_ctzll(m); m &= m - 1; v3 = base[b*16]; }
        if (m) { b = __builtin_ctzll(m); m &= m - 1; v4 = base[b*16]; }
        if (m) { b = __builtin_ctzll(m); m &= m - 1; v5 = base[b*16]; }
        if (m) { b = __builtin_ctzll(m); m &= m - 1; v6 = base[b*16]; }
        if (m) { b = __builtin_ctzll(m); m &= m - 1; v7 = base[b*16]; }
        out |= ((v0 | v1) | (v2 | v3)) | ((v4 | v5) | (v6 | v7));
      }
    }
  }
  mask[(size_t)u*64 + t] = out;
  mask_wm[(size_t)t*4096 + u] = out;
  u64 bal = __ballot(out != 0ULL);            // bit t == word kw nonzero for node u
  if (t == 0 && bal) atomicOr((unsigned long long*)&cmask[64 + (u >> 6)], bal);
  int cnt = __popcll(out);
  for (int off = 32; off > 0; off >>= 1) cnt += __shfl_down(cnt, off);
  if (t == 0) deg2[u] = cnt;
}

// ---------- 4. bit transpose -> maskT word-major + deg1 atomics + cmask[g=0] ----------
__global__ __launch_bounds__(256) void k_bittrans2(const u64* __restrict__ mask, u64* __restrict__ wmT,
                                                   int* __restrict__ deg1, u64* __restrict__ cmask) {
  __shared__ u64 tile[4096];   // 64 rows x 64 words = 32 KB
  int tI = blockIdx.x, tid = threadIdx.x;
  for (int e = tid; e < 4096; e += 256) tile[e] = mask[(size_t)tI*4096 + e];
  __syncthreads();
  int wv = tid >> 6, lane = tid & 63;
  int tJ0 = blockIdx.y*16;
  for (int j = 0; j < 4; ++j) {
    int tJ = tJ0 + wv*4 + j;
    u64 o = 0;
    #pragma unroll 8
    for (int k = 0; k < 64; ++k) o |= ((tile[k*64 + tJ] >> lane) & 1ULL) << k;
    wmT[(size_t)tI*4096 + tJ*64 + lane] = o;
    atomicAdd(&deg1[tJ*64 + lane], __popcll(o));
    u64 bal = __ballot(o != 0ULL);
    if (lane == 0 && bal) atomicOr((unsigned long long*)&cmask[tJ], 1ULL << tI);
  }
}

// ---------- 5. weight prep (both layers in one dispatch) ----------
__global__ __launch_bounds__(256) void k_prepWTall(const float* __restrict__ wAC1, const float* __restrict__ wCA1,
                                                   const float* __restrict__ wAC2, const float* __restrict__ wCA2,
                                                   short* __restrict__ w1h, short* __restrict__ w1l,
                                                   short* __restrict__ w2h, short* __restrict__ w2l) {
  __shared__ float lds[64*65];
  int z = blockIdx.z;
  int bx = blockIdx.x;
  if (z == 0 && bx >= 2) return;
  int K = z ? 512 : 128;
  const float* Wa = z ? wAC2 : wAC1;
  const float* Wb = z ? wCA2 : wCA1;
  short* wph = z ? w2h : w1h;
  short* wpl = z ? w2l : w1l;
  int tid = threadIdx.x;
  int k0 = bx*64, n0 = blockIdx.y*64;
  const float* W = (n0 < 256) ? Wa : Wb;
  int nc0 = n0 & 255;
  for (int e = tid; e < 4096; e += 256) {
    int r = e >> 6, c = e & 63;
    lds[r*65 + c] = W[(size_t)(k0+r)*256 + nc0 + c];
  }
  __syncthreads();
  int KC = K >> 5;
  for (int e = tid; e < 4096; e += 256) {
    int j = e & 7, ln = (e >> 3) & 63, cp = (e >> 9) & 1, Tp = e >> 10;
    int q = ln >> 4, rr = ln & 15;
    float v = lds[(cp*32 + q*8 + j)*65 + (Tp*16 + rr)];
    short h, l; split2(v, h, l);
    size_t off = (((size_t)((n0>>4)+Tp)*KC + (k0>>5)+cp)*64 + ln)*8 + j;
    wph[off] = h; wpl[off] = l;
  }
}

// ---------- 6. dense GEMM + fused B-prep: Z tile + nrm-scaled frag-major BT packs ----------
__global__ __launch_bounds__(256) void k_dense3(const short* __restrict__ Ah, const short* __restrict__ Al,
                                                const short* __restrict__ Bh, const short* __restrict__ Bl,
                                                float* __restrict__ Z, int KC,
                                                const int* __restrict__ deg1, const int* __restrict__ deg2,
                                                short* __restrict__ bph, short* __restrict__ bpl) {
  __shared__ float tile[64*65];
  int tid = threadIdx.x, lane = tid & 63, wid = tid >> 6;
  int quad = lane >> 4, l15 = lane & 15;
  int m0 = blockIdx.x*64, n0 = blockIdx.y*64;
  const s8v* ah = (const s8v*)Ah + ((size_t)((m0>>4) + wid))*KC*64 + lane;
  const s8v* al = (const s8v*)Al + ((size_t)((m0>>4) + wid))*KC*64 + lane;
  const s8v* bh0 = (const s8v*)Bh + ((size_t)((n0>>4) + 0))*KC*64 + lane;
  const s8v* bh1 = (const s8v*)Bh + ((size_t)((n0>>4) + 1))*KC*64 + lane;
  const s8v* bh2 = (const s8v*)Bh + ((size_t)((n0>>4) + 2))*KC*64 + lane;
  const s8v* bh3 = (const s8v*)Bh + ((size_t)((n0>>4) + 3))*KC*64 + lane;
  const s8v* bl0 = (const s8v*)Bl + ((size_t)((n0>>4) + 0))*KC*64 + lane;
  const s8v* bl1 = (const s8v*)Bl + ((size_t)((n0>>4) + 1))*KC*64 + lane;
  const s8v* bl2 = (const s8v*)Bl + ((size_t)((n0>>4) + 2))*KC*64 + lane;
  const s8v* bl3 = (const s8v*)Bl + ((size_t)((n0>>4) + 3))*KC*64 + lane;
  f4v acc[4];
  #pragma unroll
  for (int i = 0; i < 4; ++i) { acc[i][0]=0.f; acc[i][1]=0.f; acc[i][2]=0.f; acc[i][3]=0.f; }
  for (int c = 0; c < KC; ++c) {
    s8v a_h = ah[c*64];
    s8v a_l = al[c*64];
    acc[0] = __builtin_amdgcn_mfma_f32_16x16x32_bf16(a_h, bh0[c*64], acc[0], 0, 0, 0);
    acc[0] = __builtin_amdgcn_mfma_f32_16x16x32_bf16(a_h, bl0[c*64], acc[0], 0, 0, 0);
    acc[0] = __builtin_amdgcn_mfma_f32_16x16x32_bf16(a_l, bh0[c*64], acc[0], 0, 0, 0);
    acc[1] = __builtin_amdgcn_mfma_f32_16x16x32_bf16(a_h, bh1[c*64], acc[1], 0, 0, 0);
    acc[1] = __builtin_amdgcn_mfma_f32_16x16x32_bf16(a_h, bl1[c*64], acc[1], 0, 0, 0);
    acc[1] = __builtin_amdgcn_mfma_f32_16x16x32_bf16(a_l, bh1[c*64], acc[1], 0, 0, 0);
    acc[2] = __builtin_amdgcn_mfma_f32_16x16x32_bf16(a_h, bh2[c*64], acc[2], 0, 0, 0);
    acc[2] = __builtin_amdgcn_mfma_f32_16x16x32_bf16(a_h, bl2[c*64], acc[2], 0, 0, 0);
    acc[2] = __builtin_amdgcn_mfma_f32_16x16x32_bf16(a_l, bh2[c*64], acc[2], 0, 0, 0);
    acc[3] = __builtin_amdgcn_mfma_f32_16x16x32_bf16(a_h, bh3[c*64], acc[3], 0, 0, 0);
    acc[3] = __builtin_amdgcn_mfma_f32_16x16x32_bf16(a_h, bl3[c*64], acc[3], 0, 0, 0);
    acc[3] = __builtin_amdgcn_mfma_f32_16x16x32_bf16(a_l, bh3[c*64], acc[3], 0, 0, 0);
  }
  #pragma unroll
  for (int nt = 0; nt < 4; ++nt) {
    #pragma unroll
    for (int reg = 0; reg < 4; ++reg) {
      int rl = wid*16 + quad*4 + reg;
      int cl = nt*16 + l15;
      float v = acc[nt][reg];
      Z[(size_t)(m0+rl)*512 + n0 + cl] = v;
      tile[rl*65 + cl] = v;
    }
  }
  __syncthreads();
  const int* dg = (n0 < 256) ? deg1 : deg2;
  for (int e = tid; e < 4096; e += 256) {   // pack-major write order (coalesced)
    int j = e & 7, ln = (e >> 3) & 63, cp = (e >> 9) & 1, Tp = e >> 10;
    int q = ln >> 4, rr = ln & 15;
    int krow = cp*32 + q*8 + j;             // node-local row
    int d = dg[m0 + krow];
    float nr = d > 0 ? (1.0f / sqrtf((float)d)) : 0.0f;
    float v = tile[krow*65 + (Tp*16 + rr)] * nr;
    short h, l; split2(v, h, l);
    size_t off = (((size_t)((n0>>4)+Tp)*128 + (m0>>5)+cp)*64 + ln)*8 + j;
    bph[off] = h; bpl[off] = l;
  }
}

// ---------- 7. mask GEMM v3 + fused BN partial sums ----------
__global__ __launch_bounds__(512) void k_mg3(const u64* __restrict__ wmT, const u64* __restrict__ wmR,
                                             const u64* __restrict__ cmask,
                                             const short* __restrict__ bph, const short* __restrict__ bpl,
                                             const float* __restrict__ Z,
                                             const int* __restrict__ deg1, const int* __restrict__ deg2,
                                             const float* __restrict__ biasA, const float* __restrict__ biasB,
                                             float* __restrict__ h, float* __restrict__ bnacc) {
  __shared__ s8v lut[256];   // byte -> 8 bf16 {0,1}
  __shared__ float tile[64*65];
  int tid = threadIdx.x;
  if (tid < 256) {
    s8v e;
    #pragma unroll
    for (int j = 0; j < 8; ++j) e[j] = ((tid >> j) & 1) ? (short)0x3F80 : (short)0;
    lut[tid] = e;
  }
  __syncthreads();
  int g = blockIdx.z;
  const u64* wm = g ? wmR : wmT;
  u64 cm = cmask[g*64 + blockIdx.x];
  int m0 = blockIdx.x*64, n0 = blockIdx.y*64;
  int lane = tid & 63, wid = tid >> 6, quad = lane >> 4, l15 = lane & 15;
  int nw = wid & 3, ks = wid >> 2;
  u64 cmw = ks ? (cm >> 32) : (cm & 0xffffffffULL);
  int kwb = ks << 5;
  int T = g*16 + (n0 >> 4) + nw;
  const s8v* BH = (const s8v*)bph + (size_t)T*128*64 + lane;
  const s8v* BL = (const s8v*)bpl + (size_t)T*128*64 + lane;
  f4v acc[4];
  #pragma unroll
  for (int i = 0; i < 4; ++i) { acc[i][0]=0.f; acc[i][1]=0.f; acc[i][2]=0.f; acc[i][3]=0.f; }
  s8v z8;
  #pragma unroll
  for (int j = 0; j < 8; ++j) z8[j] = 0;

  int kw = -1;
  u64 w0 = 0, w1 = 0, w2 = 0, w3 = 0;
  s8v b0h = z8, b0l = z8, b1h = z8, b1l = z8;
  if (cmw) {
    kw = kwb + __builtin_ctzll(cmw); cmw &= cmw - 1;
    const u64* wp = wm + (size_t)kw*4096 + m0;
    w0 = wp[l15]; w1 = wp[16 + l15]; w2 = wp[32 + l15]; w3 = wp[48 + l15];
    b0h = BH[(kw*2)*64];   b0l = BL[(kw*2)*64];
    b1h = BH[(kw*2+1)*64]; b1l = BL[(kw*2+1)*64];
  }
  while (kw >= 0) {
    int kwn = -1;
    u64 nw0 = 0, nw1 = 0, nw2 = 0, nw3 = 0;
    s8v nb0h = z8, nb0l = z8, nb1h = z8, nb1l = z8;
    if (cmw) {                                  // prefetch next chunk (mask words + B frags)
      kwn = kwb + __builtin_ctzll(cmw); cmw &= cmw - 1;
      const u64* wp = wm + (size_t)kwn*4096 + m0;
      nw0 = wp[l15]; nw1 = wp[16 + l15]; nw2 = wp[32 + l15]; nw3 = wp[48 + l15];
      nb0h = BH[(kwn*2)*64];   nb0l = BL[(kwn*2)*64];
      nb1h = BH[(kwn*2+1)*64]; nb1l = BL[(kwn*2+1)*64];
    }
    {
      unsigned sh = quad*8;
      s8v a0 = lut[(unsigned)(w0 >> sh) & 0xffu];
      s8v a1 = lut[(unsigned)(w1 >> sh) & 0xffu];
      s8v a2 = lut[(unsigned)(w2 >> sh) & 0xffu];
      s8v a3 = lut[(unsigned)(w3 >> sh) & 0xffu];
      acc[0] = __builtin_amdgcn_mfma_f32_16x16x32_bf16(a0, b0h, acc[0], 0, 0, 0);
      acc[0] = __builtin_amdgcn_mfma_f32_16x16x32_bf16(a0, b0l, acc[0], 0, 0, 0);
      acc[1] = __builtin_amdgcn_mfma_f32_16x16x32_bf16(a1, b0h, acc[1], 0, 0, 0);
      acc[1] = __builtin_amdgcn_mfma_f32_16x16x32_bf16(a1, b0l, acc[1], 0, 0, 0);
      acc[2] = __builtin_amdgcn_mfma_f32_16x16x32_bf16(a2, b0h, acc[2], 0, 0, 0);
      acc[2] = __builtin_amdgcn_mfma_f32_16x16x32_bf16(a2, b0l, acc[2], 0, 0, 0);
      acc[3] = __builtin_amdgcn_mfma_f32_16x16x32_bf16(a3, b0h, acc[3], 0, 0, 0);
      acc[3] = __builtin_amdgcn_mfma_f32_16x16x32_bf16(a3, b0l, acc[3], 0, 0, 0);
      sh = 32 + quad*8;
      a0 = lut[(unsigned)(w0 >> sh) & 0xffu];
      a1 = lut[(unsigned)(w1 >> sh) & 0xffu];
      a2 = lut[(unsigned)(w2 >> sh) & 0xffu];
      a3 = lut[(unsigned)(w3 >> sh) & 0xffu];
      acc[0] = __builtin_amdgcn_mfma_f32_16x16x32_bf16(a0, b1h, acc[0], 0, 0, 0);
      acc[0] = __builtin_amdgcn_mfma_f32_16x16x32_bf16(a0, b1l, acc[0], 0, 0, 0);
      acc[1] = __builtin_amdgcn_mfma_f32_16x16x32_bf16(a1, b1h, acc[1], 0, 0, 0);
      acc[1] = __builtin_amdgcn_mfma_f32_16x16x32_bf16(a1, b1l, acc[1], 0, 0, 0);
      acc[2] = __builtin_amdgcn_mfma_f32_16x16x32_bf16(a2, b1h, acc[2], 0, 0, 0);
      acc[2] = __builtin_amdgcn_mfma_f32_16x16x32_bf16(a2, b1l, acc[2], 0, 0, 0);
      acc[3] = __builtin_amdgcn_mfma_f32_16x16x32_bf16(a3, b1h, acc[3], 0, 0, 0);
      acc[3] = __builtin_amdgcn_mfma_f32_16x16x32_bf16(a3, b1l, acc[3], 0, 0, 0);
    }
    kw = kwn;
    w0 = nw0; w1 = nw1; w2 = nw2; w3 = nw3;
    b0h = nb0h; b0l = nb0l; b1h = nb1h; b1l = nb1l;
  }
  // combine K-halves through LDS; epilogue + BN partial sums by ks==0 waves
  int nl = nw*16 + l15;
  if (ks == 1) {
    #pragma unroll
    for (int mf = 0; mf < 4; ++mf) {
      #pragma unroll
      for (int reg = 0; reg < 4; ++reg)
        tile[(mf*16 + quad*4 + reg)*65 + nl] = acc[mf][reg];
    }
  }
  __syncthreads();
  if (ks == 0) {
    int n = n0 + nl;
    const int* dgp = g ? deg2 : deg1;
    float bn = (g ? biasB : biasA)[n];
    int zoff = g*256;
    float sv = 0.0f, qv = 0.0f;
    #pragma unroll
    for (int mf = 0; mf < 4; ++mf) {
      #pragma unroll
      for (int reg = 0; reg < 4; ++reg) {
        int v = m0 + mf*16 + quad*4 + reg;
        float s = acc[mf][reg] + tile[(mf*16 + quad*4 + reg)*65 + nl];
        int d = dgp[v];
        float sfac = 0.0f;
        if (d > 0) { float df = (float)d; sfac = (1.0f / sqrtf(df)) / df; }
        float val = Z[(size_t)v*512 + zoff + n] + sfac*s + bn;
        val = fmaxf(val, 0.0f);
        h[(size_t)v*512 + zoff + n] = val;
        sv += val; qv += val*val;
      }
    }
    // reduce over the 4 quads sharing column n (lanes l15, +16, +32, +48)
    sv += __shfl_down(sv, 32); qv += __shfl_down(qv, 32);
    sv += __shfl_down(sv, 16); qv += __shfl_down(qv, 16);
    if (quad == 0) {
      int col = zoff + n;
      atomicAdd(&bnacc[col*2 + 0], sv);
      atomicAdd(&bnacc[col*2 + 1], qv);
    }
  }
}

// ---------- 8. BN apply + split to frag-major hn packs (K=512) ----------
__global__ __launch_bounds__(256) void k_bnapply_split(const float* __restrict__ h, const float* __restrict__ acc,
                                                       const float* __restrict__ gamma, const float* __restrict__ beta,
                                                       short* __restrict__ hPh, short* __restrict__ hPl) {
  int i = blockIdx.x*256 + threadIdx.x;       // 524288 float4s
  float4 v = ((const float4*)h)[i];
  int r = i >> 7;
  int colb = (i & 127) * 4;
  float vv[4] = {v.x, v.y, v.z, v.w};
  short4 hh, ll;
  short* hp = (short*)&hh; short* lp = (short*)&ll;
  #pragma unroll
  for (int j = 0; j < 4; ++j) {
    int col = colb + j;
    float mean = acc[col*2] * (1.0f/4096.0f);
    float var  = acc[col*2 + 1] * (1.0f/4096.0f) - mean*mean;
    float inv  = rsqrtf(var + 1e-5f);
    float sc = gamma[col] * inv;
    float sh = beta[col] - mean * sc;
    split2(vv[j]*sc + sh, hp[j], lp[j]);
  }
  size_t off = packoff(r, colb, 16);
  ((short4*)hPh)[off >> 2] = hh;
  ((short4*)hPl)[off >> 2] = ll;
}

// ---------- 9. final: inline BN2 + readout + modality softmax mix ----------
__global__ __launch_bounds__(256) void k_final2(const float* __restrict__ h, const float* __restrict__ acc2,
                                                const float* __restrict__ gamma2, const float* __restrict__ beta2,
                                                const float* __restrict__ w_ro, const float* __restrict__ cl,
                                                float* __restrict__ out) {
  int node = blockIdx.x;
  int t = threadIdx.x, m = t >> 6, lane = t & 63;
  const float* row = h + (size_t)(m*1024 + node)*512;
  float a0 = 0.f, a1 = 0.f, a2 = 0.f, a3 = 0.f;
  for (int it = 0; it < 8; ++it) {
    int k = lane + it*64;
    float mean = acc2[k*2] * (1.0f/4096.0f);
    float var  = acc2[k*2 + 1] * (1.0f/4096.0f) - mean*mean;
    float inv  = rsqrtf(var + 1e-5f);
    float sc = gamma2[k] * inv;
    float sh = beta2[k] - mean * sc;
    float hv = row[k]*sc + sh;
    float4 w = ((const float4*)w_ro)[k];
    a0 += hv*w.x; a1 += hv*w.y; a2 += hv*w.z; a3 += hv*w.w;
  }
  for (int off = 32; off > 0; off >>= 1) {
    a0 += __shfl_down(a0, off); a1 += __shfl_down(a1, off);
    a2 += __shfl_down(a2, off); a3 += __shfl_down(a3, off);
  }
  __shared__ float part[4][4];
  if (lane == 0) { part[m][0]=a0; part[m][1]=a1; part[m][2]=a2; part[m][3]=a3; }
  __syncthreads();
  if (t < 4) {
    float c0 = cl[0], c1 = cl[1], c2 = cl[2], c3 = cl[3];
    float mx = fmaxf(fmaxf(c0,c1), fmaxf(c2,c3));
    float e0 = expf(c0-mx), e1 = expf(c1-mx), e2 = expf(c2-mx), e3 = expf(c3-mx);
    float inv = 1.0f/(e0+e1+e2+e3);
    float r = (e0*part[0][t] + e1*part[1][t] + e2*part[2][t] + e3*part[3][t]) * inv;
    out[node*4 + t] = r;
  }
}

extern "C" void kernel_launch(void* const* d_in, const int* in_sizes, int n_in,
                              void* d_out, int out_size, void* d_ws, size_t ws_size,
                              hipStream_t stream) {
  const float* features = (const float*)d_in[0];
  const float* sparse   = (const float*)d_in[1];
  const float* cmix     = (const float*)d_in[2];
  const float* wAC1 = (const float*)d_in[3];
  const float* bAC1 = (const float*)d_in[4];
  const float* wCA1 = (const float*)d_in[5];
  const float* bCA1 = (const float*)d_in[6];
  const float* wAC2 = (const float*)d_in[7];
  const float* bAC2 = (const float*)d_in[8];
  const float* wCA2 = (const float*)d_in[9];
  const float* bCA2 = (const float*)d_in[10];
  const float* gamma1 = (const float*)d_in[11];
  const float* beta1  = (const float*)d_in[12];
  const float* gamma2 = (const float*)d_in[13];
  const float* beta2  = (const float*)d_in[14];
  const float* w_ro   = (const float*)d_in[15];
  float* out = (float*)d_out;

  char* ws = (char*)d_ws;
  const size_t MB = 1024ull*1024ull, KB = 1024ull;
  u64*   bits    = (u64*)(ws + 0);               // 1.25 MB
  u64*   mask    = (u64*)(ws + 2*MB);            // 2 MB (row-major)
  u64*   mask_wm = (u64*)(ws + 4*MB);            // 2 MB (word-major)
  u64*   maskT_wm= (u64*)(ws + 6*MB);            // 2 MB (word-major)
  int*   deg1    = (int*)(ws + 8*MB);            // 16 KB  [zeroed]
  float* bnacc1  = (float*)(ws + 8*MB + 16*KB);  // 4 KB   [zeroed]
  float* bnacc2  = (float*)(ws + 8*MB + 20*KB);  // 4 KB   [zeroed]
  u64*   cmask   = (u64*)(ws + 8*MB + 24*KB);    // 1 KB   [zeroed]
  int*   deg2    = (int*)(ws + 8*MB + 28*KB);    // 16 KB
  short* WT1h  = (short*)(ws + 9*MB);            // 128 KB (frag-major pack)
  short* WT1l  = (short*)(ws + 9*MB + 128*KB);   // 128 KB
  short* WT2h  = (short*)(ws + 9*MB + 256*KB);   // 512 KB
  short* WT2l  = (short*)(ws + 9*MB + 768*KB);   // 512 KB
  short* yhP   = (short*)(ws + 11*MB);           // 1 MB (dead after corr3)
  short* ymP   = (short*)(ws + 12*MB);           // 1 MB
  short* ylP   = (short*)(ws + 13*MB);           // 1 MB
  short* fPh   = (short*)(ws + 14*MB);           // 1 MB (dead after L1 dense)
  short* fPl   = (short*)(ws + 15*MB);           // 1 MB
  short* hnPh  = (short*)(ws + 16*MB);           // 4 MB (frag-major, K=512)
  short* hnPl  = (short*)(ws + 20*MB);           // 4 MB
  short* BTh   = (short*)(ws + 24*MB);           // 4 MB (frag-major, distinct from hnP!)
  short* BTl   = (short*)(ws + 28*MB);           // 4 MB
  float* Z     = (float*)(ws + 32*MB);           // 8 MB
  float* h     = (float*)(ws + 40*MB);           // 8 MB (total 48 MB)

  hipMemsetAsync(ws + 8*MB, 0, 25*KB, stream);   // deg1 + bnacc1 + bnacc2 + cmask

  // graph prep
  k_rownorm<<<dim3(4096), dim3(128), 0, stream>>>(features, yhP, ymP, ylP, fPh, fPl);
  k_corr3<<<dim3(16,16,10), dim3(256), 0, stream>>>(yhP, ymP, ylP, sparse, bits);
  k_maskrows<<<dim3(4096), dim3(64), 0, stream>>>(bits, mask, mask_wm, deg2, cmask);
  k_bittrans2<<<dim3(64,4), dim3(256), 0, stream>>>(mask, maskT_wm, deg1, cmask);
  k_prepWTall<<<dim3(8,8,2), dim3(256), 0, stream>>>(wAC1, wCA1, wAC2, wCA2, WT1h, WT1l, WT2h, WT2l);

  // layer 1:  h = relu(Z + sfac*(bits @ (nrm*Z)) + b)  [dense3 also emits BT packs]
  k_dense3<<<dim3(64,8), dim3(256), 0, stream>>>(fPh, fPl, WT1h, WT1l, Z, 4, deg1, deg2, BTh, BTl);
  k_mg3<<<dim3(64,4,2), dim3(512), 0, stream>>>(maskT_wm, mask_wm, cmask, BTh, BTl, Z,
                                                deg1, deg2, bAC1, bCA1, h, bnacc1);
  k_bnapply_split<<<dim3(2048), dim3(256), 0, stream>>>(h, bnacc1, gamma1, beta1, hnPh, hnPl);

  // layer 2
  k_dense3<<<dim3(64,8), dim3(256), 0, stream>>>(hnPh, hnPl, WT2h, WT2l, Z, 16, deg1, deg2, BTh, BTl);
  k_mg3<<<dim3(64,4,2), dim3(512), 0, stream>>>(maskT_wm, mask_wm, cmask, BTh, BTl, Z,
                                                deg1, deg2, bAC2, bCA2, h, bnacc2);

  // readout (BN2 folded inline)
  k_final2<<<dim3(1024), dim3(256), 0, stream>>>(h, bnacc2, gamma2, beta2, w_ro, cmix, out);
}